// Round 15
// baseline (1308.637 us; speedup 1.0000x reference)
//
#include <hip/hip_runtime.h>
#include <hip/hip_bf16.h>

typedef unsigned int u32;
typedef float f4 __attribute__((ext_vector_type(4)));

#define EPS_MSG 1e-7f
#define BN_EPS  1e-5f

#define NTL(p)    __builtin_nontemporal_load(p)
#define NTS(v, p) __builtin_nontemporal_store(v, p)

// ---- small linear: Y[i*ldY + c] = X[i,:]·W[:,c] + B[c] ----------------------
template<int I, int O>
__global__ void k_lin(const float* __restrict__ X, const float* __restrict__ W,
                      const float* __restrict__ B, float* __restrict__ Y,
                      int ldY, int n) {
  __shared__ float Wl[I * O];
  __shared__ float Bl[O];
  for (int t = threadIdx.x; t < I * O; t += blockDim.x) Wl[t] = W[t];
  if (threadIdx.x < O) Bl[threadIdx.x] = B[threadIdx.x];
  __syncthreads();
  int i = blockIdx.x * blockDim.x + threadIdx.x;
  if (i >= n) return;
  float acc[O];
#pragma unroll
  for (int c = 0; c < O; c++) acc[c] = Bl[c];
  const f4* xp = (const f4*)(X + (size_t)i * I);
  for (int q = 0; q < I / 4; q++) {
    f4 v = NTL(xp + q);                 // x is read exactly once: keep out of L3
#pragma unroll
    for (int c = 0; c < O; c++) acc[c] += v.x * Wl[(4 * q + 0) * O + c];
#pragma unroll
    for (int c = 0; c < O; c++) acc[c] += v.y * Wl[(4 * q + 1) * O + c];
#pragma unroll
    for (int c = 0; c < O; c++) acc[c] += v.z * Wl[(4 * q + 2) * O + c];
#pragma unroll
    for (int c = 0; c < O; c++) acc[c] += v.w * Wl[(4 * q + 3) * O + c];
  }
  float* y = Y + (size_t)i * ldY;
#pragma unroll
  for (int c = 0; c < O; c++) y[c] = acc[c];
}

// ---- CSR construction -------------------------------------------------------
__global__ void k_deg(const int* __restrict__ ei, u32* __restrict__ deg, int E) {
  int e = blockIdx.x * blockDim.x + threadIdx.x;
  if (e < E) atomicAdd(&deg[ei[E + e]], 1u);
}

__global__ void k_scan1(const u32* __restrict__ deg, u32* __restrict__ excl,
                        u32* __restrict__ part, int n) {
  __shared__ u32 sm[256];
  int t = threadIdx.x;
  int base = blockIdx.x * 1024 + t * 4;
  u32 v0 = (base + 0 < n) ? deg[base + 0] : 0u;
  u32 v1 = (base + 1 < n) ? deg[base + 1] : 0u;
  u32 v2 = (base + 2 < n) ? deg[base + 2] : 0u;
  u32 v3 = (base + 3 < n) ? deg[base + 3] : 0u;
  u32 tsum = v0 + v1 + v2 + v3;
  sm[t] = tsum;
  __syncthreads();
  for (int o = 1; o < 256; o <<= 1) {
    u32 v = (t >= o) ? sm[t - o] : 0u;
    __syncthreads();
    sm[t] += v;
    __syncthreads();
  }
  u32 tex = sm[t] - tsum;
  if (t == 255) part[blockIdx.x] = sm[255];
  if (base + 0 < n) excl[base + 0] = tex;
  if (base + 1 < n) excl[base + 1] = tex + v0;
  if (base + 2 < n) excl[base + 2] = tex + v0 + v1;
  if (base + 3 < n) excl[base + 3] = tex + v0 + v1 + v2;
}

__global__ void k_scan2(u32* __restrict__ part, int nb) {
  if (threadIdx.x == 0) {
    u32 acc = 0;
    for (int i = 0; i < nb; i++) { u32 v = part[i]; part[i] = acc; acc += v; }
  }
}

__global__ void k_scan3(u32* __restrict__ rowptr, const u32* __restrict__ part,
                        int n, int E) {
  int i = blockIdx.x * blockDim.x + threadIdx.x;
  if (i < n) rowptr[i] += part[i >> 10];
  if (i == 0) rowptr[n] = (u32)E;
}

// slot-fill, csr only (cheap)
__global__ void k_slots(const int* __restrict__ ei, const u32* __restrict__ rowptr,
                        u32* __restrict__ cnt, int* __restrict__ csr_src,
                        int* __restrict__ csr_eid, int E) {
  int e = blockIdx.x * blockDim.x + threadIdx.x;
  if (e >= E) return;
  int s = ei[e], d = ei[E + e];
  u32 slot = rowptr[d] + atomicAdd(&cnt[d], 1u);
  csr_src[slot] = s;
  csr_eid[slot] = e;
}

// slot-major attr permute: nt gather reads, nt coalesced writes (pure stream)
__global__ void k_gather(const int* __restrict__ csr_eid, const float* __restrict__ ea,
                         float* __restrict__ eaperm, int E) {
  int i = blockIdx.x * blockDim.x + threadIdx.x;
  if (i >= E) return;
  int e = NTL(csr_eid + i);
  const f4* p = (const f4*)(ea + (size_t)e * 16);
  f4* q = (f4*)(eaperm + (size_t)i * 16);
  f4 a = NTL(p + 0), b = NTL(p + 1), c = NTL(p + 2), d = NTL(p + 3);
  NTS(a, q + 0); NTS(b, q + 1); NTS(c, q + 2); NTS(d, q + 3);
}

__global__ void k_dinv(const u32* __restrict__ deg, float* __restrict__ dinv, int n) {
  int i = blockIdx.x * blockDim.x + threadIdx.x;
  if (i < n) dinv[i] = rsqrtf((float)(deg[i] + 1u));
}

#define EDGE_DOT(A0,A1,A2,A3) (bias + \
  A0.x * wc[0]  + A0.y * wc[1]  + A0.z * wc[2]  + A0.w * wc[3] + \
  A1.x * wc[4]  + A1.y * wc[5]  + A1.z * wc[6]  + A1.w * wc[7] + \
  A2.x * wc[8]  + A2.y * wc[9]  + A2.z * wc[10] + A2.w * wc[11] + \
  A3.x * wc[12] + A3.y * wc[13] + A3.z * wc[14] + A3.w * wc[15])

// ---- GENConv aggregation d=48: wave/node; nt streams, cached h gathers ------
template<bool PERM>
__global__ void k_agg48(const u32* __restrict__ rowptr, const int* __restrict__ csr_src,
                        const int* __restrict__ csr_eid, const float* __restrict__ attrs,
                        const float* __restrict__ we, const float* __restrict__ be,
                        const float* __restrict__ h, float* __restrict__ out, int n) {
  int lane = threadIdx.x & 63;
  int node = (blockIdx.x * blockDim.x + threadIdx.x) >> 6;
  if (node >= n) return;
  float wc[16];
#pragma unroll
  for (int k = 0; k < 16; k++) wc[k] = 0.f;
  float bias = 0.f;
  if (lane < 48) {
#pragma unroll
    for (int k = 0; k < 16; k++) wc[k] = we[k * 48 + lane];
    bias = be[lane];
  }
  float hself = (lane < 48) ? h[(size_t)node * 48 + lane] : 0.f;
  u32 b = rowptr[node], t = rowptr[node + 1];
  float den = 0.f, num = 0.f;
  u32 i = b;
  if (PERM) {
    for (; i + 4 <= t; i += 4) {
      int s0 = NTL(csr_src + i + 0);
      int s1 = NTL(csr_src + i + 1);
      int s2 = NTL(csr_src + i + 2);
      int s3 = NTL(csr_src + i + 3);
      float hv[4];
      if (lane < 48) {           // 4 independent gathers in flight (cached)
        hv[0] = h[(size_t)s0 * 48 + lane];
        hv[1] = h[(size_t)s1 * 48 + lane];
        hv[2] = h[(size_t)s2 * 48 + lane];
        hv[3] = h[(size_t)s3 * 48 + lane];
      } else { hv[0] = hv[1] = hv[2] = hv[3] = 0.f; }
#pragma unroll
      for (int j = 0; j < 4; j++) {
        const f4* p = (const f4*)(attrs + (size_t)(i + j) * 16);
        f4 a0 = NTL(p + 0), a1 = NTL(p + 1), a2 = NTL(p + 2), a3 = NTL(p + 3);
        float ml = EDGE_DOT(a0, a1, a2, a3);
        float m  = fmaxf(hv[j] + ml, 0.f) + EPS_MSG;
        float ex = __expf(m);
        den += ex; num += ex * m;
      }
    }
  }
  for (; i < t; i++) {
    int s = csr_src[i];
    const f4* p = (const f4*)(attrs + (PERM ? (size_t)i : (size_t)csr_eid[i]) * 16);
    f4 a0 = NTL(p + 0), a1 = NTL(p + 1), a2 = NTL(p + 2), a3 = NTL(p + 3);
    float hvs = (lane < 48) ? h[(size_t)s * 48 + lane] : 0.f;
    float ml = EDGE_DOT(a0, a1, a2, a3);
    float m  = fmaxf(hvs + ml, 0.f) + EPS_MSG;
    float ex = __expf(m);
    den += ex; num += ex * m;
  }
  if (lane < 48)
    out[(size_t)node * 48 + lane] = hself + num / (den + 1e-16f);
}

// ---- GENConv aggregation d=32: half-wave/node; nt streams -------------------
template<bool PERM>
__global__ void k_agg32(const u32* __restrict__ rowptr, const int* __restrict__ csr_src,
                        const int* __restrict__ csr_eid, const float* __restrict__ attrs,
                        const float* __restrict__ we, const float* __restrict__ be,
                        const float* __restrict__ h, float* __restrict__ out, int n) {
  int c    = threadIdx.x & 31;
  int node = (blockIdx.x * blockDim.x + threadIdx.x) >> 5;
  if (node >= n) return;
  float wc[16];
#pragma unroll
  for (int k = 0; k < 16; k++) wc[k] = we[k * 32 + c];
  float bias  = be[c];
  float hself = h[(size_t)node * 32 + c];
  u32 b = rowptr[node], t = rowptr[node + 1];
  float den = 0.f, num = 0.f;
  u32 i = b;
  if (PERM) {
    for (; i + 4 <= t; i += 4) {
      int s0 = NTL(csr_src + i + 0);
      int s1 = NTL(csr_src + i + 1);
      int s2 = NTL(csr_src + i + 2);
      int s3 = NTL(csr_src + i + 3);
      float hv[4];
      hv[0] = h[(size_t)s0 * 32 + c];
      hv[1] = h[(size_t)s1 * 32 + c];
      hv[2] = h[(size_t)s2 * 32 + c];
      hv[3] = h[(size_t)s3 * 32 + c];
#pragma unroll
      for (int j = 0; j < 4; j++) {
        const f4* p = (const f4*)(attrs + (size_t)(i + j) * 16);
        f4 a0 = NTL(p + 0), a1 = NTL(p + 1), a2 = NTL(p + 2), a3 = NTL(p + 3);
        float ml = EDGE_DOT(a0, a1, a2, a3);
        float m  = fmaxf(hv[j] + ml, 0.f) + EPS_MSG;
        float ex = __expf(m);
        den += ex; num += ex * m;
      }
    }
  }
  for (; i < t; i++) {
    int s = csr_src[i];
    const f4* p = (const f4*)(attrs + (PERM ? (size_t)i : (size_t)csr_eid[i]) * 16);
    f4 a0 = NTL(p + 0), a1 = NTL(p + 1), a2 = NTL(p + 2), a3 = NTL(p + 3);
    float hvs = h[(size_t)s * 32 + c];
    float ml = EDGE_DOT(a0, a1, a2, a3);
    float m  = fmaxf(hvs + ml, 0.f) + EPS_MSG;
    float ex = __expf(m);
    den += ex; num += ex * m;
  }
  out[(size_t)node * 32 + c] = hself + num / (den + 1e-16f);
}

// ---- zt = X@W1 + B1 (split panels) + per-block BN-stat partials -------------
template<int D>
__global__ void k_ztstats(const float* __restrict__ X, const float* __restrict__ W,
                          const float* __restrict__ B, float* __restrict__ Z1,
                          float* __restrict__ Z2, float* __restrict__ partial, int n) {
  __shared__ float Wl[D * 2 * D];
  __shared__ float Bl[2 * D];
  __shared__ float red[4][4 * D];
  for (int t = threadIdx.x; t < D * 2 * D; t += blockDim.x) Wl[t] = W[t];
  for (int t = threadIdx.x; t < 2 * D; t += blockDim.x) Bl[t] = B[t];
  __syncthreads();
  int i = blockIdx.x * blockDim.x + threadIdx.x;
  bool act = (i < n);
  float acc[2 * D];
#pragma unroll
  for (int c = 0; c < 2 * D; c++) acc[c] = 0.f;
  if (act) {
#pragma unroll
    for (int c = 0; c < 2 * D; c++) acc[c] = Bl[c];
    const float4* xp = (const float4*)(X + (size_t)i * D);
    for (int q = 0; q < D / 4; q++) {
      float4 v = xp[q];
#pragma unroll
      for (int c = 0; c < 2 * D; c++) acc[c] += v.x * Wl[(4 * q + 0) * 2 * D + c];
#pragma unroll
      for (int c = 0; c < 2 * D; c++) acc[c] += v.y * Wl[(4 * q + 1) * 2 * D + c];
#pragma unroll
      for (int c = 0; c < 2 * D; c++) acc[c] += v.z * Wl[(4 * q + 2) * 2 * D + c];
#pragma unroll
      for (int c = 0; c < 2 * D; c++) acc[c] += v.w * Wl[(4 * q + 3) * 2 * D + c];
    }
    float* z1 = Z1 + (size_t)i * D;
    float* z2 = Z2 + (size_t)i * D;
#pragma unroll
    for (int c = 0; c < D; c++) { z1[c] = acc[c]; z2[c] = acc[D + c]; }
  } else {
#pragma unroll
    for (int c = 0; c < 2 * D; c++) acc[c] = 0.f;
  }
  int lane = threadIdx.x & 63;
  int wv   = threadIdx.x >> 6;
#pragma unroll
  for (int c = 0; c < 2 * D; c++) {
    float v = acc[c], v2 = v * v;
#pragma unroll
    for (int o = 32; o; o >>= 1) { v += __shfl_xor(v, o); v2 += __shfl_xor(v2, o); }
    if (lane == 0) { red[wv][c] = v; red[wv][2 * D + c] = v2; }
  }
  __syncthreads();
  if (threadIdx.x < 4 * D) {
    float s = red[0][threadIdx.x] + red[1][threadIdx.x] +
              red[2][threadIdx.x] + red[3][threadIdx.x];
    partial[(size_t)blockIdx.x * 4 * D + threadIdx.x] = s;
  }
}

__global__ void k_bnfin(const float* __restrict__ partial, float* __restrict__ stats,
                        int nb, int m) {
  int c = blockIdx.x * blockDim.x + threadIdx.x;
  if (c >= m) return;
  float s = 0.f;
  for (int b = 0; b < nb; b++) s += partial[(size_t)b * m + c];
  stats[c] = s;
}

// ---- BN-normalize -> relu -> @W2+b2 -> relu -> @Ws(+Bs) -> out (O wide) -----
template<int D, int DD, int O, bool ADDBS>
__global__ void k_mlp_lin(const float* __restrict__ ztA, const float* __restrict__ ztB,
                          const float* __restrict__ stats,
                          const float* __restrict__ G, const float* __restrict__ BE,
                          const float* __restrict__ W2, const float* __restrict__ B2,
                          const float* __restrict__ Wsa, const float* __restrict__ Wsb,
                          const float* __restrict__ Bs,
                          float* __restrict__ out, float invN, int n) {
  __shared__ float Wl[DD * D];
  __shared__ float Ws[D * O];
  __shared__ float Bl[D];
  __shared__ float Bsl[O];
  __shared__ float sc[DD], sh[DD];
  for (int t = threadIdx.x; t < DD * D; t += blockDim.x) Wl[t] = W2[t];
  if (Wsb == nullptr) {
    for (int t = threadIdx.x; t < D * O; t += blockDim.x) Ws[t] = Wsa[t];
  } else {
    for (int t = threadIdx.x; t < D * O; t += blockDim.x) {
      int k = t / O, o = t % O;
      Ws[t] = (o < O / 2) ? Wsa[k * (O / 2) + o] : Wsb[k * (O / 2) + (o - O / 2)];
    }
  }
  if (threadIdx.x < D) Bl[threadIdx.x] = B2[threadIdx.x];
  if (threadIdx.x < O) Bsl[threadIdx.x] = ADDBS ? Bs[threadIdx.x] : 0.f;
  if (threadIdx.x < DD) {
    int c   = threadIdx.x;
    float m = stats[c] * invN;
    float v = stats[DD + c] * invN - m * m;
    float s = G[c] * rsqrtf(v + BN_EPS);
    sc[c] = s; sh[c] = BE[c] - m * s;
  }
  __syncthreads();
  int i = blockIdx.x * blockDim.x + threadIdx.x;
  if (i >= n) return;
  float y[D];
#pragma unroll
  for (int c = 0; c < D; c++) y[c] = Bl[c];
  const float* a = ztA + (size_t)i * D;
  const float* b = ztB + (size_t)i * D;
  for (int k = 0; k < D; k++) {
    float z = fmaxf(a[k] * sc[k] + sh[k], 0.f);
#pragma unroll
    for (int c = 0; c < D; c++) y[c] += z * Wl[k * D + c];
  }
  for (int k = D; k < DD; k++) {
    float z = fmaxf(b[k - D] * sc[k] + sh[k], 0.f);
#pragma unroll
    for (int c = 0; c < D; c++) y[c] += z * Wl[k * D + c];
  }
  float acc[O];
#pragma unroll
  for (int o = 0; o < O; o++) acc[o] = Bsl[o];
#pragma unroll
  for (int k = 0; k < D; k++) {
    float z = fmaxf(y[k], 0.f);
#pragma unroll
    for (int o = 0; o < O; o++) acc[o] += z * Ws[k * O + o];
  }
  float* yo = out + (size_t)i * O;
#pragma unroll
  for (int o = 0; o < O; o++) yo[o] = acc[o];
}

// ---- scale head outputs by dinv: yzd[i][c] = yz[i][c] * dinv[i] -------------
__global__ void k_scale(const float* __restrict__ yz, const float* __restrict__ dinv,
                        float* __restrict__ yzd, int n) {
  int idx = blockIdx.x * blockDim.x + threadIdx.x;
  if (idx >= n * 32) return;
  yzd[idx] = yz[idx] * dinv[idx >> 5];
}

// ---- GCN heads: CSR gather of pre-scaled rows, chunk-4, fused store ---------
__global__ void k_gcn(const u32* __restrict__ rowptr, const int* __restrict__ csr_src,
                      const float* __restrict__ yzd, const float* __restrict__ dinv,
                      const float* __restrict__ bmu, const float* __restrict__ bls,
                      float* __restrict__ out, int n) {
  int c    = threadIdx.x & 31;
  int node = (blockIdx.x * blockDim.x + threadIdx.x) >> 5;
  if (node >= n) return;
  u32 b = rowptr[node], t = rowptr[node + 1];
  float acc = 0.f;
  u32 i = b;
  for (; i + 4 <= t; i += 4) {
    int s0 = NTL(csr_src + i + 0);
    int s1 = NTL(csr_src + i + 1);
    int s2 = NTL(csr_src + i + 2);
    int s3 = NTL(csr_src + i + 3);
    float y0 = yzd[(size_t)s0 * 32 + c];
    float y1 = yzd[(size_t)s1 * 32 + c];
    float y2 = yzd[(size_t)s2 * 32 + c];
    float y3 = yzd[(size_t)s3 * 32 + c];
    acc += y0 + y1 + y2 + y3;
  }
  for (; i < t; i++) {
    int s0 = csr_src[i];
    acc += yzd[(size_t)s0 * 32 + c];
  }
  float dv  = dinv[node];
  float val = (acc + yzd[(size_t)node * 32 + c]) * dv +
              ((c < 16) ? bmu[c] : bls[c - 16]);
  if (c < 16) out[(size_t)node * 16 + c] = val;
  else        out[(size_t)n * 16 + (size_t)node * 16 + (c - 16)] = val;
}

extern "C" void kernel_launch(void* const* d_in, const int* in_sizes, int n_in,
                              void* d_out, int out_size, void* d_ws, size_t ws_size,
                              hipStream_t stream) {
  const float* x      = (const float*)d_in[0];
  const int*  ei      = (const int*)d_in[1];          // int32 (2,E) rows
  const float* ea     = (const float*)d_in[2];
  const float* w_src1 = (const float*)d_in[3];  const float* b_src1 = (const float*)d_in[4];
  const float* w_edge1= (const float*)d_in[5];  const float* b_edge1= (const float*)d_in[6];
  const float* w_m1a  = (const float*)d_in[7];  const float* b_m1a  = (const float*)d_in[8];
  const float* g1     = (const float*)d_in[9];  const float* be1    = (const float*)d_in[10];
  const float* w_m1b  = (const float*)d_in[11]; const float* b_m1b  = (const float*)d_in[12];
  const float* w_src2 = (const float*)d_in[13]; const float* b_src2 = (const float*)d_in[14];
  const float* w_edge2= (const float*)d_in[15]; const float* b_edge2= (const float*)d_in[16];
  const float* w_m2a  = (const float*)d_in[17]; const float* b_m2a  = (const float*)d_in[18];
  const float* g2     = (const float*)d_in[19]; const float* be2    = (const float*)d_in[20];
  const float* w_m2b  = (const float*)d_in[21]; const float* b_m2b  = (const float*)d_in[22];
  const float* w_mu   = (const float*)d_in[23]; const float* b_mu   = (const float*)d_in[24];
  const float* w_ls   = (const float*)d_in[25]; const float* b_ls   = (const float*)d_in[26];

  const int N = in_sizes[0] / 64;
  const int E = in_sizes[1] / 2;

  const int NB  = (N + 255) / 256;
  const int EB  = (E + 255) / 256;
  const int SB1 = (N + 1023) / 1024;

  float* ws     = (float*)d_ws;
  size_t N48    = (size_t)N * 48;
  float* P0     = ws;
  float* P1     = ws + N48;
  float* P2     = ws + 2 * N48;
  float* P3     = ws + 3 * N48;
  size_t o      = 4 * N48;
  u32*  rowptr  = (u32*)(ws + o);            // N+1
  u32*  cnt     = rowptr + (N + 1);          // N
  u32*  deg     = cnt + N;                   // N
  u32*  part    = deg + N;                   // 256
  float* dinv   = (float*)(part + 256);      // N
  float* stats  = dinv + N;                  // 512
  size_t po     = o + 4 * (size_t)N + 769;
  float* partial= ws + po;                   // NB*192
  size_t co     = (po + (size_t)NB * 192 + 3) & ~(size_t)3;
  int*  csr_src = (int*)(ws + co);           // E ints
  int*  csr_eid = csr_src + E;               // E ints
  size_t eo     = co + 2 * (size_t)E;
  float* eaperm = ws + eo;                   // 16E floats (perm path only)
  size_t needB  = (eo + 16 * (size_t)E + 16) * sizeof(float);
  const bool PERM = (ws_size >= needB);

  dim3 b256(256);

  hipMemsetAsync(cnt, 0, 2 * (size_t)N * sizeof(u32), stream);

  // CSR build
  k_deg<<<EB, b256, 0, stream>>>(ei, deg, E);
  k_scan1<<<SB1, b256, 0, stream>>>(deg, rowptr, part, N);
  k_scan2<<<1, 64, 0, stream>>>(part, SB1);
  k_scan3<<<NB, b256, 0, stream>>>(rowptr, part, N, E);
  k_slots<<<EB, b256, 0, stream>>>(ei, rowptr, cnt, csr_src, csr_eid, E);
  if (PERM) k_gather<<<EB, b256, 0, stream>>>(csr_eid, ea, eaperm, E);
  k_dinv<<<NB, b256, 0, stream>>>(deg, dinv, N);

  const float* attrs = PERM ? eaperm : ea;

  // ---- GENConv 1 (64 -> 48) ----
  k_lin<64, 48><<<NB, b256, 0, stream>>>(x, w_src1, b_src1, P0, 48, N);
  if (PERM) k_agg48<true><<<(N * 64 + 255) / 256, b256, 0, stream>>>(rowptr, csr_src,
                                           csr_eid, attrs, w_edge1, b_edge1, P0, P3, N);
  else      k_agg48<false><<<(N * 64 + 255) / 256, b256, 0, stream>>>(rowptr, csr_src,
                                           csr_eid, attrs, w_edge1, b_edge1, P0, P3, N);
  k_ztstats<48><<<NB, b256, 0, stream>>>(P3, w_m1a, b_m1a, P1, P2, partial, N);
  k_bnfin<<<1, 256, 0, stream>>>(partial, stats, NB, 192);
  k_mlp_lin<48, 96, 32, true><<<NB, b256, 0, stream>>>(P1, P2, stats, g1, be1,
                                                       w_m1b, b_m1b, w_src2, nullptr,
                                                       b_src2, P0, 1.0f / (float)N, N);

  // ---- GENConv 2 (48 -> 32) ----
  if (PERM) k_agg32<true><<<(N * 32 + 255) / 256, b256, 0, stream>>>(rowptr, csr_src,
                                           csr_eid, attrs, w_edge2, b_edge2, P0, P3, N);
  else      k_agg32<false><<<(N * 32 + 255) / 256, b256, 0, stream>>>(rowptr, csr_src,
                                           csr_eid, attrs, w_edge2, b_edge2, P0, P3, N);
  k_ztstats<32><<<NB, b256, 0, stream>>>(P3, w_m2a, b_m2a, P1, P2, partial, N);
  k_bnfin<<<1, 256, 0, stream>>>(partial, stats + 256, NB, 128);
  k_mlp_lin<32, 64, 32, false><<<NB, b256, 0, stream>>>(P1, P2, stats + 256, g2, be2,
                                                        w_m2b, b_m2b, w_mu, w_ls,
                                                        nullptr, P0, 1.0f / (float)N, N);

  // ---- GCN heads: pre-scale rows by dinv, then gather ----
  k_scale<<<(N * 32 + 255) / 256, b256, 0, stream>>>(P0, dinv, P3, N);
  k_gcn<<<(N * 32 + 255) / 256, b256, 0, stream>>>(rowptr, csr_src, P3, dinv,
                                                   b_mu, b_ls, (float*)d_out, N);
}

// Round 16
// 1008.618 us; speedup vs baseline: 1.2975x; 1.2975x over previous
//
#include <hip/hip_runtime.h>
#include <hip/hip_bf16.h>

typedef unsigned int u32;
typedef unsigned short u16;

#define EPS_MSG 1e-7f
#define BN_EPS  1e-5f

__device__ __forceinline__ u16 f2bf(float f) {          // round-to-nearest-even
  u32 u = __float_as_uint(f);
  return (u16)((u + 0x7FFFu + ((u >> 16) & 1u)) >> 16);
}
__device__ __forceinline__ float bflo(u32 v) { return __uint_as_float(v << 16); }
__device__ __forceinline__ float bfhi(u32 v) { return __uint_as_float(v & 0xFFFF0000u); }
__device__ __forceinline__ float bf1(u16 v)  { return __uint_as_float(((u32)v) << 16); }

// dot of 16 bf16 attrs (2×uint4) against wc[16]
#define DOTBF(V0, V1) (bias + \
  bflo(V0.x) * wc[0]  + bfhi(V0.x) * wc[1]  + bflo(V0.y) * wc[2]  + bfhi(V0.y) * wc[3] + \
  bflo(V0.z) * wc[4]  + bfhi(V0.z) * wc[5]  + bflo(V0.w) * wc[6]  + bfhi(V0.w) * wc[7] + \
  bflo(V1.x) * wc[8]  + bfhi(V1.x) * wc[9]  + bflo(V1.y) * wc[10] + bfhi(V1.y) * wc[11] + \
  bflo(V1.z) * wc[12] + bfhi(V1.z) * wc[13] + bflo(V1.w) * wc[14] + bfhi(V1.w) * wc[15])

#define EDGE_DOT(A0,A1,A2,A3) (bias + \
  A0.x * wc[0]  + A0.y * wc[1]  + A0.z * wc[2]  + A0.w * wc[3] + \
  A1.x * wc[4]  + A1.y * wc[5]  + A1.z * wc[6]  + A1.w * wc[7] + \
  A2.x * wc[8]  + A2.y * wc[9]  + A2.z * wc[10] + A2.w * wc[11] + \
  A3.x * wc[12] + A3.y * wc[13] + A3.z * wc[14] + A3.w * wc[15])

// ---- small linear: Y[i*ldY+c] = X[i,:]·W[:,c] + B[c]; optional bf16 shadow --
template<int I, int O, bool WBF>
__global__ void k_lin(const float* __restrict__ X, const float* __restrict__ W,
                      const float* __restrict__ B, float* __restrict__ Y,
                      u16* __restrict__ Ybf, int ldY, int n) {
  __shared__ float Wl[I * O];
  __shared__ float Bl[O];
  for (int t = threadIdx.x; t < I * O; t += blockDim.x) Wl[t] = W[t];
  if (threadIdx.x < O) Bl[threadIdx.x] = B[threadIdx.x];
  __syncthreads();
  int i = blockIdx.x * blockDim.x + threadIdx.x;
  if (i >= n) return;
  float acc[O];
#pragma unroll
  for (int c = 0; c < O; c++) acc[c] = Bl[c];
  const float4* xp = (const float4*)(X + (size_t)i * I);
  for (int q = 0; q < I / 4; q++) {
    float4 v = xp[q];
#pragma unroll
    for (int c = 0; c < O; c++) acc[c] += v.x * Wl[(4 * q + 0) * O + c];
#pragma unroll
    for (int c = 0; c < O; c++) acc[c] += v.y * Wl[(4 * q + 1) * O + c];
#pragma unroll
    for (int c = 0; c < O; c++) acc[c] += v.z * Wl[(4 * q + 2) * O + c];
#pragma unroll
    for (int c = 0; c < O; c++) acc[c] += v.w * Wl[(4 * q + 3) * O + c];
  }
  float* y = Y + (size_t)i * ldY;
#pragma unroll
  for (int c = 0; c < O; c++) y[c] = acc[c];
  if (WBF) {
    u16* yb = Ybf + (size_t)i * O;
#pragma unroll
    for (int c = 0; c < O; c++) yb[c] = f2bf(acc[c]);
  }
}

// ---- CSR construction -------------------------------------------------------
__global__ void k_deg(const int* __restrict__ ei, u32* __restrict__ deg, int E) {
  int e = blockIdx.x * blockDim.x + threadIdx.x;
  if (e < E) atomicAdd(&deg[ei[E + e]], 1u);
}

__global__ void k_scan1(const u32* __restrict__ deg, u32* __restrict__ excl,
                        u32* __restrict__ part, int n) {
  __shared__ u32 sm[256];
  int t = threadIdx.x;
  int base = blockIdx.x * 1024 + t * 4;
  u32 v0 = (base + 0 < n) ? deg[base + 0] : 0u;
  u32 v1 = (base + 1 < n) ? deg[base + 1] : 0u;
  u32 v2 = (base + 2 < n) ? deg[base + 2] : 0u;
  u32 v3 = (base + 3 < n) ? deg[base + 3] : 0u;
  u32 tsum = v0 + v1 + v2 + v3;
  sm[t] = tsum;
  __syncthreads();
  for (int o = 1; o < 256; o <<= 1) {
    u32 v = (t >= o) ? sm[t - o] : 0u;
    __syncthreads();
    sm[t] += v;
    __syncthreads();
  }
  u32 tex = sm[t] - tsum;
  if (t == 255) part[blockIdx.x] = sm[255];
  if (base + 0 < n) excl[base + 0] = tex;
  if (base + 1 < n) excl[base + 1] = tex + v0;
  if (base + 2 < n) excl[base + 2] = tex + v0 + v1;
  if (base + 3 < n) excl[base + 3] = tex + v0 + v1 + v2;
}

__global__ void k_scan2(u32* __restrict__ part, int nb) {
  if (threadIdx.x == 0) {
    u32 acc = 0;
    for (int i = 0; i < nb; i++) { u32 v = part[i]; part[i] = acc; acc += v; }
  }
}

__global__ void k_scan3(u32* __restrict__ rowptr, const u32* __restrict__ part,
                        int n, int E) {
  int i = blockIdx.x * blockDim.x + threadIdx.x;
  if (i < n) rowptr[i] += part[i >> 10];
  if (i == 0) rowptr[n] = (u32)E;
}

__global__ void k_slots(const int* __restrict__ ei, const u32* __restrict__ rowptr,
                        u32* __restrict__ cnt, int* __restrict__ csr_src,
                        int* __restrict__ csr_eid, int E) {
  int e = blockIdx.x * blockDim.x + threadIdx.x;
  if (e >= E) return;
  int s = ei[e], d = ei[E + e];
  u32 slot = rowptr[d] + atomicAdd(&cnt[d], 1u);
  csr_src[slot] = s;
  csr_eid[slot] = e;
}

// slot-major attr permute, packed bf16: 32B/edge, coalesced writes
__global__ void k_gather(const int* __restrict__ csr_eid, const float* __restrict__ ea,
                         u32* __restrict__ eaperm, int E) {
  int i = blockIdx.x * blockDim.x + threadIdx.x;
  if (i >= E) return;
  int e = csr_eid[i];
  const float4* p = (const float4*)(ea + (size_t)e * 16);
  float4 a = p[0], b = p[1], c = p[2], d = p[3];
  uint4* q = (uint4*)(eaperm + (size_t)i * 8);
  uint4 w0, w1;
  w0.x = ((u32)f2bf(a.y) << 16) | f2bf(a.x);
  w0.y = ((u32)f2bf(a.w) << 16) | f2bf(a.z);
  w0.z = ((u32)f2bf(b.y) << 16) | f2bf(b.x);
  w0.w = ((u32)f2bf(b.w) << 16) | f2bf(b.z);
  w1.x = ((u32)f2bf(c.y) << 16) | f2bf(c.x);
  w1.y = ((u32)f2bf(c.w) << 16) | f2bf(c.z);
  w1.z = ((u32)f2bf(d.y) << 16) | f2bf(d.x);
  w1.w = ((u32)f2bf(d.w) << 16) | f2bf(d.z);
  q[0] = w0; q[1] = w1;
}

__global__ void k_dinv(const u32* __restrict__ deg, float* __restrict__ dinv, int n) {
  int i = blockIdx.x * blockDim.x + threadIdx.x;
  if (i < n) dinv[i] = rsqrtf((float)(deg[i] + 1u));
}

// ---- GENConv agg d=48: wave/node; bf16 attrs + bf16 h-gather, f32 hself -----
template<bool PERM>
__global__ void k_agg48(const u32* __restrict__ rowptr, const int* __restrict__ csr_src,
                        const int* __restrict__ csr_eid, const u32* __restrict__ eaperm,
                        const float* __restrict__ ea,
                        const float* __restrict__ we, const float* __restrict__ be,
                        const float* __restrict__ h, const u16* __restrict__ hbf,
                        float* __restrict__ out, int n) {
  int lane = threadIdx.x & 63;
  int node = (blockIdx.x * blockDim.x + threadIdx.x) >> 6;
  if (node >= n) return;
  float wc[16];
#pragma unroll
  for (int k = 0; k < 16; k++) wc[k] = 0.f;
  float bias = 0.f;
  if (lane < 48) {
#pragma unroll
    for (int k = 0; k < 16; k++) wc[k] = we[k * 48 + lane];
    bias = be[lane];
  }
  float hself = (lane < 48) ? h[(size_t)node * 48 + lane] : 0.f;
  u32 b = rowptr[node], t = rowptr[node + 1];
  float den = 0.f, num = 0.f;
  u32 i = b;
  if (PERM) {
    for (; i + 2 <= t; i += 2) {
      int s0 = csr_src[i + 0];
      int s1 = csr_src[i + 1];
      const uint4* pa = (const uint4*)(eaperm + (size_t)i * 8);
      uint4 a0 = pa[0], a1 = pa[1];
      uint4 b0 = pa[2], b1 = pa[3];
      float h0 = (lane < 48) ? bf1(hbf[(size_t)s0 * 48 + lane]) : 0.f;
      float h1 = (lane < 48) ? bf1(hbf[(size_t)s1 * 48 + lane]) : 0.f;
      float ml0 = DOTBF(a0, a1);
      float ml1 = DOTBF(b0, b1);
      float m0 = fmaxf(h0 + ml0, 0.f) + EPS_MSG;
      float m1 = fmaxf(h1 + ml1, 0.f) + EPS_MSG;
      float ex0 = __expf(m0);
      float ex1 = __expf(m1);
      den += ex0 + ex1;
      num += ex0 * m0 + ex1 * m1;
    }
    for (; i < t; i++) {
      int s = csr_src[i];
      const uint4* pa = (const uint4*)(eaperm + (size_t)i * 8);
      uint4 a0 = pa[0], a1 = pa[1];
      float hv = (lane < 48) ? bf1(hbf[(size_t)s * 48 + lane]) : 0.f;
      float ml = DOTBF(a0, a1);
      float m  = fmaxf(hv + ml, 0.f) + EPS_MSG;
      float ex = __expf(m);
      den += ex; num += ex * m;
    }
  } else {
    for (; i < t; i++) {
      int s = csr_src[i];
      const float4* p = (const float4*)(ea + (size_t)csr_eid[i] * 16);
      float4 a0 = p[0], a1 = p[1], a2 = p[2], a3 = p[3];
      float hv = (lane < 48) ? h[(size_t)s * 48 + lane] : 0.f;
      float ml = EDGE_DOT(a0, a1, a2, a3);
      float m  = fmaxf(hv + ml, 0.f) + EPS_MSG;
      float ex = __expf(m);
      den += ex; num += ex * m;
    }
  }
  if (lane < 48)
    out[(size_t)node * 48 + lane] = hself + num / (den + 1e-16f);
}

// ---- GENConv agg d=32: half-wave/node; bf16 attrs + bf16 h-gather -----------
template<bool PERM>
__global__ void k_agg32(const u32* __restrict__ rowptr, const int* __restrict__ csr_src,
                        const int* __restrict__ csr_eid, const u32* __restrict__ eaperm,
                        const float* __restrict__ ea,
                        const float* __restrict__ we, const float* __restrict__ be,
                        const float* __restrict__ h, const u16* __restrict__ hbf,
                        float* __restrict__ out, int n) {
  int c    = threadIdx.x & 31;
  int node = (blockIdx.x * blockDim.x + threadIdx.x) >> 5;
  if (node >= n) return;
  float wc[16];
#pragma unroll
  for (int k = 0; k < 16; k++) wc[k] = we[k * 32 + c];
  float bias  = be[c];
  float hself = h[(size_t)node * 32 + c];
  u32 b = rowptr[node], t = rowptr[node + 1];
  float den = 0.f, num = 0.f;
  u32 i = b;
  if (PERM) {
    for (; i + 2 <= t; i += 2) {
      int s0 = csr_src[i + 0];
      int s1 = csr_src[i + 1];
      const uint4* pa = (const uint4*)(eaperm + (size_t)i * 8);
      uint4 a0 = pa[0], a1 = pa[1];
      uint4 b0 = pa[2], b1 = pa[3];
      float h0 = bf1(hbf[(size_t)s0 * 32 + c]);
      float h1 = bf1(hbf[(size_t)s1 * 32 + c]);
      float ml0 = DOTBF(a0, a1);
      float ml1 = DOTBF(b0, b1);
      float m0 = fmaxf(h0 + ml0, 0.f) + EPS_MSG;
      float m1 = fmaxf(h1 + ml1, 0.f) + EPS_MSG;
      float ex0 = __expf(m0);
      float ex1 = __expf(m1);
      den += ex0 + ex1;
      num += ex0 * m0 + ex1 * m1;
    }
    for (; i < t; i++) {
      int s = csr_src[i];
      const uint4* pa = (const uint4*)(eaperm + (size_t)i * 8);
      uint4 a0 = pa[0], a1 = pa[1];
      float hv = bf1(hbf[(size_t)s * 32 + c]);
      float ml = DOTBF(a0, a1);
      float m  = fmaxf(hv + ml, 0.f) + EPS_MSG;
      float ex = __expf(m);
      den += ex; num += ex * m;
    }
  } else {
    for (; i < t; i++) {
      int s = csr_src[i];
      const float4* p = (const float4*)(ea + (size_t)csr_eid[i] * 16);
      float4 a0 = p[0], a1 = p[1], a2 = p[2], a3 = p[3];
      float hv = h[(size_t)s * 32 + c];
      float ml = EDGE_DOT(a0, a1, a2, a3);
      float m  = fmaxf(hv + ml, 0.f) + EPS_MSG;
      float ex = __expf(m);
      den += ex; num += ex * m;
    }
  }
  out[(size_t)node * 32 + c] = hself + num / (den + 1e-16f);
}

// ---- zt = X@W1 + B1 (split panels) + per-block BN-stat partials -------------
template<int D>
__global__ void k_ztstats(const float* __restrict__ X, const float* __restrict__ W,
                          const float* __restrict__ B, float* __restrict__ Z1,
                          float* __restrict__ Z2, float* __restrict__ partial, int n) {
  __shared__ float Wl[D * 2 * D];
  __shared__ float Bl[2 * D];
  __shared__ float red[4][4 * D];
  for (int t = threadIdx.x; t < D * 2 * D; t += blockDim.x) Wl[t] = W[t];
  for (int t = threadIdx.x; t < 2 * D; t += blockDim.x) Bl[t] = B[t];
  __syncthreads();
  int i = blockIdx.x * blockDim.x + threadIdx.x;
  bool act = (i < n);
  float acc[2 * D];
#pragma unroll
  for (int c = 0; c < 2 * D; c++) acc[c] = 0.f;
  if (act) {
#pragma unroll
    for (int c = 0; c < 2 * D; c++) acc[c] = Bl[c];
    const float4* xp = (const float4*)(X + (size_t)i * D);
    for (int q = 0; q < D / 4; q++) {
      float4 v = xp[q];
#pragma unroll
      for (int c = 0; c < 2 * D; c++) acc[c] += v.x * Wl[(4 * q + 0) * 2 * D + c];
#pragma unroll
      for (int c = 0; c < 2 * D; c++) acc[c] += v.y * Wl[(4 * q + 1) * 2 * D + c];
#pragma unroll
      for (int c = 0; c < 2 * D; c++) acc[c] += v.z * Wl[(4 * q + 2) * 2 * D + c];
#pragma unroll
      for (int c = 0; c < 2 * D; c++) acc[c] += v.w * Wl[(4 * q + 3) * 2 * D + c];
    }
    float* z1 = Z1 + (size_t)i * D;
    float* z2 = Z2 + (size_t)i * D;
#pragma unroll
    for (int c = 0; c < D; c++) { z1[c] = acc[c]; z2[c] = acc[D + c]; }
  } else {
#pragma unroll
    for (int c = 0; c < 2 * D; c++) acc[c] = 0.f;
  }
  int lane = threadIdx.x & 63;
  int wv   = threadIdx.x >> 6;
#pragma unroll
  for (int c = 0; c < 2 * D; c++) {
    float v = acc[c], v2 = v * v;
#pragma unroll
    for (int o = 32; o; o >>= 1) { v += __shfl_xor(v, o); v2 += __shfl_xor(v2, o); }
    if (lane == 0) { red[wv][c] = v; red[wv][2 * D + c] = v2; }
  }
  __syncthreads();
  if (threadIdx.x < 4 * D) {
    float s = red[0][threadIdx.x] + red[1][threadIdx.x] +
              red[2][threadIdx.x] + red[3][threadIdx.x];
    partial[(size_t)blockIdx.x * 4 * D + threadIdx.x] = s;
  }
}

__global__ void k_bnfin(const float* __restrict__ partial, float* __restrict__ stats,
                        int nb, int m) {
  int c = blockIdx.x * blockDim.x + threadIdx.x;
  if (c >= m) return;
  float s = 0.f;
  for (int b = 0; b < nb; b++) s += partial[(size_t)b * m + c];
  stats[c] = s;
}

// ---- BN -> relu -> @W2+b2 -> relu -> @Ws(+Bs); optional bf16 shadow out -----
template<int D, int DD, int O, bool ADDBS, bool WBF>
__global__ void k_mlp_lin(const float* __restrict__ ztA, const float* __restrict__ ztB,
                          const float* __restrict__ stats,
                          const float* __restrict__ G, const float* __restrict__ BE,
                          const float* __restrict__ W2, const float* __restrict__ B2,
                          const float* __restrict__ Wsa, const float* __restrict__ Wsb,
                          const float* __restrict__ Bs,
                          float* __restrict__ out, u16* __restrict__ outbf,
                          float invN, int n) {
  __shared__ float Wl[DD * D];
  __shared__ float Ws[D * O];
  __shared__ float Bl[D];
  __shared__ float Bsl[O];
  __shared__ float sc[DD], sh[DD];
  for (int t = threadIdx.x; t < DD * D; t += blockDim.x) Wl[t] = W2[t];
  if (Wsb == nullptr) {
    for (int t = threadIdx.x; t < D * O; t += blockDim.x) Ws[t] = Wsa[t];
  } else {
    for (int t = threadIdx.x; t < D * O; t += blockDim.x) {
      int k = t / O, o = t % O;
      Ws[t] = (o < O / 2) ? Wsa[k * (O / 2) + o] : Wsb[k * (O / 2) + (o - O / 2)];
    }
  }
  if (threadIdx.x < D) Bl[threadIdx.x] = B2[threadIdx.x];
  if (threadIdx.x < O) Bsl[threadIdx.x] = ADDBS ? Bs[threadIdx.x] : 0.f;
  if (threadIdx.x < DD) {
    int c   = threadIdx.x;
    float m = stats[c] * invN;
    float v = stats[DD + c] * invN - m * m;
    float s = G[c] * rsqrtf(v + BN_EPS);
    sc[c] = s; sh[c] = BE[c] - m * s;
  }
  __syncthreads();
  int i = blockIdx.x * blockDim.x + threadIdx.x;
  if (i >= n) return;
  float y[D];
#pragma unroll
  for (int c = 0; c < D; c++) y[c] = Bl[c];
  const float* a = ztA + (size_t)i * D;
  const float* b = ztB + (size_t)i * D;
  for (int k = 0; k < D; k++) {
    float z = fmaxf(a[k] * sc[k] + sh[k], 0.f);
#pragma unroll
    for (int c = 0; c < D; c++) y[c] += z * Wl[k * D + c];
  }
  for (int k = D; k < DD; k++) {
    float z = fmaxf(b[k - D] * sc[k] + sh[k], 0.f);
#pragma unroll
    for (int c = 0; c < D; c++) y[c] += z * Wl[k * D + c];
  }
  float acc[O];
#pragma unroll
  for (int o = 0; o < O; o++) acc[o] = Bsl[o];
#pragma unroll
  for (int k = 0; k < D; k++) {
    float z = fmaxf(y[k], 0.f);
#pragma unroll
    for (int o = 0; o < O; o++) acc[o] += z * Ws[k * O + o];
  }
  float* yo = out + (size_t)i * O;
#pragma unroll
  for (int o = 0; o < O; o++) yo[o] = acc[o];
  if (WBF) {
    u16* yb = outbf + (size_t)i * O;
#pragma unroll
    for (int o = 0; o < O; o++) yb[o] = f2bf(acc[o]);
  }
}

// ---- scale head outputs by dinv ---------------------------------------------
__global__ void k_scale(const float* __restrict__ yz, const float* __restrict__ dinv,
                        float* __restrict__ yzd, int n) {
  int idx = blockIdx.x * blockDim.x + threadIdx.x;
  if (idx >= n * 32) return;
  yzd[idx] = yz[idx] * dinv[idx >> 5];
}

// ---- GCN heads: CSR gather of pre-scaled rows, chunk-2, fused store ---------
__global__ void k_gcn(const u32* __restrict__ rowptr, const int* __restrict__ csr_src,
                      const float* __restrict__ yzd, const float* __restrict__ dinv,
                      const float* __restrict__ bmu, const float* __restrict__ bls,
                      float* __restrict__ out, int n) {
  int c    = threadIdx.x & 31;
  int node = (blockIdx.x * blockDim.x + threadIdx.x) >> 5;
  if (node >= n) return;
  u32 b = rowptr[node], t = rowptr[node + 1];
  float acc = 0.f;
  u32 i = b;
  for (; i + 2 <= t; i += 2) {
    int s0 = csr_src[i];
    int s1 = csr_src[i + 1];
    float y0 = yzd[(size_t)s0 * 32 + c];
    float y1 = yzd[(size_t)s1 * 32 + c];
    acc += y0 + y1;
  }
  if (i < t) acc += yzd[(size_t)csr_src[i] * 32 + c];
  float dv  = dinv[node];
  float val = (acc + yzd[(size_t)node * 32 + c]) * dv +
              ((c < 16) ? bmu[c] : bls[c - 16]);
  if (c < 16) out[(size_t)node * 16 + c] = val;
  else        out[(size_t)n * 16 + (size_t)node * 16 + (c - 16)] = val;
}

extern "C" void kernel_launch(void* const* d_in, const int* in_sizes, int n_in,
                              void* d_out, int out_size, void* d_ws, size_t ws_size,
                              hipStream_t stream) {
  const float* x      = (const float*)d_in[0];
  const int*  ei      = (const int*)d_in[1];          // int32 (2,E) rows
  const float* ea     = (const float*)d_in[2];
  const float* w_src1 = (const float*)d_in[3];  const float* b_src1 = (const float*)d_in[4];
  const float* w_edge1= (const float*)d_in[5];  const float* b_edge1= (const float*)d_in[6];
  const float* w_m1a  = (const float*)d_in[7];  const float* b_m1a  = (const float*)d_in[8];
  const float* g1     = (const float*)d_in[9];  const float* be1    = (const float*)d_in[10];
  const float* w_m1b  = (const float*)d_in[11]; const float* b_m1b  = (const float*)d_in[12];
  const float* w_src2 = (const float*)d_in[13]; const float* b_src2 = (const float*)d_in[14];
  const float* w_edge2= (const float*)d_in[15]; const float* b_edge2= (const float*)d_in[16];
  const float* w_m2a  = (const float*)d_in[17]; const float* b_m2a  = (const float*)d_in[18];
  const float* g2     = (const float*)d_in[19]; const float* be2    = (const float*)d_in[20];
  const float* w_m2b  = (const float*)d_in[21]; const float* b_m2b  = (const float*)d_in[22];
  const float* w_mu   = (const float*)d_in[23]; const float* b_mu   = (const float*)d_in[24];
  const float* w_ls   = (const float*)d_in[25]; const float* b_ls   = (const float*)d_in[26];

  const int N = in_sizes[0] / 64;
  const int E = in_sizes[1] / 2;

  const int NB  = (N + 255) / 256;
  const int EB  = (E + 255) / 256;
  const int SB1 = (N + 1023) / 1024;

  float* ws     = (float*)d_ws;
  size_t N48    = (size_t)N * 48;
  float* P0     = ws;
  float* P1     = ws + N48;
  float* P2     = ws + 2 * N48;
  float* P3     = ws + 3 * N48;
  size_t o      = 4 * N48;
  u32*  rowptr  = (u32*)(ws + o);            // N+1
  u32*  cnt     = rowptr + (N + 1);          // N
  u32*  deg     = cnt + N;                   // N
  u32*  part    = deg + N;                   // 256
  float* dinv   = (float*)(part + 256);      // N
  float* stats  = dinv + N;                  // 512
  size_t po     = o + 4 * (size_t)N + 769;
  float* partial= ws + po;                   // NB*192
  size_t co     = (po + (size_t)NB * 192 + 3) & ~(size_t)3;
  int*  csr_src = (int*)(ws + co);           // E ints
  int*  csr_eid = csr_src + E;               // E ints
  size_t eo     = co + 2 * (size_t)E;        // 16B-aligned (co mult of 4, E even)
  u32*  eaperm  = (u32*)(ws + eo);           // 8E u32 (bf16-packed attrs)
  size_t ho     = eo + 8 * (size_t)E;
  u16*  hbf1    = (u16*)(ws + ho);           // N*48 u16 (= 24N floats)
  size_t h2o    = ho + 24 * (size_t)N;
  u16*  hbf2    = (u16*)(ws + h2o);          // N*32 u16 (= 16N floats)
  size_t needB  = (h2o + 16 * (size_t)N + 16) * sizeof(float);
  const bool PERM = (ws_size >= needB);

  dim3 b256(256);

  hipMemsetAsync(cnt, 0, 2 * (size_t)N * sizeof(u32), stream);

  // CSR build
  k_deg<<<EB, b256, 0, stream>>>(ei, deg, E);
  k_scan1<<<SB1, b256, 0, stream>>>(deg, rowptr, part, N);
  k_scan2<<<1, 64, 0, stream>>>(part, SB1);
  k_scan3<<<NB, b256, 0, stream>>>(rowptr, part, N, E);
  k_slots<<<EB, b256, 0, stream>>>(ei, rowptr, cnt, csr_src, csr_eid, E);
  if (PERM) k_gather<<<EB, b256, 0, stream>>>(csr_eid, ea, eaperm, E);
  k_dinv<<<NB, b256, 0, stream>>>(deg, dinv, N);

  // ---- GENConv 1 (64 -> 48) ----
  if (PERM) k_lin<64, 48, true><<<NB, b256, 0, stream>>>(x, w_src1, b_src1, P0, hbf1, 48, N);
  else      k_lin<64, 48, false><<<NB, b256, 0, stream>>>(x, w_src1, b_src1, P0, nullptr, 48, N);
  if (PERM) k_agg48<true><<<(N * 64 + 255) / 256, b256, 0, stream>>>(rowptr, csr_src,
                       csr_eid, eaperm, ea, w_edge1, b_edge1, P0, hbf1, P3, N);
  else      k_agg48<false><<<(N * 64 + 255) / 256, b256, 0, stream>>>(rowptr, csr_src,
                       csr_eid, eaperm, ea, w_edge1, b_edge1, P0, hbf1, P3, N);
  k_ztstats<48><<<NB, b256, 0, stream>>>(P3, w_m1a, b_m1a, P1, P2, partial, N);
  k_bnfin<<<1, 256, 0, stream>>>(partial, stats, NB, 192);
  if (PERM)
    k_mlp_lin<48, 96, 32, true, true><<<NB, b256, 0, stream>>>(P1, P2, stats, g1, be1,
                       w_m1b, b_m1b, w_src2, nullptr, b_src2, P0, hbf2, 1.0f / (float)N, N);
  else
    k_mlp_lin<48, 96, 32, true, false><<<NB, b256, 0, stream>>>(P1, P2, stats, g1, be1,
                       w_m1b, b_m1b, w_src2, nullptr, b_src2, P0, nullptr, 1.0f / (float)N, N);

  // ---- GENConv 2 (48 -> 32) ----
  if (PERM) k_agg32<true><<<(N * 32 + 255) / 256, b256, 0, stream>>>(rowptr, csr_src,
                       csr_eid, eaperm, ea, w_edge2, b_edge2, P0, hbf2, P3, N);
  else      k_agg32<false><<<(N * 32 + 255) / 256, b256, 0, stream>>>(rowptr, csr_src,
                       csr_eid, eaperm, ea, w_edge2, b_edge2, P0, hbf2, P3, N);
  k_ztstats<32><<<NB, b256, 0, stream>>>(P3, w_m2a, b_m2a, P1, P2, partial, N);
  k_bnfin<<<1, 256, 0, stream>>>(partial, stats + 256, NB, 128);
  k_mlp_lin<32, 64, 32, false, false><<<NB, b256, 0, stream>>>(P1, P2, stats + 256, g2, be2,
                       w_m2b, b_m2b, w_mu, w_ls, nullptr, P0, nullptr, 1.0f / (float)N, N);

  // ---- GCN heads: pre-scale rows by dinv, then gather ----
  k_scale<<<(N * 32 + 255) / 256, b256, 0, stream>>>(P0, dinv, P3, N);
  k_gcn<<<(N * 32 + 255) / 256, b256, 0, stream>>>(rowptr, csr_src, P3, dinv,
                                                   b_mu, b_ls, (float*)d_out, N);
}

// Round 17
// 975.612 us; speedup vs baseline: 1.3414x; 1.0338x over previous
//
#include <hip/hip_runtime.h>
#include <hip/hip_bf16.h>

typedef unsigned int u32;
typedef unsigned short u16;
typedef float f2 __attribute__((ext_vector_type(2)));

#define EPS_MSG 1e-7f
#define BN_EPS  1e-5f

__device__ __forceinline__ u16 f2bf(float f) {          // round-to-nearest-even
  u32 u = __float_as_uint(f);
  return (u16)((u + 0x7FFFu + ((u >> 16) & 1u)) >> 16);
}
__device__ __forceinline__ float bflo(u32 v) { return __uint_as_float(v << 16); }
__device__ __forceinline__ float bfhi(u32 v) { return __uint_as_float(v & 0xFFFF0000u); }
__device__ __forceinline__ float bf1(u16 v)  { return __uint_as_float(((u32)v) << 16); }

// 8 MACs as 4 packed-f32 FMAs (v_pk_fma_f32 on gfx90a+)
__device__ __forceinline__ void dot4(f2& acc, uint4 v, const f2* w) {
  f2 p;
  p.x = bflo(v.x); p.y = bfhi(v.x); acc = __builtin_elementwise_fma(p, w[0], acc);
  p.x = bflo(v.y); p.y = bfhi(v.y); acc = __builtin_elementwise_fma(p, w[1], acc);
  p.x = bflo(v.z); p.y = bfhi(v.z); acc = __builtin_elementwise_fma(p, w[2], acc);
  p.x = bflo(v.w); p.y = bfhi(v.w); acc = __builtin_elementwise_fma(p, w[3], acc);
}

#define EDGE_DOT(A0,A1,A2,A3) (bias + \
  A0.x * wc[0]  + A0.y * wc[1]  + A0.z * wc[2]  + A0.w * wc[3] + \
  A1.x * wc[4]  + A1.y * wc[5]  + A1.z * wc[6]  + A1.w * wc[7] + \
  A2.x * wc[8]  + A2.y * wc[9]  + A2.z * wc[10] + A2.w * wc[11] + \
  A3.x * wc[12] + A3.y * wc[13] + A3.z * wc[14] + A3.w * wc[15])

// ---- small linear: Y[i*ldY+c] = X[i,:]·W[:,c] + B[c]; optional bf16 shadow --
template<int I, int O, bool WBF>
__global__ void k_lin(const float* __restrict__ X, const float* __restrict__ W,
                      const float* __restrict__ B, float* __restrict__ Y,
                      u16* __restrict__ Ybf, int ldY, int n) {
  __shared__ float Wl[I * O];
  __shared__ float Bl[O];
  for (int t = threadIdx.x; t < I * O; t += blockDim.x) Wl[t] = W[t];
  if (threadIdx.x < O) Bl[threadIdx.x] = B[threadIdx.x];
  __syncthreads();
  int i = blockIdx.x * blockDim.x + threadIdx.x;
  if (i >= n) return;
  float acc[O];
#pragma unroll
  for (int c = 0; c < O; c++) acc[c] = Bl[c];
  const float4* xp = (const float4*)(X + (size_t)i * I);
  for (int q = 0; q < I / 4; q++) {
    float4 v = xp[q];
#pragma unroll
    for (int c = 0; c < O; c++) acc[c] += v.x * Wl[(4 * q + 0) * O + c];
#pragma unroll
    for (int c = 0; c < O; c++) acc[c] += v.y * Wl[(4 * q + 1) * O + c];
#pragma unroll
    for (int c = 0; c < O; c++) acc[c] += v.z * Wl[(4 * q + 2) * O + c];
#pragma unroll
    for (int c = 0; c < O; c++) acc[c] += v.w * Wl[(4 * q + 3) * O + c];
  }
  float* y = Y + (size_t)i * ldY;
#pragma unroll
  for (int c = 0; c < O; c++) y[c] = acc[c];
  if (WBF) {
    u16* yb = Ybf + (size_t)i * O;
#pragma unroll
    for (int c = 0; c < O; c++) yb[c] = f2bf(acc[c]);
  }
}

// ---- CSR construction -------------------------------------------------------
__global__ void k_deg(const int* __restrict__ ei, u32* __restrict__ deg, int E) {
  int e = blockIdx.x * blockDim.x + threadIdx.x;
  if (e < E) atomicAdd(&deg[ei[E + e]], 1u);
}

__global__ void k_scan1(const u32* __restrict__ deg, u32* __restrict__ excl,
                        u32* __restrict__ part, int n) {
  __shared__ u32 sm[256];
  int t = threadIdx.x;
  int base = blockIdx.x * 1024 + t * 4;
  u32 v0 = (base + 0 < n) ? deg[base + 0] : 0u;
  u32 v1 = (base + 1 < n) ? deg[base + 1] : 0u;
  u32 v2 = (base + 2 < n) ? deg[base + 2] : 0u;
  u32 v3 = (base + 3 < n) ? deg[base + 3] : 0u;
  u32 tsum = v0 + v1 + v2 + v3;
  sm[t] = tsum;
  __syncthreads();
  for (int o = 1; o < 256; o <<= 1) {
    u32 v = (t >= o) ? sm[t - o] : 0u;
    __syncthreads();
    sm[t] += v;
    __syncthreads();
  }
  u32 tex = sm[t] - tsum;
  if (t == 255) part[blockIdx.x] = sm[255];
  if (base + 0 < n) excl[base + 0] = tex;
  if (base + 1 < n) excl[base + 1] = tex + v0;
  if (base + 2 < n) excl[base + 2] = tex + v0 + v1;
  if (base + 3 < n) excl[base + 3] = tex + v0 + v1 + v2;
}

__global__ void k_scan2(u32* __restrict__ part, int nb) {
  if (threadIdx.x == 0) {
    u32 acc = 0;
    for (int i = 0; i < nb; i++) { u32 v = part[i]; part[i] = acc; acc += v; }
  }
}

__global__ void k_scan3(u32* __restrict__ rowptr, const u32* __restrict__ part,
                        int n, int E) {
  int i = blockIdx.x * blockDim.x + threadIdx.x;
  if (i < n) rowptr[i] += part[i >> 10];
  if (i == 0) rowptr[n] = (u32)E;
}

__global__ void k_slots(const int* __restrict__ ei, const u32* __restrict__ rowptr,
                        u32* __restrict__ cnt, int* __restrict__ csr_src,
                        int* __restrict__ csr_eid, int E) {
  int e = blockIdx.x * blockDim.x + threadIdx.x;
  if (e >= E) return;
  int s = ei[e], d = ei[E + e];
  u32 slot = rowptr[d] + atomicAdd(&cnt[d], 1u);
  csr_src[slot] = s;
  csr_eid[slot] = e;
}

// slot-major attr permute, packed bf16: 32B/edge, coalesced writes
__global__ void k_gather(const int* __restrict__ csr_eid, const float* __restrict__ ea,
                         u32* __restrict__ eaperm, int E) {
  int i = blockIdx.x * blockDim.x + threadIdx.x;
  if (i >= E) return;
  int e = csr_eid[i];
  const float4* p = (const float4*)(ea + (size_t)e * 16);
  float4 a = p[0], b = p[1], c = p[2], d = p[3];
  uint4* q = (uint4*)(eaperm + (size_t)i * 8);
  uint4 w0, w1;
  w0.x = ((u32)f2bf(a.y) << 16) | f2bf(a.x);
  w0.y = ((u32)f2bf(a.w) << 16) | f2bf(a.z);
  w0.z = ((u32)f2bf(b.y) << 16) | f2bf(b.x);
  w0.w = ((u32)f2bf(b.w) << 16) | f2bf(b.z);
  w1.x = ((u32)f2bf(c.y) << 16) | f2bf(c.x);
  w1.y = ((u32)f2bf(c.w) << 16) | f2bf(c.z);
  w1.z = ((u32)f2bf(d.y) << 16) | f2bf(d.x);
  w1.w = ((u32)f2bf(d.w) << 16) | f2bf(d.z);
  q[0] = w0; q[1] = w1;
}

__global__ void k_dinv(const u32* __restrict__ deg, float* __restrict__ dinv, int n) {
  int i = blockIdx.x * blockDim.x + threadIdx.x;
  if (i < n) dinv[i] = rsqrtf((float)(deg[i] + 1u));
}

// ---- GENConv agg d=48: wave/node; pk-f32 dot, branchless lane wrap ----------
template<bool PERM>
__global__ void k_agg48(const u32* __restrict__ rowptr, const int* __restrict__ csr_src,
                        const int* __restrict__ csr_eid, const u32* __restrict__ eaperm,
                        const float* __restrict__ ea,
                        const float* __restrict__ we, const float* __restrict__ be,
                        const float* __restrict__ h, const u16* __restrict__ hbf,
                        float* __restrict__ out, int n) {
  int lane = threadIdx.x & 63;
  int cl   = (lane < 48) ? lane : lane - 48;   // lanes 48-63 duplicate ch 0-15
  int node = (blockIdx.x * blockDim.x + threadIdx.x) >> 6;
  if (node >= n) return;
  f2 wc2[8];
  float bias = be[cl];
#pragma unroll
  for (int k = 0; k < 8; k++) {
    wc2[k].x = we[(2 * k + 0) * 48 + cl];
    wc2[k].y = we[(2 * k + 1) * 48 + cl];
  }
  float hself = h[(size_t)node * 48 + cl];
  u32 b = rowptr[node], t = rowptr[node + 1];
  float den = 0.f, num = 0.f;
  u32 i = b;
  if (PERM) {
    for (; i + 2 <= t; i += 2) {
      int s0 = csr_src[i + 0];
      int s1 = csr_src[i + 1];
      const uint4* pa = (const uint4*)(eaperm + (size_t)i * 8);
      uint4 a0 = pa[0], a1 = pa[1];
      uint4 b0 = pa[2], b1 = pa[3];
      float h0 = bf1(hbf[(size_t)s0 * 48 + cl]);
      float h1 = bf1(hbf[(size_t)s1 * 48 + cl]);
      f2 ac0 = {bias, 0.f};
      f2 ac1 = {bias, 0.f};
      dot4(ac0, a0, wc2); dot4(ac0, a1, wc2 + 4);
      dot4(ac1, b0, wc2); dot4(ac1, b1, wc2 + 4);
      float m0 = fmaxf(h0 + ac0.x + ac0.y, 0.f) + EPS_MSG;
      float m1 = fmaxf(h1 + ac1.x + ac1.y, 0.f) + EPS_MSG;
      float ex0 = __expf(m0);
      float ex1 = __expf(m1);
      den += ex0 + ex1;
      num += ex0 * m0 + ex1 * m1;
    }
    for (; i < t; i++) {
      int s = csr_src[i];
      const uint4* pa = (const uint4*)(eaperm + (size_t)i * 8);
      uint4 a0 = pa[0], a1 = pa[1];
      float hv = bf1(hbf[(size_t)s * 48 + cl]);
      f2 ac = {bias, 0.f};
      dot4(ac, a0, wc2); dot4(ac, a1, wc2 + 4);
      float m  = fmaxf(hv + ac.x + ac.y, 0.f) + EPS_MSG;
      float ex = __expf(m);
      den += ex; num += ex * m;
    }
  } else {
    float wc[16];
#pragma unroll
    for (int k = 0; k < 16; k++) wc[k] = we[k * 48 + cl];
    for (; i < t; i++) {
      int s = csr_src[i];
      const float4* p = (const float4*)(ea + (size_t)csr_eid[i] * 16);
      float4 a0 = p[0], a1 = p[1], a2 = p[2], a3 = p[3];
      float hv = h[(size_t)s * 48 + cl];
      float ml = EDGE_DOT(a0, a1, a2, a3);
      float m  = fmaxf(hv + ml, 0.f) + EPS_MSG;
      float ex = __expf(m);
      den += ex; num += ex * m;
    }
  }
  if (lane < 48)
    out[(size_t)node * 48 + lane] = hself + num / (den + 1e-16f);
}

// ---- GENConv agg d=32: half-wave/node; pk-f32 dot ---------------------------
template<bool PERM>
__global__ void k_agg32(const u32* __restrict__ rowptr, const int* __restrict__ csr_src,
                        const int* __restrict__ csr_eid, const u32* __restrict__ eaperm,
                        const float* __restrict__ ea,
                        const float* __restrict__ we, const float* __restrict__ be,
                        const float* __restrict__ h, const u16* __restrict__ hbf,
                        float* __restrict__ out, int n) {
  int c    = threadIdx.x & 31;
  int node = (blockIdx.x * blockDim.x + threadIdx.x) >> 5;
  if (node >= n) return;
  f2 wc2[8];
  float bias = be[c];
#pragma unroll
  for (int k = 0; k < 8; k++) {
    wc2[k].x = we[(2 * k + 0) * 32 + c];
    wc2[k].y = we[(2 * k + 1) * 32 + c];
  }
  float hself = h[(size_t)node * 32 + c];
  u32 b = rowptr[node], t = rowptr[node + 1];
  float den = 0.f, num = 0.f;
  u32 i = b;
  if (PERM) {
    for (; i + 2 <= t; i += 2) {
      int s0 = csr_src[i + 0];
      int s1 = csr_src[i + 1];
      const uint4* pa = (const uint4*)(eaperm + (size_t)i * 8);
      uint4 a0 = pa[0], a1 = pa[1];
      uint4 b0 = pa[2], b1 = pa[3];
      float h0 = bf1(hbf[(size_t)s0 * 32 + c]);
      float h1 = bf1(hbf[(size_t)s1 * 32 + c]);
      f2 ac0 = {bias, 0.f};
      f2 ac1 = {bias, 0.f};
      dot4(ac0, a0, wc2); dot4(ac0, a1, wc2 + 4);
      dot4(ac1, b0, wc2); dot4(ac1, b1, wc2 + 4);
      float m0 = fmaxf(h0 + ac0.x + ac0.y, 0.f) + EPS_MSG;
      float m1 = fmaxf(h1 + ac1.x + ac1.y, 0.f) + EPS_MSG;
      float ex0 = __expf(m0);
      float ex1 = __expf(m1);
      den += ex0 + ex1;
      num += ex0 * m0 + ex1 * m1;
    }
    for (; i < t; i++) {
      int s = csr_src[i];
      const uint4* pa = (const uint4*)(eaperm + (size_t)i * 8);
      uint4 a0 = pa[0], a1 = pa[1];
      float hv = bf1(hbf[(size_t)s * 32 + c]);
      f2 ac = {bias, 0.f};
      dot4(ac, a0, wc2); dot4(ac, a1, wc2 + 4);
      float m  = fmaxf(hv + ac.x + ac.y, 0.f) + EPS_MSG;
      float ex = __expf(m);
      den += ex; num += ex * m;
    }
  } else {
    float wc[16];
#pragma unroll
    for (int k = 0; k < 16; k++) wc[k] = we[k * 32 + c];
    for (; i < t; i++) {
      int s = csr_src[i];
      const float4* p = (const float4*)(ea + (size_t)csr_eid[i] * 16);
      float4 a0 = p[0], a1 = p[1], a2 = p[2], a3 = p[3];
      float hv = h[(size_t)s * 32 + c];
      float ml = EDGE_DOT(a0, a1, a2, a3);
      float m  = fmaxf(hv + ml, 0.f) + EPS_MSG;
      float ex = __expf(m);
      den += ex; num += ex * m;
    }
  }
  out[(size_t)node * 32 + c] = hself + num / (den + 1e-16f);
}

// ---- zt = X@W1 + B1 (split panels) + per-block BN-stat partials -------------
template<int D>
__global__ void k_ztstats(const float* __restrict__ X, const float* __restrict__ W,
                          const float* __restrict__ B, float* __restrict__ Z1,
                          float* __restrict__ Z2, float* __restrict__ partial, int n) {
  __shared__ float Wl[D * 2 * D];
  __shared__ float Bl[2 * D];
  __shared__ float red[4][4 * D];
  for (int t = threadIdx.x; t < D * 2 * D; t += blockDim.x) Wl[t] = W[t];
  for (int t = threadIdx.x; t < 2 * D; t += blockDim.x) Bl[t] = B[t];
  __syncthreads();
  int i = blockIdx.x * blockDim.x + threadIdx.x;
  bool act = (i < n);
  float acc[2 * D];
#pragma unroll
  for (int c = 0; c < 2 * D; c++) acc[c] = 0.f;
  if (act) {
#pragma unroll
    for (int c = 0; c < 2 * D; c++) acc[c] = Bl[c];
    const float4* xp = (const float4*)(X + (size_t)i * D);
    for (int q = 0; q < D / 4; q++) {
      float4 v = xp[q];
#pragma unroll
      for (int c = 0; c < 2 * D; c++) acc[c] += v.x * Wl[(4 * q + 0) * 2 * D + c];
#pragma unroll
      for (int c = 0; c < 2 * D; c++) acc[c] += v.y * Wl[(4 * q + 1) * 2 * D + c];
#pragma unroll
      for (int c = 0; c < 2 * D; c++) acc[c] += v.z * Wl[(4 * q + 2) * 2 * D + c];
#pragma unroll
      for (int c = 0; c < 2 * D; c++) acc[c] += v.w * Wl[(4 * q + 3) * 2 * D + c];
    }
    float* z1 = Z1 + (size_t)i * D;
    float* z2 = Z2 + (size_t)i * D;
#pragma unroll
    for (int c = 0; c < D; c++) { z1[c] = acc[c]; z2[c] = acc[D + c]; }
  } else {
#pragma unroll
    for (int c = 0; c < 2 * D; c++) acc[c] = 0.f;
  }
  int lane = threadIdx.x & 63;
  int wv   = threadIdx.x >> 6;
#pragma unroll
  for (int c = 0; c < 2 * D; c++) {
    float v = acc[c], v2 = v * v;
#pragma unroll
    for (int o = 32; o; o >>= 1) { v += __shfl_xor(v, o); v2 += __shfl_xor(v2, o); }
    if (lane == 0) { red[wv][c] = v; red[wv][2 * D + c] = v2; }
  }
  __syncthreads();
  if (threadIdx.x < 4 * D) {
    float s = red[0][threadIdx.x] + red[1][threadIdx.x] +
              red[2][threadIdx.x] + red[3][threadIdx.x];
    partial[(size_t)blockIdx.x * 4 * D + threadIdx.x] = s;
  }
}

__global__ void k_bnfin(const float* __restrict__ partial, float* __restrict__ stats,
                        int nb, int m) {
  int c = blockIdx.x * blockDim.x + threadIdx.x;
  if (c >= m) return;
  float s = 0.f;
  for (int b = 0; b < nb; b++) s += partial[(size_t)b * m + c];
  stats[c] = s;
}

// ---- BN -> relu -> @W2+b2 -> relu -> @Ws(+Bs); optional bf16 / dinv-scale ---
template<int D, int DD, int O, bool ADDBS, bool WBF, bool SCALE>
__global__ void k_mlp_lin(const float* __restrict__ ztA, const float* __restrict__ ztB,
                          const float* __restrict__ stats,
                          const float* __restrict__ G, const float* __restrict__ BE,
                          const float* __restrict__ W2, const float* __restrict__ B2,
                          const float* __restrict__ Wsa, const float* __restrict__ Wsb,
                          const float* __restrict__ Bs, const float* __restrict__ dinv,
                          float* __restrict__ out, u16* __restrict__ outbf,
                          float invN, int n) {
  __shared__ float Wl[DD * D];
  __shared__ float Ws[D * O];
  __shared__ float Bl[D];
  __shared__ float Bsl[O];
  __shared__ float sc[DD], sh[DD];
  for (int t = threadIdx.x; t < DD * D; t += blockDim.x) Wl[t] = W2[t];
  if (Wsb == nullptr) {
    for (int t = threadIdx.x; t < D * O; t += blockDim.x) Ws[t] = Wsa[t];
  } else {
    for (int t = threadIdx.x; t < D * O; t += blockDim.x) {
      int k = t / O, o = t % O;
      Ws[t] = (o < O / 2) ? Wsa[k * (O / 2) + o] : Wsb[k * (O / 2) + (o - O / 2)];
    }
  }
  if (threadIdx.x < D) Bl[threadIdx.x] = B2[threadIdx.x];
  if (threadIdx.x < O) Bsl[threadIdx.x] = ADDBS ? Bs[threadIdx.x] : 0.f;
  if (threadIdx.x < DD) {
    int c   = threadIdx.x;
    float m = stats[c] * invN;
    float v = stats[DD + c] * invN - m * m;
    float s = G[c] * rsqrtf(v + BN_EPS);
    sc[c] = s; sh[c] = BE[c] - m * s;
  }
  __syncthreads();
  int i = blockIdx.x * blockDim.x + threadIdx.x;
  if (i >= n) return;
  float y[D];
#pragma unroll
  for (int c = 0; c < D; c++) y[c] = Bl[c];
  const float* a = ztA + (size_t)i * D;
  const float* b = ztB + (size_t)i * D;
  for (int k = 0; k < D; k++) {
    float z = fmaxf(a[k] * sc[k] + sh[k], 0.f);
#pragma unroll
    for (int c = 0; c < D; c++) y[c] += z * Wl[k * D + c];
  }
  for (int k = D; k < DD; k++) {
    float z = fmaxf(b[k - D] * sc[k] + sh[k], 0.f);
#pragma unroll
    for (int c = 0; c < D; c++) y[c] += z * Wl[k * D + c];
  }
  float acc[O];
#pragma unroll
  for (int o = 0; o < O; o++) acc[o] = Bsl[o];
#pragma unroll
  for (int k = 0; k < D; k++) {
    float z = fmaxf(y[k], 0.f);
#pragma unroll
    for (int o = 0; o < O; o++) acc[o] += z * Ws[k * O + o];
  }
  float dv = SCALE ? dinv[i] : 1.f;
  float* yo = out + (size_t)i * O;
#pragma unroll
  for (int o = 0; o < O; o++) yo[o] = SCALE ? acc[o] * dv : acc[o];
  if (WBF) {
    u16* yb = outbf + (size_t)i * O;
#pragma unroll
    for (int o = 0; o < O; o++) yb[o] = f2bf(acc[o]);
  }
}

// ---- GCN heads: CSR gather of pre-scaled rows, chunk-2, fused store ---------
__global__ void k_gcn(const u32* __restrict__ rowptr, const int* __restrict__ csr_src,
                      const float* __restrict__ yzd, const float* __restrict__ dinv,
                      const float* __restrict__ bmu, const float* __restrict__ bls,
                      float* __restrict__ out, int n) {
  int c    = threadIdx.x & 31;
  int node = (blockIdx.x * blockDim.x + threadIdx.x) >> 5;
  if (node >= n) return;
  u32 b = rowptr[node], t = rowptr[node + 1];
  float acc = 0.f;
  u32 i = b;
  for (; i + 2 <= t; i += 2) {
    int s0 = csr_src[i];
    int s1 = csr_src[i + 1];
    float y0 = yzd[(size_t)s0 * 32 + c];
    float y1 = yzd[(size_t)s1 * 32 + c];
    acc += y0 + y1;
  }
  if (i < t) acc += yzd[(size_t)csr_src[i] * 32 + c];
  float dv  = dinv[node];
  float val = (acc + yzd[(size_t)node * 32 + c]) * dv +
              ((c < 16) ? bmu[c] : bls[c - 16]);
  if (c < 16) out[(size_t)node * 16 + c] = val;
  else        out[(size_t)n * 16 + (size_t)node * 16 + (c - 16)] = val;
}

extern "C" void kernel_launch(void* const* d_in, const int* in_sizes, int n_in,
                              void* d_out, int out_size, void* d_ws, size_t ws_size,
                              hipStream_t stream) {
  const float* x      = (const float*)d_in[0];
  const int*  ei      = (const int*)d_in[1];          // int32 (2,E) rows
  const float* ea     = (const float*)d_in[2];
  const float* w_src1 = (const float*)d_in[3];  const float* b_src1 = (const float*)d_in[4];
  const float* w_edge1= (const float*)d_in[5];  const float* b_edge1= (const float*)d_in[6];
  const float* w_m1a  = (const float*)d_in[7];  const float* b_m1a  = (const float*)d_in[8];
  const float* g1     = (const float*)d_in[9];  const float* be1    = (const float*)d_in[10];
  const float* w_m1b  = (const float*)d_in[11]; const float* b_m1b  = (const float*)d_in[12];
  const float* w_src2 = (const float*)d_in[13]; const float* b_src2 = (const float*)d_in[14];
  const float* w_edge2= (const float*)d_in[15]; const float* b_edge2= (const float*)d_in[16];
  const float* w_m2a  = (const float*)d_in[17]; const float* b_m2a  = (const float*)d_in[18];
  const float* g2     = (const float*)d_in[19]; const float* be2    = (const float*)d_in[20];
  const float* w_m2b  = (const float*)d_in[21]; const float* b_m2b  = (const float*)d_in[22];
  const float* w_mu   = (const float*)d_in[23]; const float* b_mu   = (const float*)d_in[24];
  const float* w_ls   = (const float*)d_in[25]; const float* b_ls   = (const float*)d_in[26];

  const int N = in_sizes[0] / 64;
  const int E = in_sizes[1] / 2;

  const int NB  = (N + 255) / 256;
  const int EB  = (E + 255) / 256;
  const int SB1 = (N + 1023) / 1024;

  float* ws     = (float*)d_ws;
  size_t N48    = (size_t)N * 48;
  float* P0     = ws;
  float* P1     = ws + N48;
  float* P2     = ws + 2 * N48;
  float* P3     = ws + 3 * N48;
  size_t o      = 4 * N48;
  u32*  rowptr  = (u32*)(ws + o);            // N+1
  u32*  cnt     = rowptr + (N + 1);          // N
  u32*  deg     = cnt + N;                   // N
  u32*  part    = deg + N;                   // 256
  float* dinv   = (float*)(part + 256);      // N
  float* stats  = dinv + N;                  // 512
  size_t po     = o + 4 * (size_t)N + 769;
  float* partial= ws + po;                   // NB*192
  size_t co     = (po + (size_t)NB * 192 + 3) & ~(size_t)3;
  int*  csr_src = (int*)(ws + co);           // E ints
  int*  csr_eid = csr_src + E;               // E ints
  size_t eo     = co + 2 * (size_t)E;        // 16B-aligned
  u32*  eaperm  = (u32*)(ws + eo);           // 8E u32 (bf16-packed attrs)
  size_t ho     = eo + 8 * (size_t)E;
  u16*  hbf1    = (u16*)(ws + ho);           // N*48 u16
  size_t h2o    = ho + 24 * (size_t)N;
  u16*  hbf2    = (u16*)(ws + h2o);          // N*32 u16
  size_t needB  = (h2o + 16 * (size_t)N + 16) * sizeof(float);
  const bool PERM = (ws_size >= needB);

  dim3 b256(256);

  hipMemsetAsync(cnt, 0, 2 * (size_t)N * sizeof(u32), stream);

  // CSR build
  k_deg<<<EB, b256, 0, stream>>>(ei, deg, E);
  k_scan1<<<SB1, b256, 0, stream>>>(deg, rowptr, part, N);
  k_scan2<<<1, 64, 0, stream>>>(part, SB1);
  k_scan3<<<NB, b256, 0, stream>>>(rowptr, part, N, E);
  k_slots<<<EB, b256, 0, stream>>>(ei, rowptr, cnt, csr_src, csr_eid, E);
  if (PERM) k_gather<<<EB, b256, 0, stream>>>(csr_eid, ea, eaperm, E);
  k_dinv<<<NB, b256, 0, stream>>>(deg, dinv, N);

  // ---- GENConv 1 (64 -> 48) ----
  if (PERM) k_lin<64, 48, true><<<NB, b256, 0, stream>>>(x, w_src1, b_src1, P0, hbf1, 48, N);
  else      k_lin<64, 48, false><<<NB, b256, 0, stream>>>(x, w_src1, b_src1, P0, nullptr, 48, N);
  if (PERM) k_agg48<true><<<(N * 64 + 255) / 256, b256, 0, stream>>>(rowptr, csr_src,
                       csr_eid, eaperm, ea, w_edge1, b_edge1, P0, hbf1, P3, N);
  else      k_agg48<false><<<(N * 64 + 255) / 256, b256, 0, stream>>>(rowptr, csr_src,
                       csr_eid, eaperm, ea, w_edge1, b_edge1, P0, hbf1, P3, N);
  k_ztstats<48><<<NB, b256, 0, stream>>>(P3, w_m1a, b_m1a, P1, P2, partial, N);
  k_bnfin<<<1, 256, 0, stream>>>(partial, stats, NB, 192);
  if (PERM)
    k_mlp_lin<48, 96, 32, true, true, false><<<NB, b256, 0, stream>>>(P1, P2, stats, g1, be1,
                       w_m1b, b_m1b, w_src2, nullptr, b_src2, nullptr, P0, hbf2,
                       1.0f / (float)N, N);
  else
    k_mlp_lin<48, 96, 32, true, false, false><<<NB, b256, 0, stream>>>(P1, P2, stats, g1, be1,
                       w_m1b, b_m1b, w_src2, nullptr, b_src2, nullptr, P0, nullptr,
                       1.0f / (float)N, N);

  // ---- GENConv 2 (48 -> 32) ----
  if (PERM) k_agg32<true><<<(N * 32 + 255) / 256, b256, 0, stream>>>(rowptr, csr_src,
                       csr_eid, eaperm, ea, w_edge2, b_edge2, P0, hbf2, P3, N);
  else      k_agg32<false><<<(N * 32 + 255) / 256, b256, 0, stream>>>(rowptr, csr_src,
                       csr_eid, eaperm, ea, w_edge2, b_edge2, P0, hbf2, P3, N);
  k_ztstats<32><<<NB, b256, 0, stream>>>(P3, w_m2a, b_m2a, P1, P2, partial, N);
  k_bnfin<<<1, 256, 0, stream>>>(partial, stats + 256, NB, 128);
  // fused dinv scale: writes yzd = (heads output)·dinv[i] directly
  k_mlp_lin<32, 64, 32, false, false, true><<<NB, b256, 0, stream>>>(P1, P2, stats + 256,
                       g2, be2, w_m2b, b_m2b, w_mu, w_ls, nullptr, dinv, P0, nullptr,
                       1.0f / (float)N, N);

  // ---- GCN heads ----
  k_gcn<<<(N * 32 + 255) / 256, b256, 0, stream>>>(rowptr, csr_src, P0, dinv,
                                                   b_mu, b_ls, (float*)d_out, N);
}

// Round 19
// 936.032 us; speedup vs baseline: 1.3981x; 1.0423x over previous
//
#include <hip/hip_runtime.h>
#include <hip/hip_bf16.h>

typedef unsigned int u32;
typedef unsigned short u16;
typedef _Float16 h2 __attribute__((ext_vector_type(2)));

#define EPS_MSG 1e-7f
#define BN_EPS  1e-5f

__device__ __forceinline__ u16 f2bf(float f) {          // round-to-nearest-even
  u32 u = __float_as_uint(f);
  return (u16)((u + 0x7FFFu + ((u >> 16) & 1u)) >> 16);
}
__device__ __forceinline__ float bf1(u16 v) { return __uint_as_float(((u32)v) << 16); }
__device__ __forceinline__ h2 u2h(u32 v) { union { u32 u; h2 h; } t; t.u = v; return t.h; }

// pack two f32 -> pk f16 pair as raw u32 (via __fp16 vector return type)
__device__ __forceinline__ u32 pkrtz(float a, float b) {
  union { __fp16 v __attribute__((ext_vector_type(2))); u32 u; } t;
  t.v = __builtin_amdgcn_cvt_pkrtz(a, b);
  return t.u;
}

// 8 f16 pairs (one uint4) dotted against packed weights via v_dot2_f32_f16
__device__ __forceinline__ float dot8(uint4 v, const u32* w, float acc) {
  acc = __builtin_amdgcn_fdot2(u2h(v.x), u2h(w[0]), acc, false);
  acc = __builtin_amdgcn_fdot2(u2h(v.y), u2h(w[1]), acc, false);
  acc = __builtin_amdgcn_fdot2(u2h(v.z), u2h(w[2]), acc, false);
  acc = __builtin_amdgcn_fdot2(u2h(v.w), u2h(w[3]), acc, false);
  return acc;
}

#define EDGE_DOT(A0,A1,A2,A3) (bias + \
  A0.x * wc[0]  + A0.y * wc[1]  + A0.z * wc[2]  + A0.w * wc[3] + \
  A1.x * wc[4]  + A1.y * wc[5]  + A1.z * wc[6]  + A1.w * wc[7] + \
  A2.x * wc[8]  + A2.y * wc[9]  + A2.z * wc[10] + A2.w * wc[11] + \
  A3.x * wc[12] + A3.y * wc[13] + A3.z * wc[14] + A3.w * wc[15])

// ---- small linear: Y[i*ldY+c] = X[i,:]·W[:,c] + B[c]; optional bf16 shadow --
template<int I, int O, bool WBF>
__global__ void k_lin(const float* __restrict__ X, const float* __restrict__ W,
                      const float* __restrict__ B, float* __restrict__ Y,
                      u16* __restrict__ Ybf, int ldY, int n) {
  __shared__ float Wl[I * O];
  __shared__ float Bl[O];
  for (int t = threadIdx.x; t < I * O; t += blockDim.x) Wl[t] = W[t];
  if (threadIdx.x < O) Bl[threadIdx.x] = B[threadIdx.x];
  __syncthreads();
  int i = blockIdx.x * blockDim.x + threadIdx.x;
  if (i >= n) return;
  float acc[O];
#pragma unroll
  for (int c = 0; c < O; c++) acc[c] = Bl[c];
  const float4* xp = (const float4*)(X + (size_t)i * I);
  for (int q = 0; q < I / 4; q++) {
    float4 v = xp[q];
#pragma unroll
    for (int c = 0; c < O; c++) acc[c] += v.x * Wl[(4 * q + 0) * O + c];
#pragma unroll
    for (int c = 0; c < O; c++) acc[c] += v.y * Wl[(4 * q + 1) * O + c];
#pragma unroll
    for (int c = 0; c < O; c++) acc[c] += v.z * Wl[(4 * q + 2) * O + c];
#pragma unroll
    for (int c = 0; c < O; c++) acc[c] += v.w * Wl[(4 * q + 3) * O + c];
  }
  float* y = Y + (size_t)i * ldY;
#pragma unroll
  for (int c = 0; c < O; c++) y[c] = acc[c];
  if (WBF) {
    u16* yb = Ybf + (size_t)i * O;
#pragma unroll
    for (int c = 0; c < O; c++) yb[c] = f2bf(acc[c]);
  }
}

// ---- CSR construction -------------------------------------------------------
__global__ void k_deg(const int* __restrict__ ei, u32* __restrict__ deg, int E) {
  int e = blockIdx.x * blockDim.x + threadIdx.x;
  if (e < E) atomicAdd(&deg[ei[E + e]], 1u);
}

__global__ void k_scan1(const u32* __restrict__ deg, u32* __restrict__ excl,
                        u32* __restrict__ part, int n) {
  __shared__ u32 sm[256];
  int t = threadIdx.x;
  int base = blockIdx.x * 1024 + t * 4;
  u32 v0 = (base + 0 < n) ? deg[base + 0] : 0u;
  u32 v1 = (base + 1 < n) ? deg[base + 1] : 0u;
  u32 v2 = (base + 2 < n) ? deg[base + 2] : 0u;
  u32 v3 = (base + 3 < n) ? deg[base + 3] : 0u;
  u32 tsum = v0 + v1 + v2 + v3;
  sm[t] = tsum;
  __syncthreads();
  for (int o = 1; o < 256; o <<= 1) {
    u32 v = (t >= o) ? sm[t - o] : 0u;
    __syncthreads();
    sm[t] += v;
    __syncthreads();
  }
  u32 tex = sm[t] - tsum;
  if (t == 255) part[blockIdx.x] = sm[255];
  if (base + 0 < n) excl[base + 0] = tex;
  if (base + 1 < n) excl[base + 1] = tex + v0;
  if (base + 2 < n) excl[base + 2] = tex + v0 + v1;
  if (base + 3 < n) excl[base + 3] = tex + v0 + v1 + v2;
}

__global__ void k_scan2(u32* __restrict__ part, int nb) {
  if (threadIdx.x == 0) {
    u32 acc = 0;
    for (int i = 0; i < nb; i++) { u32 v = part[i]; part[i] = acc; acc += v; }
  }
}

// scan finalize + dinv fused
__global__ void k_scan3(u32* __restrict__ rowptr, const u32* __restrict__ part,
                        const u32* __restrict__ deg, float* __restrict__ dinv,
                        int n, int E) {
  int i = blockIdx.x * blockDim.x + threadIdx.x;
  if (i < n) {
    rowptr[i] += part[i >> 10];
    dinv[i] = rsqrtf((float)(deg[i] + 1u));
  }
  if (i == 0) rowptr[n] = (u32)E;
}

__global__ void k_slots(const int* __restrict__ ei, const u32* __restrict__ rowptr,
                        u32* __restrict__ cnt, int* __restrict__ csr_src,
                        int* __restrict__ csr_eid, int E) {
  int e = blockIdx.x * blockDim.x + threadIdx.x;
  if (e >= E) return;
  int s = ei[e], d = ei[E + e];
  u32 slot = rowptr[d] + atomicAdd(&cnt[d], 1u);
  csr_src[slot] = s;
  csr_eid[slot] = e;
}

// slot-major attr permute, packed f16: 32B/edge, v_cvt_pkrtz packing
__global__ void k_gather(const int* __restrict__ csr_eid, const float* __restrict__ ea,
                         u32* __restrict__ eaperm, int E) {
  int i = blockIdx.x * blockDim.x + threadIdx.x;
  if (i >= E) return;
  int e = csr_eid[i];
  const float4* p = (const float4*)(ea + (size_t)e * 16);
  float4 a = p[0], b = p[1], c = p[2], d = p[3];
  uint4* q = (uint4*)(eaperm + (size_t)i * 8);
  uint4 w0, w1;
  w0.x = pkrtz(a.x, a.y);
  w0.y = pkrtz(a.z, a.w);
  w0.z = pkrtz(b.x, b.y);
  w0.w = pkrtz(b.z, b.w);
  w1.x = pkrtz(c.x, c.y);
  w1.y = pkrtz(c.z, c.w);
  w1.z = pkrtz(d.x, d.y);
  w1.w = pkrtz(d.z, d.w);
  q[0] = w0; q[1] = w1;
}

// ---- GENConv agg d=48: wave/node; fdot2 f16 dot, bf16 h-gather --------------
template<bool PERM>
__global__ void k_agg48(const u32* __restrict__ rowptr, const int* __restrict__ csr_src,
                        const int* __restrict__ csr_eid, const u32* __restrict__ eaperm,
                        const float* __restrict__ ea,
                        const float* __restrict__ we, const float* __restrict__ be,
                        const float* __restrict__ h, const u16* __restrict__ hbf,
                        float* __restrict__ out, int n) {
  int lane = threadIdx.x & 63;
  int cl   = (lane < 48) ? lane : lane - 48;   // lanes 48-63 duplicate ch 0-15
  int node = (blockIdx.x * blockDim.x + threadIdx.x) >> 6;
  if (node >= n) return;
  float bias = be[cl];
  float hself = h[(size_t)node * 48 + cl];
  u32 b = rowptr[node], t = rowptr[node + 1];
  float den = 0.f, num = 0.f;
  u32 i = b;
  if (PERM) {
    u32 wcp[8];
#pragma unroll
    for (int k = 0; k < 8; k++)
      wcp[k] = pkrtz(we[(2 * k + 0) * 48 + cl], we[(2 * k + 1) * 48 + cl]);
    for (; i + 2 <= t; i += 2) {
      int s0 = csr_src[i + 0];
      int s1 = csr_src[i + 1];
      const uint4* pa = (const uint4*)(eaperm + (size_t)i * 8);
      uint4 a0 = pa[0], a1 = pa[1];
      uint4 b0 = pa[2], b1 = pa[3];
      float h0 = bf1(hbf[(size_t)s0 * 48 + cl]);
      float h1 = bf1(hbf[(size_t)s1 * 48 + cl]);
      float ml0 = dot8(a1, wcp + 4, dot8(a0, wcp, bias));
      float ml1 = dot8(b1, wcp + 4, dot8(b0, wcp, bias));
      float m0 = fmaxf(h0 + ml0, 0.f) + EPS_MSG;
      float m1 = fmaxf(h1 + ml1, 0.f) + EPS_MSG;
      float ex0 = __expf(m0);
      float ex1 = __expf(m1);
      den += ex0 + ex1;
      num += ex0 * m0 + ex1 * m1;
    }
    for (; i < t; i++) {
      int s = csr_src[i];
      const uint4* pa = (const uint4*)(eaperm + (size_t)i * 8);
      uint4 a0 = pa[0], a1 = pa[1];
      float hv = bf1(hbf[(size_t)s * 48 + cl]);
      float ml = dot8(a1, wcp + 4, dot8(a0, wcp, bias));
      float m  = fmaxf(hv + ml, 0.f) + EPS_MSG;
      float ex = __expf(m);
      den += ex; num += ex * m;
    }
  } else {
    float wc[16];
#pragma unroll
    for (int k = 0; k < 16; k++) wc[k] = we[k * 48 + cl];
    for (; i < t; i++) {
      int s = csr_src[i];
      const float4* p = (const float4*)(ea + (size_t)csr_eid[i] * 16);
      float4 a0 = p[0], a1 = p[1], a2 = p[2], a3 = p[3];
      float hv = h[(size_t)s * 48 + cl];
      float ml = EDGE_DOT(a0, a1, a2, a3);
      float m  = fmaxf(hv + ml, 0.f) + EPS_MSG;
      float ex = __expf(m);
      den += ex; num += ex * m;
    }
  }
  if (lane < 48)
    out[(size_t)node * 48 + lane] = hself + num / (den + 1e-16f);
}

// ---- GENConv agg d=32: half-wave/node; fdot2 f16 dot ------------------------
template<bool PERM>
__global__ void k_agg32(const u32* __restrict__ rowptr, const int* __restrict__ csr_src,
                        const int* __restrict__ csr_eid, const u32* __restrict__ eaperm,
                        const float* __restrict__ ea,
                        const float* __restrict__ we, const float* __restrict__ be,
                        const float* __restrict__ h, const u16* __restrict__ hbf,
                        float* __restrict__ out, int n) {
  int c    = threadIdx.x & 31;
  int node = (blockIdx.x * blockDim.x + threadIdx.x) >> 5;
  if (node >= n) return;
  float bias = be[c];
  float hself = h[(size_t)node * 32 + c];
  u32 b = rowptr[node], t = rowptr[node + 1];
  float den = 0.f, num = 0.f;
  u32 i = b;
  if (PERM) {
    u32 wcp[8];
#pragma unroll
    for (int k = 0; k < 8; k++)
      wcp[k] = pkrtz(we[(2 * k + 0) * 32 + c], we[(2 * k + 1) * 32 + c]);
    for (; i + 2 <= t; i += 2) {
      int s0 = csr_src[i + 0];
      int s1 = csr_src[i + 1];
      const uint4* pa = (const uint4*)(eaperm + (size_t)i * 8);
      uint4 a0 = pa[0], a1 = pa[1];
      uint4 b0 = pa[2], b1 = pa[3];
      float h0 = bf1(hbf[(size_t)s0 * 32 + c]);
      float h1 = bf1(hbf[(size_t)s1 * 32 + c]);
      float ml0 = dot8(a1, wcp + 4, dot8(a0, wcp, bias));
      float ml1 = dot8(b1, wcp + 4, dot8(b0, wcp, bias));
      float m0 = fmaxf(h0 + ml0, 0.f) + EPS_MSG;
      float m1 = fmaxf(h1 + ml1, 0.f) + EPS_MSG;
      float ex0 = __expf(m0);
      float ex1 = __expf(m1);
      den += ex0 + ex1;
      num += ex0 * m0 + ex1 * m1;
    }
    for (; i < t; i++) {
      int s = csr_src[i];
      const uint4* pa = (const uint4*)(eaperm + (size_t)i * 8);
      uint4 a0 = pa[0], a1 = pa[1];
      float hv = bf1(hbf[(size_t)s * 32 + c]);
      float ml = dot8(a1, wcp + 4, dot8(a0, wcp, bias));
      float m  = fmaxf(hv + ml, 0.f) + EPS_MSG;
      float ex = __expf(m);
      den += ex; num += ex * m;
    }
  } else {
    float wc[16];
#pragma unroll
    for (int k = 0; k < 16; k++) wc[k] = we[k * 32 + c];
    for (; i < t; i++) {
      int s = csr_src[i];
      const float4* p = (const float4*)(ea + (size_t)csr_eid[i] * 16);
      float4 a0 = p[0], a1 = p[1], a2 = p[2], a3 = p[3];
      float hv = h[(size_t)s * 32 + c];
      float ml = EDGE_DOT(a0, a1, a2, a3);
      float m  = fmaxf(hv + ml, 0.f) + EPS_MSG;
      float ex = __expf(m);
      den += ex; num += ex * m;
    }
  }
  out[(size_t)node * 32 + c] = hself + num / (den + 1e-16f);
}

// ---- zt = X@W1 + B1 (split panels) + per-block BN-stat partials -------------
template<int D>
__global__ void k_ztstats(const float* __restrict__ X, const float* __restrict__ W,
                          const float* __restrict__ B, float* __restrict__ Z1,
                          float* __restrict__ Z2, float* __restrict__ partial, int n) {
  __shared__ float Wl[D * 2 * D];
  __shared__ float Bl[2 * D];
  __shared__ float red[4][4 * D];
  for (int t = threadIdx.x; t < D * 2 * D; t += blockDim.x) Wl[t] = W[t];
  for (int t = threadIdx.x; t < 2 * D; t += blockDim.x) Bl[t] = B[t];
  __syncthreads();
  int i = blockIdx.x * blockDim.x + threadIdx.x;
  bool act = (i < n);
  float acc[2 * D];
#pragma unroll
  for (int c = 0; c < 2 * D; c++) acc[c] = 0.f;
  if (act) {
#pragma unroll
    for (int c = 0; c < 2 * D; c++) acc[c] = Bl[c];
    const float4* xp = (const float4*)(X + (size_t)i * D);
    for (int q = 0; q < D / 4; q++) {
      float4 v = xp[q];
#pragma unroll
      for (int c = 0; c < 2 * D; c++) acc[c] += v.x * Wl[(4 * q + 0) * 2 * D + c];
#pragma unroll
      for (int c = 0; c < 2 * D; c++) acc[c] += v.y * Wl[(4 * q + 1) * 2 * D + c];
#pragma unroll
      for (int c = 0; c < 2 * D; c++) acc[c] += v.z * Wl[(4 * q + 2) * 2 * D + c];
#pragma unroll
      for (int c = 0; c < 2 * D; c++) acc[c] += v.w * Wl[(4 * q + 3) * 2 * D + c];
    }
    float* z1 = Z1 + (size_t)i * D;
    float* z2 = Z2 + (size_t)i * D;
#pragma unroll
    for (int c = 0; c < D; c++) { z1[c] = acc[c]; z2[c] = acc[D + c]; }
  } else {
#pragma unroll
    for (int c = 0; c < 2 * D; c++) acc[c] = 0.f;
  }
  int lane = threadIdx.x & 63;
  int wv   = threadIdx.x >> 6;
#pragma unroll
  for (int c = 0; c < 2 * D; c++) {
    float v = acc[c], v2 = v * v;
#pragma unroll
    for (int o = 32; o; o >>= 1) { v += __shfl_xor(v, o); v2 += __shfl_xor(v2, o); }
    if (lane == 0) { red[wv][c] = v; red[wv][2 * D + c] = v2; }
  }
  __syncthreads();
  if (threadIdx.x < 4 * D) {
    float s = red[0][threadIdx.x] + red[1][threadIdx.x] +
              red[2][threadIdx.x] + red[3][threadIdx.x];
    partial[(size_t)blockIdx.x * 4 * D + threadIdx.x] = s;
  }
}

__global__ void k_bnfin(const float* __restrict__ partial, float* __restrict__ stats,
                        int nb, int m) {
  int c = blockIdx.x * blockDim.x + threadIdx.x;
  if (c >= m) return;
  float s = 0.f;
  for (int b = 0; b < nb; b++) s += partial[(size_t)b * m + c];
  stats[c] = s;
}

// ---- BN -> relu -> @W2+b2 -> relu -> @Ws(+Bs); optional bf16 / dinv-scale ---
template<int D, int DD, int O, bool ADDBS, bool WBF, bool SCALE>
__global__ void k_mlp_lin(const float* __restrict__ ztA, const float* __restrict__ ztB,
                          const float* __restrict__ stats,
                          const float* __restrict__ G, const float* __restrict__ BE,
                          const float* __restrict__ W2, const float* __restrict__ B2,
                          const float* __restrict__ Wsa, const float* __restrict__ Wsb,
                          const float* __restrict__ Bs, const float* __restrict__ dinv,
                          float* __restrict__ out, u16* __restrict__ outbf,
                          float invN, int n) {
  __shared__ float Wl[DD * D];
  __shared__ float Ws[D * O];
  __shared__ float Bl[D];
  __shared__ float Bsl[O];
  __shared__ float sc[DD], sh[DD];
  for (int t = threadIdx.x; t < DD * D; t += blockDim.x) Wl[t] = W2[t];
  if (Wsb == nullptr) {
    for (int t = threadIdx.x; t < D * O; t += blockDim.x) Ws[t] = Wsa[t];
  } else {
    for (int t = threadIdx.x; t < D * O; t += blockDim.x) {
      int k = t / O, o = t % O;
      Ws[t] = (o < O / 2) ? Wsa[k * (O / 2) + o] : Wsb[k * (O / 2) + (o - O / 2)];
    }
  }
  if (threadIdx.x < D) Bl[threadIdx.x] = B2[threadIdx.x];
  if (threadIdx.x < O) Bsl[threadIdx.x] = ADDBS ? Bs[threadIdx.x] : 0.f;
  if (threadIdx.x < DD) {
    int c   = threadIdx.x;
    float m = stats[c] * invN;
    float v = stats[DD + c] * invN - m * m;
    float s = G[c] * rsqrtf(v + BN_EPS);
    sc[c] = s; sh[c] = BE[c] - m * s;
  }
  __syncthreads();
  int i = blockIdx.x * blockDim.x + threadIdx.x;
  if (i >= n) return;
  float y[D];
#pragma unroll
  for (int c = 0; c < D; c++) y[c] = Bl[c];
  const float* a = ztA + (size_t)i * D;
  const float* b = ztB + (size_t)i * D;
  for (int k = 0; k < D; k++) {
    float z = fmaxf(a[k] * sc[k] + sh[k], 0.f);
#pragma unroll
    for (int c = 0; c < D; c++) y[c] += z * Wl[k * D + c];
  }
  for (int k = D; k < DD; k++) {
    float z = fmaxf(b[k - D] * sc[k] + sh[k], 0.f);
#pragma unroll
    for (int c = 0; c < D; c++) y[c] += z * Wl[k * D + c];
  }
  float acc[O];
#pragma unroll
  for (int o = 0; o < O; o++) acc[o] = Bsl[o];
#pragma unroll
  for (int k = 0; k < D; k++) {
    float z = fmaxf(y[k], 0.f);
#pragma unroll
    for (int o = 0; o < O; o++) acc[o] += z * Ws[k * O + o];
  }
  float dv = SCALE ? dinv[i] : 1.f;
  float* yo = out + (size_t)i * O;
#pragma unroll
  for (int o = 0; o < O; o++) yo[o] = SCALE ? acc[o] * dv : acc[o];
  if (WBF) {
    u16* yb = outbf + (size_t)i * O;
#pragma unroll
    for (int o = 0; o < O; o++) yb[o] = f2bf(acc[o]);
  }
}

// ---- GCN heads: CSR gather of pre-scaled rows, chunk-2, fused store ---------
__global__ void k_gcn(const u32* __restrict__ rowptr, const int* __restrict__ csr_src,
                      const float* __restrict__ yzd, const float* __restrict__ dinv,
                      const float* __restrict__ bmu, const float* __restrict__ bls,
                      float* __restrict__ out, int n) {
  int c    = threadIdx.x & 31;
  int node = (blockIdx.x * blockDim.x + threadIdx.x) >> 5;
  if (node >= n) return;
  u32 b = rowptr[node], t = rowptr[node + 1];
  float acc = 0.f;
  u32 i = b;
  for (; i + 2 <= t; i += 2) {
    int s0 = csr_src[i];
    int s1 = csr_src[i + 1];
    float y0 = yzd[(size_t)s0 * 32 + c];
    float y1 = yzd[(size_t)s1 * 32 + c];
    acc += y0 + y1;
  }
  if (i < t) acc += yzd[(size_t)csr_src[i] * 32 + c];
  float dv  = dinv[node];
  float val = (acc + yzd[(size_t)node * 32 + c]) * dv +
              ((c < 16) ? bmu[c] : bls[c - 16]);
  if (c < 16) out[(size_t)node * 16 + c] = val;
  else        out[(size_t)n * 16 + (size_t)node * 16 + (c - 16)] = val;
}

extern "C" void kernel_launch(void* const* d_in, const int* in_sizes, int n_in,
                              void* d_out, int out_size, void* d_ws, size_t ws_size,
                              hipStream_t stream) {
  const float* x      = (const float*)d_in[0];
  const int*  ei      = (const int*)d_in[1];          // int32 (2,E) rows
  const float* ea     = (const float*)d_in[2];
  const float* w_src1 = (const float*)d_in[3];  const float* b_src1 = (const float*)d_in[4];
  const float* w_edge1= (const float*)d_in[5];  const float* b_edge1= (const float*)d_in[6];
  const float* w_m1a  = (const float*)d_in[7];  const float* b_m1a  = (const float*)d_in[8];
  const float* g1     = (const float*)d_in[9];  const float* be1    = (const float*)d_in[10];
  const float* w_m1b  = (const float*)d_in[11]; const float* b_m1b  = (const float*)d_in[12];
  const float* w_src2 = (const float*)d_in[13]; const float* b_src2 = (const float*)d_in[14];
  const float* w_edge2= (const float*)d_in[15]; const float* b_edge2= (const float*)d_in[16];
  const float* w_m2a  = (const float*)d_in[17]; const float* b_m2a  = (const float*)d_in[18];
  const float* g2     = (const float*)d_in[19]; const float* be2    = (const float*)d_in[20];
  const float* w_m2b  = (const float*)d_in[21]; const float* b_m2b  = (const float*)d_in[22];
  const float* w_mu   = (const float*)d_in[23]; const float* b_mu   = (const float*)d_in[24];
  const float* w_ls   = (const float*)d_in[25]; const float* b_ls   = (const float*)d_in[26];

  const int N = in_sizes[0] / 64;
  const int E = in_sizes[1] / 2;

  const int NB  = (N + 255) / 256;
  const int EB  = (E + 255) / 256;
  const int SB1 = (N + 1023) / 1024;

  float* ws     = (float*)d_ws;
  size_t N48    = (size_t)N * 48;
  float* P0     = ws;
  float* P1     = ws + N48;
  float* P2     = ws + 2 * N48;
  float* P3     = ws + 3 * N48;
  size_t o      = 4 * N48;
  u32*  rowptr  = (u32*)(ws + o);            // N+1
  u32*  cnt     = rowptr + (N + 1);          // N
  u32*  deg     = cnt + N;                   // N
  u32*  part    = deg + N;                   // 256
  float* dinv   = (float*)(part + 256);      // N
  float* stats  = dinv + N;                  // 512
  size_t po     = o + 4 * (size_t)N + 769;
  float* partial= ws + po;                   // NB*192
  size_t co     = (po + (size_t)NB * 192 + 3) & ~(size_t)3;
  int*  csr_src = (int*)(ws + co);           // E ints
  int*  csr_eid = csr_src + E;               // E ints
  size_t eo     = co + 2 * (size_t)E;        // 16B-aligned
  u32*  eaperm  = (u32*)(ws + eo);           // 8E u32 (f16-packed attrs)
  size_t ho     = eo + 8 * (size_t)E;
  u16*  hbf1    = (u16*)(ws + ho);           // N*48 u16
  size_t h2o    = ho + 24 * (size_t)N;
  u16*  hbf2    = (u16*)(ws + h2o);          // N*32 u16
  size_t needB  = (h2o + 16 * (size_t)N + 16) * sizeof(float);
  const bool PERM = (ws_size >= needB);

  dim3 b256(256);

  hipMemsetAsync(cnt, 0, 2 * (size_t)N * sizeof(u32), stream);

  // CSR build
  k_deg<<<EB, b256, 0, stream>>>(ei, deg, E);
  k_scan1<<<SB1, b256, 0, stream>>>(deg, rowptr, part, N);
  k_scan2<<<1, 64, 0, stream>>>(part, SB1);
  k_scan3<<<NB, b256, 0, stream>>>(rowptr, part, deg, dinv, N, E);
  k_slots<<<EB, b256, 0, stream>>>(ei, rowptr, cnt, csr_src, csr_eid, E);
  if (PERM) k_gather<<<EB, b256, 0, stream>>>(csr_eid, ea, eaperm, E);

  // ---- GENConv 1 (64 -> 48) ----
  if (PERM) k_lin<64, 48, true><<<NB, b256, 0, stream>>>(x, w_src1, b_src1, P0, hbf1, 48, N);
  else      k_lin<64, 48, false><<<NB, b256, 0, stream>>>(x, w_src1, b_src1, P0, nullptr, 48, N);
  if (PERM) k_agg48<true><<<(N * 64 + 255) / 256, b256, 0, stream>>>(rowptr, csr_src,
                       csr_eid, eaperm, ea, w_edge1, b_edge1, P0, hbf1, P3, N);
  else      k_agg48<false><<<(N * 64 + 255) / 256, b256, 0, stream>>>(rowptr, csr_src,
                       csr_eid, eaperm, ea, w_edge1, b_edge1, P0, hbf1, P3, N);
  k_ztstats<48><<<NB, b256, 0, stream>>>(P3, w_m1a, b_m1a, P1, P2, partial, N);
  k_bnfin<<<1, 256, 0, stream>>>(partial, stats, NB, 192);
  if (PERM)
    k_mlp_lin<48, 96, 32, true, true, false><<<NB, b256, 0, stream>>>(P1, P2, stats, g1, be1,
                       w_m1b, b_m1b, w_src2, nullptr, b_src2, nullptr, P0, hbf2,
                       1.0f / (float)N, N);
  else
    k_mlp_lin<48, 96, 32, true, false, false><<<NB, b256, 0, stream>>>(P1, P2, stats, g1, be1,
                       w_m1b, b_m1b, w_src2, nullptr, b_src2, nullptr, P0, nullptr,
                       1.0f / (float)N, N);

  // ---- GENConv 2 (48 -> 32) ----
  if (PERM) k_agg32<true><<<(N * 32 + 255) / 256, b256, 0, stream>>>(rowptr, csr_src,
                       csr_eid, eaperm, ea, w_edge2, b_edge2, P0, hbf2, P3, N);
  else      k_agg32<false><<<(N * 32 + 255) / 256, b256, 0, stream>>>(rowptr, csr_src,
                       csr_eid, eaperm, ea, w_edge2, b_edge2, P0, hbf2, P3, N);
  k_ztstats<32><<<NB, b256, 0, stream>>>(P3, w_m2a, b_m2a, P1, P2, partial, N);
  k_bnfin<<<1, 256, 0, stream>>>(partial, stats + 256, NB, 128);
  // fused dinv scale: writes yzd = (heads output)·dinv[i] directly
  k_mlp_lin<32, 64, 32, false, false, true><<<NB, b256, 0, stream>>>(P1, P2, stats + 256,
                       g2, be2, w_m2b, b_m2b, w_mu, w_ls, nullptr, dinv, P0, nullptr,
                       1.0f / (float)N, N);

  // ---- GCN heads ----
  k_gcn<<<(N * 32 + 255) / 256, b256, 0, stream>>>(rowptr, csr_src, P0, dinv,
                                                   b_mu, b_ls, (float*)d_out, N);
}

// Round 20
// 911.520 us; speedup vs baseline: 1.4357x; 1.0269x over previous
//
#include <hip/hip_runtime.h>
#include <hip/hip_bf16.h>

typedef unsigned int u32;
typedef unsigned short u16;
typedef _Float16 h2 __attribute__((ext_vector_type(2)));

#define EPS_MSG 1e-7f
#define BN_EPS  1e-5f

__device__ __forceinline__ u16 f2bf(float f) {          // round-to-nearest-even
  u32 u = __float_as_uint(f);
  return (u16)((u + 0x7FFFu + ((u >> 16) & 1u)) >> 16);
}
__device__ __forceinline__ float bf1(u16 v) { return __uint_as_float(((u32)v) << 16); }
__device__ __forceinline__ h2 u2h(u32 v) { union { u32 u; h2 h; } t; t.u = v; return t.h; }

// pack two f32 -> pk f16 pair as raw u32 (via __fp16 vector return type)
__device__ __forceinline__ u32 pkrtz(float a, float b) {
  union { __fp16 v __attribute__((ext_vector_type(2))); u32 u; } t;
  t.v = __builtin_amdgcn_cvt_pkrtz(a, b);
  return t.u;
}

// 8 f16 pairs (one uint4) dotted against packed weights via v_dot2_f32_f16
__device__ __forceinline__ float dot8(uint4 v, const u32* w, float acc) {
  acc = __builtin_amdgcn_fdot2(u2h(v.x), u2h(w[0]), acc, false);
  acc = __builtin_amdgcn_fdot2(u2h(v.y), u2h(w[1]), acc, false);
  acc = __builtin_amdgcn_fdot2(u2h(v.z), u2h(w[2]), acc, false);
  acc = __builtin_amdgcn_fdot2(u2h(v.w), u2h(w[3]), acc, false);
  return acc;
}

#define EDGE_DOT(A0,A1,A2,A3) (bias + \
  A0.x * wc[0]  + A0.y * wc[1]  + A0.z * wc[2]  + A0.w * wc[3] + \
  A1.x * wc[4]  + A1.y * wc[5]  + A1.z * wc[6]  + A1.w * wc[7] + \
  A2.x * wc[8]  + A2.y * wc[9]  + A2.z * wc[10] + A2.w * wc[11] + \
  A3.x * wc[12] + A3.y * wc[13] + A3.z * wc[14] + A3.w * wc[15])

// ---- small linear: Y[i*ldY+c] = X[i,:]·W[:,c] + B[c]; optional bf16 shadow --
template<int I, int O, bool WBF>
__global__ void k_lin(const float* __restrict__ X, const float* __restrict__ W,
                      const float* __restrict__ B, float* __restrict__ Y,
                      u16* __restrict__ Ybf, int ldY, int n) {
  __shared__ float Wl[I * O];
  __shared__ float Bl[O];
  for (int t = threadIdx.x; t < I * O; t += blockDim.x) Wl[t] = W[t];
  if (threadIdx.x < O) Bl[threadIdx.x] = B[threadIdx.x];
  __syncthreads();
  int i = blockIdx.x * blockDim.x + threadIdx.x;
  if (i >= n) return;
  float acc[O];
#pragma unroll
  for (int c = 0; c < O; c++) acc[c] = Bl[c];
  const float4* xp = (const float4*)(X + (size_t)i * I);
  for (int q = 0; q < I / 4; q++) {
    float4 v = xp[q];
#pragma unroll
    for (int c = 0; c < O; c++) acc[c] += v.x * Wl[(4 * q + 0) * O + c];
#pragma unroll
    for (int c = 0; c < O; c++) acc[c] += v.y * Wl[(4 * q + 1) * O + c];
#pragma unroll
    for (int c = 0; c < O; c++) acc[c] += v.z * Wl[(4 * q + 2) * O + c];
#pragma unroll
    for (int c = 0; c < O; c++) acc[c] += v.w * Wl[(4 * q + 3) * O + c];
  }
  float* y = Y + (size_t)i * ldY;
#pragma unroll
  for (int c = 0; c < O; c++) y[c] = acc[c];
  if (WBF) {
    u16* yb = Ybf + (size_t)i * O;
#pragma unroll
    for (int c = 0; c < O; c++) yb[c] = f2bf(acc[c]);
  }
}

// ---- CSR construction -------------------------------------------------------
__global__ void k_deg(const int* __restrict__ ei, u32* __restrict__ deg, int E) {
  int e = blockIdx.x * blockDim.x + threadIdx.x;
  if (e < E) atomicAdd(&deg[ei[E + e]], 1u);
}

__global__ void k_scan1(const u32* __restrict__ deg, u32* __restrict__ excl,
                        u32* __restrict__ part, int n) {
  __shared__ u32 sm[256];
  int t = threadIdx.x;
  int base = blockIdx.x * 1024 + t * 4;
  u32 v0 = (base + 0 < n) ? deg[base + 0] : 0u;
  u32 v1 = (base + 1 < n) ? deg[base + 1] : 0u;
  u32 v2 = (base + 2 < n) ? deg[base + 2] : 0u;
  u32 v3 = (base + 3 < n) ? deg[base + 3] : 0u;
  u32 tsum = v0 + v1 + v2 + v3;
  sm[t] = tsum;
  __syncthreads();
  for (int o = 1; o < 256; o <<= 1) {
    u32 v = (t >= o) ? sm[t - o] : 0u;
    __syncthreads();
    sm[t] += v;
    __syncthreads();
  }
  u32 tex = sm[t] - tsum;
  if (t == 255) part[blockIdx.x] = sm[255];
  if (base + 0 < n) excl[base + 0] = tex;
  if (base + 1 < n) excl[base + 1] = tex + v0;
  if (base + 2 < n) excl[base + 2] = tex + v0 + v1;
  if (base + 3 < n) excl[base + 3] = tex + v0 + v1 + v2;
}

__global__ void k_scan2(u32* __restrict__ part, int nb) {
  if (threadIdx.x == 0) {
    u32 acc = 0;
    for (int i = 0; i < nb; i++) { u32 v = part[i]; part[i] = acc; acc += v; }
  }
}

// scan finalize + dinv fused
__global__ void k_scan3(u32* __restrict__ rowptr, const u32* __restrict__ part,
                        const u32* __restrict__ deg, float* __restrict__ dinv,
                        int n, int E) {
  int i = blockIdx.x * blockDim.x + threadIdx.x;
  if (i < n) {
    rowptr[i] += part[i >> 10];
    dinv[i] = rsqrtf((float)(deg[i] + 1u));
  }
  if (i == 0) rowptr[n] = (u32)E;
}

__global__ void k_slots(const int* __restrict__ ei, const u32* __restrict__ rowptr,
                        u32* __restrict__ cnt, int* __restrict__ csr_src,
                        int* __restrict__ csr_eid, int E) {
  int e = blockIdx.x * blockDim.x + threadIdx.x;
  if (e >= E) return;
  int s = ei[e], d = ei[E + e];
  u32 slot = rowptr[d] + atomicAdd(&cnt[d], 1u);
  csr_src[slot] = s;
  csr_eid[slot] = e;
}

// slot-major attr permute, packed f16: 32B/edge, v_cvt_pkrtz packing
__global__ void k_gather(const int* __restrict__ csr_eid, const float* __restrict__ ea,
                         u32* __restrict__ eaperm, int E) {
  int i = blockIdx.x * blockDim.x + threadIdx.x;
  if (i >= E) return;
  int e = csr_eid[i];
  const float4* p = (const float4*)(ea + (size_t)e * 16);
  float4 a = p[0], b = p[1], c = p[2], d = p[3];
  uint4* q = (uint4*)(eaperm + (size_t)i * 8);
  uint4 w0, w1;
  w0.x = pkrtz(a.x, a.y);
  w0.y = pkrtz(a.z, a.w);
  w0.z = pkrtz(b.x, b.y);
  w0.w = pkrtz(b.z, b.w);
  w1.x = pkrtz(c.x, c.y);
  w1.y = pkrtz(c.z, c.w);
  w1.z = pkrtz(d.x, d.y);
  w1.w = pkrtz(d.z, d.w);
  q[0] = w0; q[1] = w1;
}

// ---- GENConv agg d=48: wave/node; fdot2 dot, chunk-4 h-gather prefetch ------
template<bool PERM>
__global__ void k_agg48(const u32* __restrict__ rowptr, const int* __restrict__ csr_src,
                        const int* __restrict__ csr_eid, const u32* __restrict__ eaperm,
                        const float* __restrict__ ea,
                        const float* __restrict__ we, const float* __restrict__ be,
                        const float* __restrict__ h, const u16* __restrict__ hbf,
                        float* __restrict__ out, int n) {
  int lane = threadIdx.x & 63;
  int cl   = (lane < 48) ? lane : lane - 48;   // lanes 48-63 duplicate ch 0-15
  int node = (blockIdx.x * blockDim.x + threadIdx.x) >> 6;
  if (node >= n) return;
  float bias = be[cl];
  float hself = h[(size_t)node * 48 + cl];
  u32 b = rowptr[node], t = rowptr[node + 1];
  float den = 0.f, num = 0.f;
  u32 i = b;
  if (PERM) {
    u32 wcp[8];
#pragma unroll
    for (int k = 0; k < 8; k++)
      wcp[k] = pkrtz(we[(2 * k + 0) * 48 + cl], we[(2 * k + 1) * 48 + cl]);
    for (; i + 4 <= t; i += 4) {
      int s0 = csr_src[i + 0];
      int s1 = csr_src[i + 1];
      int s2 = csr_src[i + 2];
      int s3 = csr_src[i + 3];
      float hv0 = bf1(hbf[(size_t)s0 * 48 + cl]);
      float hv1 = bf1(hbf[(size_t)s1 * 48 + cl]);
      float hv2 = bf1(hbf[(size_t)s2 * 48 + cl]);
      float hv3 = bf1(hbf[(size_t)s3 * 48 + cl]);
      const uint4* pa = (const uint4*)(eaperm + (size_t)i * 8);
      uint4 a0 = pa[0], a1 = pa[1];
      uint4 b0 = pa[2], b1 = pa[3];
      uint4 c0 = pa[4], c1 = pa[5];
      uint4 d0 = pa[6], d1 = pa[7];
      float ml0 = dot8(a1, wcp + 4, dot8(a0, wcp, bias));
      float ml1 = dot8(b1, wcp + 4, dot8(b0, wcp, bias));
      float ml2 = dot8(c1, wcp + 4, dot8(c0, wcp, bias));
      float ml3 = dot8(d1, wcp + 4, dot8(d0, wcp, bias));
      float m0 = fmaxf(hv0 + ml0, 0.f) + EPS_MSG;
      float m1 = fmaxf(hv1 + ml1, 0.f) + EPS_MSG;
      float m2 = fmaxf(hv2 + ml2, 0.f) + EPS_MSG;
      float m3 = fmaxf(hv3 + ml3, 0.f) + EPS_MSG;
      float ex0 = __expf(m0);
      float ex1 = __expf(m1);
      float ex2 = __expf(m2);
      float ex3 = __expf(m3);
      den += (ex0 + ex1) + (ex2 + ex3);
      num += (ex0 * m0 + ex1 * m1) + (ex2 * m2 + ex3 * m3);
    }
    for (; i < t; i++) {
      int s = csr_src[i];
      const uint4* pa = (const uint4*)(eaperm + (size_t)i * 8);
      uint4 a0 = pa[0], a1 = pa[1];
      float hv = bf1(hbf[(size_t)s * 48 + cl]);
      float ml = dot8(a1, wcp + 4, dot8(a0, wcp, bias));
      float m  = fmaxf(hv + ml, 0.f) + EPS_MSG;
      float ex = __expf(m);
      den += ex; num += ex * m;
    }
  } else {
    float wc[16];
#pragma unroll
    for (int k = 0; k < 16; k++) wc[k] = we[k * 48 + cl];
    for (; i < t; i++) {
      int s = csr_src[i];
      const float4* p = (const float4*)(ea + (size_t)csr_eid[i] * 16);
      float4 a0 = p[0], a1 = p[1], a2 = p[2], a3 = p[3];
      float hv = h[(size_t)s * 48 + cl];
      float ml = EDGE_DOT(a0, a1, a2, a3);
      float m  = fmaxf(hv + ml, 0.f) + EPS_MSG;
      float ex = __expf(m);
      den += ex; num += ex * m;
    }
  }
  if (lane < 48)
    out[(size_t)node * 48 + lane] = hself + num / (den + 1e-16f);
}

// ---- GENConv agg d=32: half-wave/node; fdot2 dot, chunk-4 -------------------
template<bool PERM>
__global__ void k_agg32(const u32* __restrict__ rowptr, const int* __restrict__ csr_src,
                        const int* __restrict__ csr_eid, const u32* __restrict__ eaperm,
                        const float* __restrict__ ea,
                        const float* __restrict__ we, const float* __restrict__ be,
                        const float* __restrict__ h, const u16* __restrict__ hbf,
                        float* __restrict__ out, int n) {
  int c    = threadIdx.x & 31;
  int node = (blockIdx.x * blockDim.x + threadIdx.x) >> 5;
  if (node >= n) return;
  float bias = be[c];
  float hself = h[(size_t)node * 32 + c];
  u32 b = rowptr[node], t = rowptr[node + 1];
  float den = 0.f, num = 0.f;
  u32 i = b;
  if (PERM) {
    u32 wcp[8];
#pragma unroll
    for (int k = 0; k < 8; k++)
      wcp[k] = pkrtz(we[(2 * k + 0) * 32 + c], we[(2 * k + 1) * 32 + c]);
    for (; i + 4 <= t; i += 4) {
      int s0 = csr_src[i + 0];
      int s1 = csr_src[i + 1];
      int s2 = csr_src[i + 2];
      int s3 = csr_src[i + 3];
      float hv0 = bf1(hbf[(size_t)s0 * 32 + c]);
      float hv1 = bf1(hbf[(size_t)s1 * 32 + c]);
      float hv2 = bf1(hbf[(size_t)s2 * 32 + c]);
      float hv3 = bf1(hbf[(size_t)s3 * 32 + c]);
      const uint4* pa = (const uint4*)(eaperm + (size_t)i * 8);
      uint4 a0 = pa[0], a1 = pa[1];
      uint4 b0 = pa[2], b1 = pa[3];
      uint4 c0 = pa[4], c1 = pa[5];
      uint4 d0 = pa[6], d1 = pa[7];
      float ml0 = dot8(a1, wcp + 4, dot8(a0, wcp, bias));
      float ml1 = dot8(b1, wcp + 4, dot8(b0, wcp, bias));
      float ml2 = dot8(c1, wcp + 4, dot8(c0, wcp, bias));
      float ml3 = dot8(d1, wcp + 4, dot8(d0, wcp, bias));
      float m0 = fmaxf(hv0 + ml0, 0.f) + EPS_MSG;
      float m1 = fmaxf(hv1 + ml1, 0.f) + EPS_MSG;
      float m2 = fmaxf(hv2 + ml2, 0.f) + EPS_MSG;
      float m3 = fmaxf(hv3 + ml3, 0.f) + EPS_MSG;
      float ex0 = __expf(m0);
      float ex1 = __expf(m1);
      float ex2 = __expf(m2);
      float ex3 = __expf(m3);
      den += (ex0 + ex1) + (ex2 + ex3);
      num += (ex0 * m0 + ex1 * m1) + (ex2 * m2 + ex3 * m3);
    }
    for (; i < t; i++) {
      int s = csr_src[i];
      const uint4* pa = (const uint4*)(eaperm + (size_t)i * 8);
      uint4 a0 = pa[0], a1 = pa[1];
      float hv = bf1(hbf[(size_t)s * 32 + c]);
      float ml = dot8(a1, wcp + 4, dot8(a0, wcp, bias));
      float m  = fmaxf(hv + ml, 0.f) + EPS_MSG;
      float ex = __expf(m);
      den += ex; num += ex * m;
    }
  } else {
    float wc[16];
#pragma unroll
    for (int k = 0; k < 16; k++) wc[k] = we[k * 32 + c];
    for (; i < t; i++) {
      int s = csr_src[i];
      const float4* p = (const float4*)(ea + (size_t)csr_eid[i] * 16);
      float4 a0 = p[0], a1 = p[1], a2 = p[2], a3 = p[3];
      float hv = h[(size_t)s * 32 + c];
      float ml = EDGE_DOT(a0, a1, a2, a3);
      float m  = fmaxf(hv + ml, 0.f) + EPS_MSG;
      float ex = __expf(m);
      den += ex; num += ex * m;
    }
  }
  out[(size_t)node * 32 + c] = hself + num / (den + 1e-16f);
}

// ---- zt = X@W1 + B1 (split panels) + per-block BN-stat partials -------------
template<int D>
__global__ void k_ztstats(const float* __restrict__ X, const float* __restrict__ W,
                          const float* __restrict__ B, float* __restrict__ Z1,
                          float* __restrict__ Z2, float* __restrict__ partial, int n) {
  __shared__ float Wl[D * 2 * D];
  __shared__ float Bl[2 * D];
  __shared__ float red[4][4 * D];
  for (int t = threadIdx.x; t < D * 2 * D; t += blockDim.x) Wl[t] = W[t];
  for (int t = threadIdx.x; t < 2 * D; t += blockDim.x) Bl[t] = B[t];
  __syncthreads();
  int i = blockIdx.x * blockDim.x + threadIdx.x;
  bool act = (i < n);
  float acc[2 * D];
#pragma unroll
  for (int c = 0; c < 2 * D; c++) acc[c] = 0.f;
  if (act) {
#pragma unroll
    for (int c = 0; c < 2 * D; c++) acc[c] = Bl[c];
    const float4* xp = (const float4*)(X + (size_t)i * D);
    for (int q = 0; q < D / 4; q++) {
      float4 v = xp[q];
#pragma unroll
      for (int c = 0; c < 2 * D; c++) acc[c] += v.x * Wl[(4 * q + 0) * 2 * D + c];
#pragma unroll
      for (int c = 0; c < 2 * D; c++) acc[c] += v.y * Wl[(4 * q + 1) * 2 * D + c];
#pragma unroll
      for (int c = 0; c < 2 * D; c++) acc[c] += v.z * Wl[(4 * q + 2) * 2 * D + c];
#pragma unroll
      for (int c = 0; c < 2 * D; c++) acc[c] += v.w * Wl[(4 * q + 3) * 2 * D + c];
    }
    float* z1 = Z1 + (size_t)i * D;
    float* z2 = Z2 + (size_t)i * D;
#pragma unroll
    for (int c = 0; c < D; c++) { z1[c] = acc[c]; z2[c] = acc[D + c]; }
  } else {
#pragma unroll
    for (int c = 0; c < 2 * D; c++) acc[c] = 0.f;
  }
  int lane = threadIdx.x & 63;
  int wv   = threadIdx.x >> 6;
#pragma unroll
  for (int c = 0; c < 2 * D; c++) {
    float v = acc[c], v2 = v * v;
#pragma unroll
    for (int o = 32; o; o >>= 1) { v += __shfl_xor(v, o); v2 += __shfl_xor(v2, o); }
    if (lane == 0) { red[wv][c] = v; red[wv][2 * D + c] = v2; }
  }
  __syncthreads();
  if (threadIdx.x < 4 * D) {
    float s = red[0][threadIdx.x] + red[1][threadIdx.x] +
              red[2][threadIdx.x] + red[3][threadIdx.x];
    partial[(size_t)blockIdx.x * 4 * D + threadIdx.x] = s;
  }
}

__global__ void k_bnfin(const float* __restrict__ partial, float* __restrict__ stats,
                        int nb, int m) {
  int c = blockIdx.x * blockDim.x + threadIdx.x;
  if (c >= m) return;
  float s = 0.f;
  for (int b = 0; b < nb; b++) s += partial[(size_t)b * m + c];
  stats[c] = s;
}

// ---- BN -> relu -> @W2+b2 -> relu -> @Ws(+Bs); WOUT f32 / WBF bf16(scaled) --
template<int D, int DD, int O, bool ADDBS, bool WBF, bool SCALE, bool WOUT>
__global__ void k_mlp_lin(const float* __restrict__ ztA, const float* __restrict__ ztB,
                          const float* __restrict__ stats,
                          const float* __restrict__ G, const float* __restrict__ BE,
                          const float* __restrict__ W2, const float* __restrict__ B2,
                          const float* __restrict__ Wsa, const float* __restrict__ Wsb,
                          const float* __restrict__ Bs, const float* __restrict__ dinv,
                          float* __restrict__ out, u16* __restrict__ outbf,
                          float invN, int n) {
  __shared__ float Wl[DD * D];
  __shared__ float Ws[D * O];
  __shared__ float Bl[D];
  __shared__ float Bsl[O];
  __shared__ float sc[DD], sh[DD];
  for (int t = threadIdx.x; t < DD * D; t += blockDim.x) Wl[t] = W2[t];
  if (Wsb == nullptr) {
    for (int t = threadIdx.x; t < D * O; t += blockDim.x) Ws[t] = Wsa[t];
  } else {
    for (int t = threadIdx.x; t < D * O; t += blockDim.x) {
      int k = t / O, o = t % O;
      Ws[t] = (o < O / 2) ? Wsa[k * (O / 2) + o] : Wsb[k * (O / 2) + (o - O / 2)];
    }
  }
  if (threadIdx.x < D) Bl[threadIdx.x] = B2[threadIdx.x];
  if (threadIdx.x < O) Bsl[threadIdx.x] = ADDBS ? Bs[threadIdx.x] : 0.f;
  if (threadIdx.x < DD) {
    int c   = threadIdx.x;
    float m = stats[c] * invN;
    float v = stats[DD + c] * invN - m * m;
    float s = G[c] * rsqrtf(v + BN_EPS);
    sc[c] = s; sh[c] = BE[c] - m * s;
  }
  __syncthreads();
  int i = blockIdx.x * blockDim.x + threadIdx.x;
  if (i >= n) return;
  float y[D];
#pragma unroll
  for (int c = 0; c < D; c++) y[c] = Bl[c];
  const float* a = ztA + (size_t)i * D;
  const float* b = ztB + (size_t)i * D;
  for (int k = 0; k < D; k++) {
    float z = fmaxf(a[k] * sc[k] + sh[k], 0.f);
#pragma unroll
    for (int c = 0; c < D; c++) y[c] += z * Wl[k * D + c];
  }
  for (int k = D; k < DD; k++) {
    float z = fmaxf(b[k - D] * sc[k] + sh[k], 0.f);
#pragma unroll
    for (int c = 0; c < D; c++) y[c] += z * Wl[k * D + c];
  }
  float acc[O];
#pragma unroll
  for (int o = 0; o < O; o++) acc[o] = Bsl[o];
#pragma unroll
  for (int k = 0; k < D; k++) {
    float z = fmaxf(y[k], 0.f);
#pragma unroll
    for (int o = 0; o < O; o++) acc[o] += z * Ws[k * O + o];
  }
  float dv = SCALE ? dinv[i] : 1.f;
  if (WOUT) {
    float* yo = out + (size_t)i * O;
#pragma unroll
    for (int o = 0; o < O; o++) yo[o] = SCALE ? acc[o] * dv : acc[o];
  }
  if (WBF) {
    u16* yb = outbf + (size_t)i * O;
#pragma unroll
    for (int o = 0; o < O; o++) yb[o] = f2bf(SCALE ? acc[o] * dv : acc[o]);
  }
}

// ---- GCN heads: bf16 CSR gather of pre-scaled rows, chunk-4, fused store ----
__global__ void k_gcn(const u32* __restrict__ rowptr, const int* __restrict__ csr_src,
                      const u16* __restrict__ yzbf, const float* __restrict__ dinv,
                      const float* __restrict__ bmu, const float* __restrict__ bls,
                      float* __restrict__ out, int n) {
  int c    = threadIdx.x & 31;
  int node = (blockIdx.x * blockDim.x + threadIdx.x) >> 5;
  if (node >= n) return;
  u32 b = rowptr[node], t = rowptr[node + 1];
  float acc = 0.f;
  u32 i = b;
  for (; i + 4 <= t; i += 4) {
    int s0 = csr_src[i + 0];
    int s1 = csr_src[i + 1];
    int s2 = csr_src[i + 2];
    int s3 = csr_src[i + 3];
    float y0 = bf1(yzbf[(size_t)s0 * 32 + c]);
    float y1 = bf1(yzbf[(size_t)s1 * 32 + c]);
    float y2 = bf1(yzbf[(size_t)s2 * 32 + c]);
    float y3 = bf1(yzbf[(size_t)s3 * 32 + c]);
    acc += (y0 + y1) + (y2 + y3);
  }
  for (; i < t; i++) acc += bf1(yzbf[(size_t)csr_src[i] * 32 + c]);
  float dv  = dinv[node];
  float val = (acc + bf1(yzbf[(size_t)node * 32 + c])) * dv +
              ((c < 16) ? bmu[c] : bls[c - 16]);
  if (c < 16) out[(size_t)node * 16 + c] = val;
  else        out[(size_t)n * 16 + (size_t)node * 16 + (c - 16)] = val;
}

extern "C" void kernel_launch(void* const* d_in, const int* in_sizes, int n_in,
                              void* d_out, int out_size, void* d_ws, size_t ws_size,
                              hipStream_t stream) {
  const float* x      = (const float*)d_in[0];
  const int*  ei      = (const int*)d_in[1];          // int32 (2,E) rows
  const float* ea     = (const float*)d_in[2];
  const float* w_src1 = (const float*)d_in[3];  const float* b_src1 = (const float*)d_in[4];
  const float* w_edge1= (const float*)d_in[5];  const float* b_edge1= (const float*)d_in[6];
  const float* w_m1a  = (const float*)d_in[7];  const float* b_m1a  = (const float*)d_in[8];
  const float* g1     = (const float*)d_in[9];  const float* be1    = (const float*)d_in[10];
  const float* w_m1b  = (const float*)d_in[11]; const float* b_m1b  = (const float*)d_in[12];
  const float* w_src2 = (const float*)d_in[13]; const float* b_src2 = (const float*)d_in[14];
  const float* w_edge2= (const float*)d_in[15]; const float* b_edge2= (const float*)d_in[16];
  const float* w_m2a  = (const float*)d_in[17]; const float* b_m2a  = (const float*)d_in[18];
  const float* g2     = (const float*)d_in[19]; const float* be2    = (const float*)d_in[20];
  const float* w_m2b  = (const float*)d_in[21]; const float* b_m2b  = (const float*)d_in[22];
  const float* w_mu   = (const float*)d_in[23]; const float* b_mu   = (const float*)d_in[24];
  const float* w_ls   = (const float*)d_in[25]; const float* b_ls   = (const float*)d_in[26];

  const int N = in_sizes[0] / 64;
  const int E = in_sizes[1] / 2;

  const int NB  = (N + 255) / 256;
  const int EB  = (E + 255) / 256;
  const int SB1 = (N + 1023) / 1024;

  float* ws     = (float*)d_ws;
  size_t N48    = (size_t)N * 48;
  float* P0     = ws;
  float* P1     = ws + N48;
  float* P2     = ws + 2 * N48;
  float* P3     = ws + 3 * N48;
  size_t o      = 4 * N48;
  u32*  rowptr  = (u32*)(ws + o);            // N+1
  u32*  cnt     = rowptr + (N + 1);          // N
  u32*  deg     = cnt + N;                   // N
  u32*  part    = deg + N;                   // 256
  float* dinv   = (float*)(part + 256);      // N
  float* stats  = dinv + N;                  // 512
  size_t po     = o + 4 * (size_t)N + 769;
  float* partial= ws + po;                   // NB*192
  size_t co     = (po + (size_t)NB * 192 + 3) & ~(size_t)3;
  int*  csr_src = (int*)(ws + co);           // E ints
  int*  csr_eid = csr_src + E;               // E ints
  size_t eo     = co + 2 * (size_t)E;        // 16B-aligned
  u32*  eaperm  = (u32*)(ws + eo);           // 8E u32 (f16-packed attrs)
  size_t ho     = eo + 8 * (size_t)E;
  u16*  hbf1    = (u16*)(ws + ho);           // N*48 u16
  size_t h2o    = ho + 24 * (size_t)N;
  u16*  hbf2    = (u16*)(ws + h2o);          // N*32 u16 (agg32 in; then yzd bf16)
  size_t needB  = (h2o + 16 * (size_t)N + 16) * sizeof(float);
  const bool PERM = (ws_size >= needB);

  dim3 b256(256);

  hipMemsetAsync(cnt, 0, 2 * (size_t)N * sizeof(u32), stream);

  // CSR build
  k_deg<<<EB, b256, 0, stream>>>(ei, deg, E);
  k_scan1<<<SB1, b256, 0, stream>>>(deg, rowptr, part, N);
  k_scan2<<<1, 64, 0, stream>>>(part, SB1);
  k_scan3<<<NB, b256, 0, stream>>>(rowptr, part, deg, dinv, N, E);
  k_slots<<<EB, b256, 0, stream>>>(ei, rowptr, cnt, csr_src, csr_eid, E);
  if (PERM) k_gather<<<EB, b256, 0, stream>>>(csr_eid, ea, eaperm, E);

  // ---- GENConv 1 (64 -> 48) ----
  if (PERM) k_lin<64, 48, true><<<NB, b256, 0, stream>>>(x, w_src1, b_src1, P0, hbf1, 48, N);
  else      k_lin<64, 48, false><<<NB, b256, 0, stream>>>(x, w_src1, b_src1, P0, nullptr, 48, N);
  if (PERM) k_agg48<true><<<(N * 64 + 255) / 256, b256, 0, stream>>>(rowptr, csr_src,
                       csr_eid, eaperm, ea, w_edge1, b_edge1, P0, hbf1, P3, N);
  else      k_agg48<false><<<(N * 64 + 255) / 256, b256, 0, stream>>>(rowptr, csr_src,
                       csr_eid, eaperm, ea, w_edge1, b_edge1, P0, hbf1, P3, N);
  k_ztstats<48><<<NB, b256, 0, stream>>>(P3, w_m1a, b_m1a, P1, P2, partial, N);
  k_bnfin<<<1, 256, 0, stream>>>(partial, stats, NB, 192);
  if (PERM)
    k_mlp_lin<48, 96, 32, true, true, false, true><<<NB, b256, 0, stream>>>(P1, P2, stats,
                       g1, be1, w_m1b, b_m1b, w_src2, nullptr, b_src2, nullptr, P0, hbf2,
                       1.0f / (float)N, N);
  else
    k_mlp_lin<48, 96, 32, true, false, false, true><<<NB, b256, 0, stream>>>(P1, P2, stats,
                       g1, be1, w_m1b, b_m1b, w_src2, nullptr, b_src2, nullptr, P0, nullptr,
                       1.0f / (float)N, N);

  // ---- GENConv 2 (48 -> 32) ----
  if (PERM) k_agg32<true><<<(N * 32 + 255) / 256, b256, 0, stream>>>(rowptr, csr_src,
                       csr_eid, eaperm, ea, w_edge2, b_edge2, P0, hbf2, P3, N);
  else      k_agg32<false><<<(N * 32 + 255) / 256, b256, 0, stream>>>(rowptr, csr_src,
                       csr_eid, eaperm, ea, w_edge2, b_edge2, P0, hbf2, P3, N);
  k_ztstats<32><<<NB, b256, 0, stream>>>(P3, w_m2a, b_m2a, P1, P2, partial, N);
  k_bnfin<<<1, 256, 0, stream>>>(partial, stats + 256, NB, 128);
  if (PERM)  // heads output written ONLY as dinv-scaled bf16 (hbf2 is free now)
    k_mlp_lin<32, 64, 32, false, true, true, false><<<NB, b256, 0, stream>>>(P1, P2,
                       stats + 256, g2, be2, w_m2b, b_m2b, w_mu, w_ls, nullptr, dinv,
                       nullptr, hbf2, 1.0f / (float)N, N);
  else
    k_mlp_lin<32, 64, 32, false, true, true, false><<<NB, b256, 0, stream>>>(P1, P2,
                       stats + 256, g2, be2, w_m2b, b_m2b, w_mu, w_ls, nullptr, dinv,
                       nullptr, hbf2, 1.0f / (float)N, N);

  // ---- GCN heads ----
  k_gcn<<<(N * 32 + 255) / 256, b256, 0, stream>>>(rowptr, csr_src, hbf2, dinv,
                                                   b_mu, b_ls, (float*)d_out, N);
}

// Round 22
// 898.099 us; speedup vs baseline: 1.4571x; 1.0149x over previous
//
#include <hip/hip_runtime.h>
#include <hip/hip_bf16.h>

typedef unsigned int u32;
typedef unsigned short u16;
typedef _Float16 h2 __attribute__((ext_vector_type(2)));

#define EPS_MSG 1e-7f
#define BN_EPS  1e-5f

__device__ __forceinline__ u16 f2bf(float f) {          // round-to-nearest-even
  u32 u = __float_as_uint(f);
  return (u16)((u + 0x7FFFu + ((u >> 16) & 1u)) >> 16);
}
__device__ __forceinline__ float bf1(u16 v) { return __uint_as_float(((u32)v) << 16); }
__device__ __forceinline__ h2 u2h(u32 v) { union { u32 u; h2 h; } t; t.u = v; return t.h; }

// pack two f32 -> pk f16 pair as raw u32 (via __fp16 vector return type)
__device__ __forceinline__ u32 pkrtz(float a, float b) {
  union { __fp16 v __attribute__((ext_vector_type(2))); u32 u; } t;
  t.v = __builtin_amdgcn_cvt_pkrtz(a, b);
  return t.u;
}

// 8 f16 pairs (one uint4) dotted against packed weights via v_dot2_f32_f16
__device__ __forceinline__ float dot8(uint4 v, const u32* w, float acc) {
  acc = __builtin_amdgcn_fdot2(u2h(v.x), u2h(w[0]), acc, false);
  acc = __builtin_amdgcn_fdot2(u2h(v.y), u2h(w[1]), acc, false);
  acc = __builtin_amdgcn_fdot2(u2h(v.z), u2h(w[2]), acc, false);
  acc = __builtin_amdgcn_fdot2(u2h(v.w), u2h(w[3]), acc, false);
  return acc;
}

#define EDGE_DOT(A0,A1,A2,A3) (bias + \
  A0.x * wc[0]  + A0.y * wc[1]  + A0.z * wc[2]  + A0.w * wc[3] + \
  A1.x * wc[4]  + A1.y * wc[5]  + A1.z * wc[6]  + A1.w * wc[7] + \
  A2.x * wc[8]  + A2.y * wc[9]  + A2.z * wc[10] + A2.w * wc[11] + \
  A3.x * wc[12] + A3.y * wc[13] + A3.z * wc[14] + A3.w * wc[15])

// ---- small linear: Y[i*ldY+c] = X[i,:]·W[:,c] + B[c]; optional bf16 shadow --
template<int I, int O, bool WBF>
__global__ void k_lin(const float* __restrict__ X, const float* __restrict__ W,
                      const float* __restrict__ B, float* __restrict__ Y,
                      u16* __restrict__ Ybf, int ldY, int n) {
  __shared__ float Wl[I * O];
  __shared__ float Bl[O];
  for (int t = threadIdx.x; t < I * O; t += blockDim.x) Wl[t] = W[t];
  if (threadIdx.x < O) Bl[threadIdx.x] = B[threadIdx.x];
  __syncthreads();
  int i = blockIdx.x * blockDim.x + threadIdx.x;
  if (i >= n) return;
  float acc[O];
#pragma unroll
  for (int c = 0; c < O; c++) acc[c] = Bl[c];
  const float4* xp = (const float4*)(X + (size_t)i * I);
  for (int q = 0; q < I / 4; q++) {
    float4 v = xp[q];
#pragma unroll
    for (int c = 0; c < O; c++) acc[c] += v.x * Wl[(4 * q + 0) * O + c];
#pragma unroll
    for (int c = 0; c < O; c++) acc[c] += v.y * Wl[(4 * q + 1) * O + c];
#pragma unroll
    for (int c = 0; c < O; c++) acc[c] += v.z * Wl[(4 * q + 2) * O + c];
#pragma unroll
    for (int c = 0; c < O; c++) acc[c] += v.w * Wl[(4 * q + 3) * O + c];
  }
  float* y = Y + (size_t)i * ldY;
#pragma unroll
  for (int c = 0; c < O; c++) y[c] = acc[c];
  if (WBF) {
    u16* yb = Ybf + (size_t)i * O;
#pragma unroll
    for (int c = 0; c < O; c++) yb[c] = f2bf(acc[c]);
  }
}

// ---- CSR construction -------------------------------------------------------
__global__ void k_deg(const int* __restrict__ ei, u32* __restrict__ deg, int E) {
  int e = blockIdx.x * blockDim.x + threadIdx.x;
  if (e < E) atomicAdd(&deg[ei[E + e]], 1u);
}

__global__ void k_scan1(const u32* __restrict__ deg, u32* __restrict__ excl,
                        u32* __restrict__ part, int n) {
  __shared__ u32 sm[256];
  int t = threadIdx.x;
  int base = blockIdx.x * 1024 + t * 4;
  u32 v0 = (base + 0 < n) ? deg[base + 0] : 0u;
  u32 v1 = (base + 1 < n) ? deg[base + 1] : 0u;
  u32 v2 = (base + 2 < n) ? deg[base + 2] : 0u;
  u32 v3 = (base + 3 < n) ? deg[base + 3] : 0u;
  u32 tsum = v0 + v1 + v2 + v3;
  sm[t] = tsum;
  __syncthreads();
  for (int o = 1; o < 256; o <<= 1) {
    u32 v = (t >= o) ? sm[t - o] : 0u;
    __syncthreads();
    sm[t] += v;
    __syncthreads();
  }
  u32 tex = sm[t] - tsum;
  if (t == 255) part[blockIdx.x] = sm[255];
  if (base + 0 < n) excl[base + 0] = tex;
  if (base + 1 < n) excl[base + 1] = tex + v0;
  if (base + 2 < n) excl[base + 2] = tex + v0 + v1;
  if (base + 3 < n) excl[base + 3] = tex + v0 + v1 + v2;
}

__global__ void k_scan2(u32* __restrict__ part, int nb) {
  if (threadIdx.x == 0) {
    u32 acc = 0;
    for (int i = 0; i < nb; i++) { u32 v = part[i]; part[i] = acc; acc += v; }
  }
}

// scan finalize + dinv fused
__global__ void k_scan3(u32* __restrict__ rowptr, const u32* __restrict__ part,
                        const u32* __restrict__ deg, float* __restrict__ dinv,
                        int n, int E) {
  int i = blockIdx.x * blockDim.x + threadIdx.x;
  if (i < n) {
    rowptr[i] += part[i >> 10];
    dinv[i] = rsqrtf((float)(deg[i] + 1u));
  }
  if (i == 0) rowptr[n] = (u32)E;
}

__global__ void k_slots(const int* __restrict__ ei, const u32* __restrict__ rowptr,
                        u32* __restrict__ cnt, int* __restrict__ csr_src,
                        int* __restrict__ csr_eid, int E) {
  int e = blockIdx.x * blockDim.x + threadIdx.x;
  if (e >= E) return;
  int s = ei[e], d = ei[E + e];
  u32 slot = rowptr[d] + atomicAdd(&cnt[d], 1u);
  csr_src[slot] = s;
  csr_eid[slot] = e;
}

// slot-major attr permute, packed f16: 32B/edge, v_cvt_pkrtz packing
__global__ void k_gather(const int* __restrict__ csr_eid, const float* __restrict__ ea,
                         u32* __restrict__ eaperm, int E) {
  int i = blockIdx.x * blockDim.x + threadIdx.x;
  if (i >= E) return;
  int e = csr_eid[i];
  const float4* p = (const float4*)(ea + (size_t)e * 16);
  float4 a = p[0], b = p[1], c = p[2], d = p[3];
  uint4* q = (uint4*)(eaperm + (size_t)i * 8);
  uint4 w0, w1;
  w0.x = pkrtz(a.x, a.y);
  w0.y = pkrtz(a.z, a.w);
  w0.z = pkrtz(b.x, b.y);
  w0.w = pkrtz(b.z, b.w);
  w1.x = pkrtz(c.x, c.y);
  w1.y = pkrtz(c.z, c.w);
  w1.z = pkrtz(d.x, d.y);
  w1.w = pkrtz(d.z, d.w);
  q[0] = w0; q[1] = w1;
}

// ---- GENConv agg d=48: wave/node; csr preloaded into lanes, readlane fetch --
// (readlane is legal here: j is wave-uniform since the whole wave = one node)
template<bool PERM>
__global__ void k_agg48(const u32* __restrict__ rowptr, const int* __restrict__ csr_src,
                        const int* __restrict__ csr_eid, const u32* __restrict__ eaperm,
                        const float* __restrict__ ea,
                        const float* __restrict__ we, const float* __restrict__ be,
                        const float* __restrict__ h, const u16* __restrict__ hbf,
                        float* __restrict__ out, int n) {
  int lane = threadIdx.x & 63;
  int cl   = (lane < 48) ? lane : lane - 48;   // lanes 48-63 duplicate ch 0-15
  int node = (blockIdx.x * blockDim.x + threadIdx.x) >> 6;
  if (node >= n) return;
  float bias = be[cl];
  float hself = h[(size_t)node * 48 + cl];
  u32 b = rowptr[node], t = rowptr[node + 1];
  u32 dn = t - b;
  float den = 0.f, num = 0.f;
  if (PERM) {
    u32 wcp[8];
#pragma unroll
    for (int k = 0; k < 8; k++)
      wcp[k] = pkrtz(we[(2 * k + 0) * 48 + cl], we[(2 * k + 1) * 48 + cl]);
    u32 nf = dn < 64u ? dn : 64u;
    int vcsr = ((u32)lane < nf) ? csr_src[b + lane] : 0;   // one vector load
    u32 j = 0;
    for (; j + 2 <= nf; j += 2) {
      int s0 = __builtin_amdgcn_readlane(vcsr, j);
      int s1 = __builtin_amdgcn_readlane(vcsr, j + 1);
      float h0 = bf1(hbf[(size_t)s0 * 48 + cl]);
      float h1 = bf1(hbf[(size_t)s1 * 48 + cl]);
      const uint4* pa = (const uint4*)(eaperm + (size_t)(b + j) * 8);
      uint4 a0 = pa[0], a1 = pa[1];
      uint4 b0 = pa[2], b1 = pa[3];
      float ml0 = dot8(a1, wcp + 4, dot8(a0, wcp, bias));
      float ml1 = dot8(b1, wcp + 4, dot8(b0, wcp, bias));
      float m0 = fmaxf(h0 + ml0, 0.f) + EPS_MSG;
      float m1 = fmaxf(h1 + ml1, 0.f) + EPS_MSG;
      float ex0 = __expf(m0);
      float ex1 = __expf(m1);
      den += ex0 + ex1;
      num += ex0 * m0 + ex1 * m1;
    }
    for (; j < nf; j++) {
      int s = __builtin_amdgcn_readlane(vcsr, j);
      const uint4* pa = (const uint4*)(eaperm + (size_t)(b + j) * 8);
      uint4 a0 = pa[0], a1 = pa[1];
      float hv = bf1(hbf[(size_t)s * 48 + cl]);
      float ml = dot8(a1, wcp + 4, dot8(a0, wcp, bias));
      float m  = fmaxf(hv + ml, 0.f) + EPS_MSG;
      float ex = __expf(m);
      den += ex; num += ex * m;
    }
    for (u32 i = b + nf; i < t; i++) {       // deg > 64 tail (rare)
      int s = csr_src[i];
      const uint4* pa = (const uint4*)(eaperm + (size_t)i * 8);
      uint4 a0 = pa[0], a1 = pa[1];
      float hv = bf1(hbf[(size_t)s * 48 + cl]);
      float ml = dot8(a1, wcp + 4, dot8(a0, wcp, bias));
      float m  = fmaxf(hv + ml, 0.f) + EPS_MSG;
      float ex = __expf(m);
      den += ex; num += ex * m;
    }
  } else {
    float wc[16];
#pragma unroll
    for (int k = 0; k < 16; k++) wc[k] = we[k * 48 + cl];
    for (u32 i = b; i < t; i++) {
      int s = csr_src[i];
      const float4* p = (const float4*)(ea + (size_t)csr_eid[i] * 16);
      float4 a0 = p[0], a1 = p[1], a2 = p[2], a3 = p[3];
      float hv = h[(size_t)s * 48 + cl];
      float ml = EDGE_DOT(a0, a1, a2, a3);
      float m  = fmaxf(hv + ml, 0.f) + EPS_MSG;
      float ex = __expf(m);
      den += ex; num += ex * m;
    }
  }
  if (lane < 48)
    out[(size_t)node * 48 + lane] = hself + num / (den + 1e-16f);
}

// ---- GENConv agg d=32: half-wave/node; csr preload + __shfl (per-lane idx) --
// __shfl lowers to ds_bpermute: legal with the divergent j across half-waves;
// each half only reads its own 32 lanes, so sources are always active.
template<bool PERM>
__global__ void k_agg32(const u32* __restrict__ rowptr, const int* __restrict__ csr_src,
                        const int* __restrict__ csr_eid, const u32* __restrict__ eaperm,
                        const float* __restrict__ ea,
                        const float* __restrict__ we, const float* __restrict__ be,
                        const float* __restrict__ h, const u16* __restrict__ hbf,
                        float* __restrict__ out, int n) {
  int lane = threadIdx.x & 63;
  int c    = lane & 31;
  int half = (lane >> 5) & 1;                 // 0 or 1: which half-wave
  int node = (blockIdx.x * blockDim.x + threadIdx.x) >> 5;
  if (node >= n) return;
  float bias = be[c];
  float hself = h[(size_t)node * 32 + c];
  u32 b = rowptr[node], t = rowptr[node + 1];
  u32 dn = t - b;
  float den = 0.f, num = 0.f;
  if (PERM) {
    u32 wcp[8];
#pragma unroll
    for (int k = 0; k < 8; k++)
      wcp[k] = pkrtz(we[(2 * k + 0) * 32 + c], we[(2 * k + 1) * 32 + c]);
    u32 nf = dn < 32u ? dn : 32u;
    int vcsr = ((u32)c < nf) ? csr_src[b + c] : 0;   // half-wave preload
    int lbase = half << 5;                           // this half's lane base
    u32 j = 0;
    for (; j + 2 <= nf; j += 2) {
      int s0 = __shfl(vcsr, lbase + (int)j);
      int s1 = __shfl(vcsr, lbase + (int)j + 1);
      float h0 = bf1(hbf[(size_t)s0 * 32 + c]);
      float h1 = bf1(hbf[(size_t)s1 * 32 + c]);
      const uint4* pa = (const uint4*)(eaperm + (size_t)(b + j) * 8);
      uint4 a0 = pa[0], a1 = pa[1];
      uint4 b0 = pa[2], b1 = pa[3];
      float ml0 = dot8(a1, wcp + 4, dot8(a0, wcp, bias));
      float ml1 = dot8(b1, wcp + 4, dot8(b0, wcp, bias));
      float m0 = fmaxf(h0 + ml0, 0.f) + EPS_MSG;
      float m1 = fmaxf(h1 + ml1, 0.f) + EPS_MSG;
      float ex0 = __expf(m0);
      float ex1 = __expf(m1);
      den += ex0 + ex1;
      num += ex0 * m0 + ex1 * m1;
    }
    for (; j < nf; j++) {
      int s = __shfl(vcsr, lbase + (int)j);
      const uint4* pa = (const uint4*)(eaperm + (size_t)(b + j) * 8);
      uint4 a0 = pa[0], a1 = pa[1];
      float hv = bf1(hbf[(size_t)s * 32 + c]);
      float ml = dot8(a1, wcp + 4, dot8(a0, wcp, bias));
      float m  = fmaxf(hv + ml, 0.f) + EPS_MSG;
      float ex = __expf(m);
      den += ex; num += ex * m;
    }
    for (u32 i = b + nf; i < t; i++) {        // deg > 32 tail
      int s = csr_src[i];
      const uint4* pa = (const uint4*)(eaperm + (size_t)i * 8);
      uint4 a0 = pa[0], a1 = pa[1];
      float hv = bf1(hbf[(size_t)s * 32 + c]);
      float ml = dot8(a1, wcp + 4, dot8(a0, wcp, bias));
      float m  = fmaxf(hv + ml, 0.f) + EPS_MSG;
      float ex = __expf(m);
      den += ex; num += ex * m;
    }
  } else {
    float wc[16];
#pragma unroll
    for (int k = 0; k < 16; k++) wc[k] = we[k * 32 + c];
    for (u32 i = b; i < t; i++) {
      int s = csr_src[i];
      const float4* p = (const float4*)(ea + (size_t)csr_eid[i] * 16);
      float4 a0 = p[0], a1 = p[1], a2 = p[2], a3 = p[3];
      float hv = h[(size_t)s * 32 + c];
      float ml = EDGE_DOT(a0, a1, a2, a3);
      float m  = fmaxf(hv + ml, 0.f) + EPS_MSG;
      float ex = __expf(m);
      den += ex; num += ex * m;
    }
  }
  out[(size_t)node * 32 + c] = hself + num / (den + 1e-16f);
}

// ---- zt = X@W1 + B1 (split panels) + per-block BN-stat partials -------------
template<int D>
__global__ void k_ztstats(const float* __restrict__ X, const float* __restrict__ W,
                          const float* __restrict__ B, float* __restrict__ Z1,
                          float* __restrict__ Z2, float* __restrict__ partial, int n) {
  __shared__ float Wl[D * 2 * D];
  __shared__ float Bl[2 * D];
  __shared__ float red[4][4 * D];
  for (int t = threadIdx.x; t < D * 2 * D; t += blockDim.x) Wl[t] = W[t];
  for (int t = threadIdx.x; t < 2 * D; t += blockDim.x) Bl[t] = B[t];
  __syncthreads();
  int i = blockIdx.x * blockDim.x + threadIdx.x;
  bool act = (i < n);
  float acc[2 * D];
#pragma unroll
  for (int c = 0; c < 2 * D; c++) acc[c] = 0.f;
  if (act) {
#pragma unroll
    for (int c = 0; c < 2 * D; c++) acc[c] = Bl[c];
    const float4* xp = (const float4*)(X + (size_t)i * D);
    for (int q = 0; q < D / 4; q++) {
      float4 v = xp[q];
#pragma unroll
      for (int c = 0; c < 2 * D; c++) acc[c] += v.x * Wl[(4 * q + 0) * 2 * D + c];
#pragma unroll
      for (int c = 0; c < 2 * D; c++) acc[c] += v.y * Wl[(4 * q + 1) * 2 * D + c];
#pragma unroll
      for (int c = 0; c < 2 * D; c++) acc[c] += v.z * Wl[(4 * q + 2) * 2 * D + c];
#pragma unroll
      for (int c = 0; c < 2 * D; c++) acc[c] += v.w * Wl[(4 * q + 3) * 2 * D + c];
    }
    float* z1 = Z1 + (size_t)i * D;
    float* z2 = Z2 + (size_t)i * D;
#pragma unroll
    for (int c = 0; c < D; c++) { z1[c] = acc[c]; z2[c] = acc[D + c]; }
  } else {
#pragma unroll
    for (int c = 0; c < 2 * D; c++) acc[c] = 0.f;
  }
  int lane = threadIdx.x & 63;
  int wv   = threadIdx.x >> 6;
#pragma unroll
  for (int c = 0; c < 2 * D; c++) {
    float v = acc[c], v2 = v * v;
#pragma unroll
    for (int o = 32; o; o >>= 1) { v += __shfl_xor(v, o); v2 += __shfl_xor(v2, o); }
    if (lane == 0) { red[wv][c] = v; red[wv][2 * D + c] = v2; }
  }
  __syncthreads();
  if (threadIdx.x < 4 * D) {
    float s = red[0][threadIdx.x] + red[1][threadIdx.x] +
              red[2][threadIdx.x] + red[3][threadIdx.x];
    partial[(size_t)blockIdx.x * 4 * D + threadIdx.x] = s;
  }
}

__global__ void k_bnfin(const float* __restrict__ partial, float* __restrict__ stats,
                        int nb, int m) {
  int c = blockIdx.x * blockDim.x + threadIdx.x;
  if (c >= m) return;
  float s = 0.f;
  for (int b = 0; b < nb; b++) s += partial[(size_t)b * m + c];
  stats[c] = s;
}

// ---- BN -> relu -> @W2+b2 -> relu -> @Ws(+Bs); WOUT f32 / WBF bf16(scaled) --
template<int D, int DD, int O, bool ADDBS, bool WBF, bool SCALE, bool WOUT>
__global__ void k_mlp_lin(const float* __restrict__ ztA, const float* __restrict__ ztB,
                          const float* __restrict__ stats,
                          const float* __restrict__ G, const float* __restrict__ BE,
                          const float* __restrict__ W2, const float* __restrict__ B2,
                          const float* __restrict__ Wsa, const float* __restrict__ Wsb,
                          const float* __restrict__ Bs, const float* __restrict__ dinv,
                          float* __restrict__ out, u16* __restrict__ outbf,
                          float invN, int n) {
  __shared__ float Wl[DD * D];
  __shared__ float Ws[D * O];
  __shared__ float Bl[D];
  __shared__ float Bsl[O];
  __shared__ float sc[DD], sh[DD];
  for (int t = threadIdx.x; t < DD * D; t += blockDim.x) Wl[t] = W2[t];
  if (Wsb == nullptr) {
    for (int t = threadIdx.x; t < D * O; t += blockDim.x) Ws[t] = Wsa[t];
  } else {
    for (int t = threadIdx.x; t < D * O; t += blockDim.x) {
      int k = t / O, o = t % O;
      Ws[t] = (o < O / 2) ? Wsa[k * (O / 2) + o] : Wsb[k * (O / 2) + (o - O / 2)];
    }
  }
  if (threadIdx.x < D) Bl[threadIdx.x] = B2[threadIdx.x];
  if (threadIdx.x < O) Bsl[threadIdx.x] = ADDBS ? Bs[threadIdx.x] : 0.f;
  if (threadIdx.x < DD) {
    int c   = threadIdx.x;
    float m = stats[c] * invN;
    float v = stats[DD + c] * invN - m * m;
    float s = G[c] * rsqrtf(v + BN_EPS);
    sc[c] = s; sh[c] = BE[c] - m * s;
  }
  __syncthreads();
  int i = blockIdx.x * blockDim.x + threadIdx.x;
  if (i >= n) return;
  float y[D];
#pragma unroll
  for (int c = 0; c < D; c++) y[c] = Bl[c];
  const float* a = ztA + (size_t)i * D;
  const float* b = ztB + (size_t)i * D;
  for (int k = 0; k < D; k++) {
    float z = fmaxf(a[k] * sc[k] + sh[k], 0.f);
#pragma unroll
    for (int c = 0; c < D; c++) y[c] += z * Wl[k * D + c];
  }
  for (int k = D; k < DD; k++) {
    float z = fmaxf(b[k - D] * sc[k] + sh[k], 0.f);
#pragma unroll
    for (int c = 0; c < D; c++) y[c] += z * Wl[k * D + c];
  }
  float acc[O];
#pragma unroll
  for (int o = 0; o < O; o++) acc[o] = Bsl[o];
#pragma unroll
  for (int k = 0; k < D; k++) {
    float z = fmaxf(y[k], 0.f);
#pragma unroll
    for (int o = 0; o < O; o++) acc[o] += z * Ws[k * O + o];
  }
  float dv = SCALE ? dinv[i] : 1.f;
  if (WOUT) {
    float* yo = out + (size_t)i * O;
#pragma unroll
    for (int o = 0; o < O; o++) yo[o] = SCALE ? acc[o] * dv : acc[o];
  }
  if (WBF) {
    u16* yb = outbf + (size_t)i * O;
#pragma unroll
    for (int o = 0; o < O; o++) yb[o] = f2bf(SCALE ? acc[o] * dv : acc[o]);
  }
}

// ---- GCN heads: bf16 CSR gather, csr preload + __shfl, fused store ----------
__global__ void k_gcn(const u32* __restrict__ rowptr, const int* __restrict__ csr_src,
                      const u16* __restrict__ yzbf, const float* __restrict__ dinv,
                      const float* __restrict__ bmu, const float* __restrict__ bls,
                      float* __restrict__ out, int n) {
  int lane = threadIdx.x & 63;
  int c    = lane & 31;
  int half = (lane >> 5) & 1;
  int node = (blockIdx.x * blockDim.x + threadIdx.x) >> 5;
  if (node >= n) return;
  u32 b = rowptr[node], t = rowptr[node + 1];
  u32 dn = t - b;
  u32 nf = dn < 32u ? dn : 32u;
  int vcsr = ((u32)c < nf) ? csr_src[b + c] : 0;
  int lbase = half << 5;
  float acc = 0.f;
  u32 j = 0;
  for (; j + 2 <= nf; j += 2) {
    int s0 = __shfl(vcsr, lbase + (int)j);
    int s1 = __shfl(vcsr, lbase + (int)j + 1);
    float y0 = bf1(yzbf[(size_t)s0 * 32 + c]);
    float y1 = bf1(yzbf[(size_t)s1 * 32 + c]);
    acc += y0 + y1;
  }
  for (; j < nf; j++) {
    int s = __shfl(vcsr, lbase + (int)j);
    acc += bf1(yzbf[(size_t)s * 32 + c]);
  }
  for (u32 i = b + nf; i < t; i++) acc += bf1(yzbf[(size_t)csr_src[i] * 32 + c]);
  float dv  = dinv[node];
  float val = (acc + bf1(yzbf[(size_t)node * 32 + c])) * dv +
              ((c < 16) ? bmu[c] : bls[c - 16]);
  if (c < 16) out[(size_t)node * 16 + c] = val;
  else        out[(size_t)n * 16 + (size_t)node * 16 + (c - 16)] = val;
}

extern "C" void kernel_launch(void* const* d_in, const int* in_sizes, int n_in,
                              void* d_out, int out_size, void* d_ws, size_t ws_size,
                              hipStream_t stream) {
  const float* x      = (const float*)d_in[0];
  const int*  ei      = (const int*)d_in[1];          // int32 (2,E) rows
  const float* ea     = (const float*)d_in[2];
  const float* w_src1 = (const float*)d_in[3];  const float* b_src1 = (const float*)d_in[4];
  const float* w_edge1= (const float*)d_in[5];  const float* b_edge1= (const float*)d_in[6];
  const float* w_m1a  = (const float*)d_in[7];  const float* b_m1a  = (const float*)d_in[8];
  const float* g1     = (const float*)d_in[9];  const float* be1    = (const float*)d_in[10];
  const float* w_m1b  = (const float*)d_in[11]; const float* b_m1b  = (const float*)d_in[12];
  const float* w_src2 = (const float*)d_in[13]; const float* b_src2 = (const float*)d_in[14];
  const float* w_edge2= (const float*)d_in[15]; const float* b_edge2= (const float*)d_in[16];
  const float* w_m2a  = (const float*)d_in[17]; const float* b_m2a  = (const float*)d_in[18];
  const float* g2     = (const float*)d_in[19]; const float* be2    = (const float*)d_in[20];
  const float* w_m2b  = (const float*)d_in[21]; const float* b_m2b  = (const float*)d_in[22];
  const float* w_mu   = (const float*)d_in[23]; const float* b_mu   = (const float*)d_in[24];
  const float* w_ls   = (const float*)d_in[25]; const float* b_ls   = (const float*)d_in[26];

  const int N = in_sizes[0] / 64;
  const int E = in_sizes[1] / 2;

  const int NB  = (N + 255) / 256;
  const int EB  = (E + 255) / 256;
  const int SB1 = (N + 1023) / 1024;

  float* ws     = (float*)d_ws;
  size_t N48    = (size_t)N * 48;
  float* P0     = ws;
  float* P1     = ws + N48;
  float* P2     = ws + 2 * N48;
  float* P3     = ws + 3 * N48;
  size_t o      = 4 * N48;
  u32*  rowptr  = (u32*)(ws + o);            // N+1
  u32*  cnt     = rowptr + (N + 1);          // N
  u32*  deg     = cnt + N;                   // N
  u32*  part    = deg + N;                   // 256
  float* dinv   = (float*)(part + 256);      // N
  float* stats  = dinv + N;                  // 512
  size_t po     = o + 4 * (size_t)N + 769;
  float* partial= ws + po;                   // NB*192
  size_t co     = (po + (size_t)NB * 192 + 3) & ~(size_t)3;
  int*  csr_src = (int*)(ws + co);           // E ints
  int*  csr_eid = csr_src + E;               // E ints
  size_t eo     = co + 2 * (size_t)E;        // 16B-aligned
  u32*  eaperm  = (u32*)(ws + eo);           // 8E u32 (f16-packed attrs)
  size_t ho     = eo + 8 * (size_t)E;
  u16*  hbf1    = (u16*)(ws + ho);           // N*48 u16
  size_t h2o    = ho + 24 * (size_t)N;
  u16*  hbf2    = (u16*)(ws + h2o);          // N*32 u16 (agg32 in; then yzd bf16)
  size_t needB  = (h2o + 16 * (size_t)N + 16) * sizeof(float);
  const bool PERM = (ws_size >= needB);

  dim3 b256(256);

  hipMemsetAsync(cnt, 0, 2 * (size_t)N * sizeof(u32), stream);

  // CSR build
  k_deg<<<EB, b256, 0, stream>>>(ei, deg, E);
  k_scan1<<<SB1, b256, 0, stream>>>(deg, rowptr, part, N);
  k_scan2<<<1, 64, 0, stream>>>(part, SB1);
  k_scan3<<<NB, b256, 0, stream>>>(rowptr, part, deg, dinv, N, E);
  k_slots<<<EB, b256, 0, stream>>>(ei, rowptr, cnt, csr_src, csr_eid, E);
  if (PERM) k_gather<<<EB, b256, 0, stream>>>(csr_eid, ea, eaperm, E);

  // ---- GENConv 1 (64 -> 48) ----
  if (PERM) k_lin<64, 48, true><<<NB, b256, 0, stream>>>(x, w_src1, b_src1, P0, hbf1, 48, N);
  else      k_lin<64, 48, false><<<NB, b256, 0, stream>>>(x, w_src1, b_src1, P0, nullptr, 48, N);
  if (PERM) k_agg48<true><<<(N * 64 + 255) / 256, b256, 0, stream>>>(rowptr, csr_src,
                       csr_eid, eaperm, ea, w_edge1, b_edge1, P0, hbf1, P3, N);
  else      k_agg48<false><<<(N * 64 + 255) / 256, b256, 0, stream>>>(rowptr, csr_src,
                       csr_eid, eaperm, ea, w_edge1, b_edge1, P0, hbf1, P3, N);
  k_ztstats<48><<<NB, b256, 0, stream>>>(P3, w_m1a, b_m1a, P1, P2, partial, N);
  k_bnfin<<<1, 256, 0, stream>>>(partial, stats, NB, 192);
  if (PERM)
    k_mlp_lin<48, 96, 32, true, true, false, true><<<NB, b256, 0, stream>>>(P1, P2, stats,
                       g1, be1, w_m1b, b_m1b, w_src2, nullptr, b_src2, nullptr, P0, hbf2,
                       1.0f / (float)N, N);
  else
    k_mlp_lin<48, 96, 32, true, false, false, true><<<NB, b256, 0, stream>>>(P1, P2, stats,
                       g1, be1, w_m1b, b_m1b, w_src2, nullptr, b_src2, nullptr, P0, nullptr,
                       1.0f / (float)N, N);

  // ---- GENConv 2 (48 -> 32) ----
  if (PERM) k_agg32<true><<<(N * 32 + 255) / 256, b256, 0, stream>>>(rowptr, csr_src,
                       csr_eid, eaperm, ea, w_edge2, b_edge2, P0, hbf2, P3, N);
  else      k_agg32<false><<<(N * 32 + 255) / 256, b256, 0, stream>>>(rowptr, csr_src,
                       csr_eid, eaperm, ea, w_edge2, b_edge2, P0, hbf2, P3, N);
  k_ztstats<32><<<NB, b256, 0, stream>>>(P3, w_m2a, b_m2a, P1, P2, partial, N);
  k_bnfin<<<1, 256, 0, stream>>>(partial, stats + 256, NB, 128);
  // heads output written ONLY as dinv-scaled bf16 (hbf2 free after agg32)
  k_mlp_lin<32, 64, 32, false, true, true, false><<<NB, b256, 0, stream>>>(P1, P2,
                       stats + 256, g2, be2, w_m2b, b_m2b, w_mu, w_ls, nullptr, dinv,
                       nullptr, hbf2, 1.0f / (float)N, N);

  // ---- GCN heads ----
  k_gcn<<<(N * 32 + 255) / 256, b256, 0, stream>>>(rowptr, csr_src, hbf2, dinv,
                                                   b_mu, b_ls, (float*)d_out, N);
}

// Round 23
// 880.803 us; speedup vs baseline: 1.4857x; 1.0196x over previous
//
#include <hip/hip_runtime.h>
#include <hip/hip_bf16.h>

typedef unsigned int u32;
typedef unsigned short u16;
typedef _Float16 h2 __attribute__((ext_vector_type(2)));

#define EPS_MSG 1e-7f
#define BN_EPS  1e-5f

__device__ __forceinline__ u16 f2bf(float f) {          // round-to-nearest-even
  u32 u = __float_as_uint(f);
  return (u16)((u + 0x7FFFu + ((u >> 16) & 1u)) >> 16);
}
__device__ __forceinline__ float bf1(u16 v) { return __uint_as_float(((u32)v) << 16); }
__device__ __forceinline__ float bflo(u32 v) { return __uint_as_float(v << 16); }
__device__ __forceinline__ float bfhi(u32 v) { return __uint_as_float(v & 0xFFFF0000u); }
__device__ __forceinline__ h2 u2h(u32 v) { union { u32 u; h2 h; } t; t.u = v; return t.h; }

// pack two f32 -> pk f16 pair as raw u32 (via __fp16 vector return type)
__device__ __forceinline__ u32 pkrtz(float a, float b) {
  union { __fp16 v __attribute__((ext_vector_type(2))); u32 u; } t;
  t.v = __builtin_amdgcn_cvt_pkrtz(a, b);
  return t.u;
}

// 8 f16 pairs (one uint4) dotted against packed weights via v_dot2_f32_f16
__device__ __forceinline__ float dot8(uint4 v, const u32* w, float acc) {
  acc = __builtin_amdgcn_fdot2(u2h(v.x), u2h(w[0]), acc, false);
  acc = __builtin_amdgcn_fdot2(u2h(v.y), u2h(w[1]), acc, false);
  acc = __builtin_amdgcn_fdot2(u2h(v.z), u2h(w[2]), acc, false);
  acc = __builtin_amdgcn_fdot2(u2h(v.w), u2h(w[3]), acc, false);
  return acc;
}

#define EDGE_DOT(A0,A1,A2,A3) (bias + \
  A0.x * wc[0]  + A0.y * wc[1]  + A0.z * wc[2]  + A0.w * wc[3] + \
  A1.x * wc[4]  + A1.y * wc[5]  + A1.z * wc[6]  + A1.w * wc[7] + \
  A2.x * wc[8]  + A2.y * wc[9]  + A2.z * wc[10] + A2.w * wc[11] + \
  A3.x * wc[12] + A3.y * wc[13] + A3.z * wc[14] + A3.w * wc[15])

// ---- small linear: Y[i*ldY+c] = X[i,:]·W[:,c] + B[c]; optional bf16 shadow --
template<int I, int O, bool WBF>
__global__ void k_lin(const float* __restrict__ X, const float* __restrict__ W,
                      const float* __restrict__ B, float* __restrict__ Y,
                      u16* __restrict__ Ybf, int ldY, int n) {
  __shared__ float Wl[I * O];
  __shared__ float Bl[O];
  for (int t = threadIdx.x; t < I * O; t += blockDim.x) Wl[t] = W[t];
  if (threadIdx.x < O) Bl[threadIdx.x] = B[threadIdx.x];
  __syncthreads();
  int i = blockIdx.x * blockDim.x + threadIdx.x;
  if (i >= n) return;
  float acc[O];
#pragma unroll
  for (int c = 0; c < O; c++) acc[c] = Bl[c];
  const float4* xp = (const float4*)(X + (size_t)i * I);
  for (int q = 0; q < I / 4; q++) {
    float4 v = xp[q];
#pragma unroll
    for (int c = 0; c < O; c++) acc[c] += v.x * Wl[(4 * q + 0) * O + c];
#pragma unroll
    for (int c = 0; c < O; c++) acc[c] += v.y * Wl[(4 * q + 1) * O + c];
#pragma unroll
    for (int c = 0; c < O; c++) acc[c] += v.z * Wl[(4 * q + 2) * O + c];
#pragma unroll
    for (int c = 0; c < O; c++) acc[c] += v.w * Wl[(4 * q + 3) * O + c];
  }
  float* y = Y + (size_t)i * ldY;
#pragma unroll
  for (int c = 0; c < O; c++) y[c] = acc[c];
  if (WBF) {
    u16* yb = Ybf + (size_t)i * O;
#pragma unroll
    for (int c = 0; c < O; c++) yb[c] = f2bf(acc[c]);
  }
}

// ---- CSR construction -------------------------------------------------------
__global__ void k_deg(const int* __restrict__ ei, u32* __restrict__ deg, int E) {
  int e = blockIdx.x * blockDim.x + threadIdx.x;
  if (e < E) atomicAdd(&deg[ei[E + e]], 1u);
}

__global__ void k_scan1(const u32* __restrict__ deg, u32* __restrict__ excl,
                        u32* __restrict__ part, int n) {
  __shared__ u32 sm[256];
  int t = threadIdx.x;
  int base = blockIdx.x * 1024 + t * 4;
  u32 v0 = (base + 0 < n) ? deg[base + 0] : 0u;
  u32 v1 = (base + 1 < n) ? deg[base + 1] : 0u;
  u32 v2 = (base + 2 < n) ? deg[base + 2] : 0u;
  u32 v3 = (base + 3 < n) ? deg[base + 3] : 0u;
  u32 tsum = v0 + v1 + v2 + v3;
  sm[t] = tsum;
  __syncthreads();
  for (int o = 1; o < 256; o <<= 1) {
    u32 v = (t >= o) ? sm[t - o] : 0u;
    __syncthreads();
    sm[t] += v;
    __syncthreads();
  }
  u32 tex = sm[t] - tsum;
  if (t == 255) part[blockIdx.x] = sm[255];
  if (base + 0 < n) excl[base + 0] = tex;
  if (base + 1 < n) excl[base + 1] = tex + v0;
  if (base + 2 < n) excl[base + 2] = tex + v0 + v1;
  if (base + 3 < n) excl[base + 3] = tex + v0 + v1 + v2;
}

__global__ void k_scan2(u32* __restrict__ part, int nb) {
  if (threadIdx.x == 0) {
    u32 acc = 0;
    for (int i = 0; i < nb; i++) { u32 v = part[i]; part[i] = acc; acc += v; }
  }
}

// scan finalize + dinv fused
__global__ void k_scan3(u32* __restrict__ rowptr, const u32* __restrict__ part,
                        const u32* __restrict__ deg, float* __restrict__ dinv,
                        int n, int E) {
  int i = blockIdx.x * blockDim.x + threadIdx.x;
  if (i < n) {
    rowptr[i] += part[i >> 10];
    dinv[i] = rsqrtf((float)(deg[i] + 1u));
  }
  if (i == 0) rowptr[n] = (u32)E;
}

__global__ void k_slots(const int* __restrict__ ei, const u32* __restrict__ rowptr,
                        u32* __restrict__ cnt, int* __restrict__ csr_src,
                        int* __restrict__ csr_eid, int E) {
  int e = blockIdx.x * blockDim.x + threadIdx.x;
  if (e >= E) return;
  int s = ei[e], d = ei[E + e];
  u32 slot = rowptr[d] + atomicAdd(&cnt[d], 1u);
  csr_src[slot] = s;
  csr_eid[slot] = e;
}

// slot-major attr permute, packed f16: 32B/edge, v_cvt_pkrtz packing
__global__ void k_gather(const int* __restrict__ csr_eid, const float* __restrict__ ea,
                         u32* __restrict__ eaperm, int E) {
  int i = blockIdx.x * blockDim.x + threadIdx.x;
  if (i >= E) return;
  int e = csr_eid[i];
  const float4* p = (const float4*)(ea + (size_t)e * 16);
  float4 a = p[0], b = p[1], c = p[2], d = p[3];
  uint4* q = (uint4*)(eaperm + (size_t)i * 8);
  uint4 w0, w1;
  w0.x = pkrtz(a.x, a.y);
  w0.y = pkrtz(a.z, a.w);
  w0.z = pkrtz(b.x, b.y);
  w0.w = pkrtz(b.z, b.w);
  w1.x = pkrtz(c.x, c.y);
  w1.y = pkrtz(c.z, c.w);
  w1.z = pkrtz(d.x, d.y);
  w1.w = pkrtz(d.z, d.w);
  q[0] = w0; q[1] = w1;
}

// ---- GENConv agg d=48: wave/node; csr preloaded into lanes, readlane fetch --
template<bool PERM>
__global__ void k_agg48(const u32* __restrict__ rowptr, const int* __restrict__ csr_src,
                        const int* __restrict__ csr_eid, const u32* __restrict__ eaperm,
                        const float* __restrict__ ea,
                        const float* __restrict__ we, const float* __restrict__ be,
                        const float* __restrict__ h, const u16* __restrict__ hbf,
                        float* __restrict__ out, int n) {
  int lane = threadIdx.x & 63;
  int cl   = (lane < 48) ? lane : lane - 48;   // lanes 48-63 duplicate ch 0-15
  int node = (blockIdx.x * blockDim.x + threadIdx.x) >> 6;
  if (node >= n) return;
  float bias = be[cl];
  float hself = h[(size_t)node * 48 + cl];
  u32 b = rowptr[node], t = rowptr[node + 1];
  u32 dn = t - b;
  float den = 0.f, num = 0.f;
  if (PERM) {
    u32 wcp[8];
#pragma unroll
    for (int k = 0; k < 8; k++)
      wcp[k] = pkrtz(we[(2 * k + 0) * 48 + cl], we[(2 * k + 1) * 48 + cl]);
    u32 nf = dn < 64u ? dn : 64u;
    int vcsr = ((u32)lane < nf) ? csr_src[b + lane] : 0;   // one vector load
    u32 j = 0;
    for (; j + 2 <= nf; j += 2) {
      int s0 = __builtin_amdgcn_readlane(vcsr, j);
      int s1 = __builtin_amdgcn_readlane(vcsr, j + 1);
      float h0 = bf1(hbf[(size_t)s0 * 48 + cl]);
      float h1 = bf1(hbf[(size_t)s1 * 48 + cl]);
      const uint4* pa = (const uint4*)(eaperm + (size_t)(b + j) * 8);
      uint4 a0 = pa[0], a1 = pa[1];
      uint4 b0 = pa[2], b1 = pa[3];
      float ml0 = dot8(a1, wcp + 4, dot8(a0, wcp, bias));
      float ml1 = dot8(b1, wcp + 4, dot8(b0, wcp, bias));
      float m0 = fmaxf(h0 + ml0, 0.f) + EPS_MSG;
      float m1 = fmaxf(h1 + ml1, 0.f) + EPS_MSG;
      float ex0 = __expf(m0);
      float ex1 = __expf(m1);
      den += ex0 + ex1;
      num += ex0 * m0 + ex1 * m1;
    }
    for (; j < nf; j++) {
      int s = __builtin_amdgcn_readlane(vcsr, j);
      const uint4* pa = (const uint4*)(eaperm + (size_t)(b + j) * 8);
      uint4 a0 = pa[0], a1 = pa[1];
      float hv = bf1(hbf[(size_t)s * 48 + cl]);
      float ml = dot8(a1, wcp + 4, dot8(a0, wcp, bias));
      float m  = fmaxf(hv + ml, 0.f) + EPS_MSG;
      float ex = __expf(m);
      den += ex; num += ex * m;
    }
    for (u32 i = b + nf; i < t; i++) {       // deg > 64 tail (rare)
      int s = csr_src[i];
      const uint4* pa = (const uint4*)(eaperm + (size_t)i * 8);
      uint4 a0 = pa[0], a1 = pa[1];
      float hv = bf1(hbf[(size_t)s * 48 + cl]);
      float ml = dot8(a1, wcp + 4, dot8(a0, wcp, bias));
      float m  = fmaxf(hv + ml, 0.f) + EPS_MSG;
      float ex = __expf(m);
      den += ex; num += ex * m;
    }
  } else {
    float wc[16];
#pragma unroll
    for (int k = 0; k < 16; k++) wc[k] = we[k * 48 + cl];
    for (u32 i = b; i < t; i++) {
      int s = csr_src[i];
      const float4* p = (const float4*)(ea + (size_t)csr_eid[i] * 16);
      float4 a0 = p[0], a1 = p[1], a2 = p[2], a3 = p[3];
      float hv = h[(size_t)s * 48 + cl];
      float ml = EDGE_DOT(a0, a1, a2, a3);
      float m  = fmaxf(hv + ml, 0.f) + EPS_MSG;
      float ex = __expf(m);
      den += ex; num += ex * m;
    }
  }
  if (lane < 48)
    out[(size_t)node * 48 + lane] = hself + num / (den + 1e-16f);
}

// ---- GENConv agg d=32: half-wave/node; csr preload + __shfl (per-lane idx) --
template<bool PERM>
__global__ void k_agg32(const u32* __restrict__ rowptr, const int* __restrict__ csr_src,
                        const int* __restrict__ csr_eid, const u32* __restrict__ eaperm,
                        const float* __restrict__ ea,
                        const float* __restrict__ we, const float* __restrict__ be,
                        const float* __restrict__ h, const u16* __restrict__ hbf,
                        float* __restrict__ out, int n) {
  int lane = threadIdx.x & 63;
  int c    = lane & 31;
  int half = (lane >> 5) & 1;                 // 0 or 1: which half-wave
  int node = (blockIdx.x * blockDim.x + threadIdx.x) >> 5;
  if (node >= n) return;
  float bias = be[c];
  float hself = h[(size_t)node * 32 + c];
  u32 b = rowptr[node], t = rowptr[node + 1];
  u32 dn = t - b;
  float den = 0.f, num = 0.f;
  if (PERM) {
    u32 wcp[8];
#pragma unroll
    for (int k = 0; k < 8; k++)
      wcp[k] = pkrtz(we[(2 * k + 0) * 32 + c], we[(2 * k + 1) * 32 + c]);
    u32 nf = dn < 32u ? dn : 32u;
    int vcsr = ((u32)c < nf) ? csr_src[b + c] : 0;   // half-wave preload
    int lbase = half << 5;                           // this half's lane base
    u32 j = 0;
    for (; j + 2 <= nf; j += 2) {
      int s0 = __shfl(vcsr, lbase + (int)j);
      int s1 = __shfl(vcsr, lbase + (int)j + 1);
      float h0 = bf1(hbf[(size_t)s0 * 32 + c]);
      float h1 = bf1(hbf[(size_t)s1 * 32 + c]);
      const uint4* pa = (const uint4*)(eaperm + (size_t)(b + j) * 8);
      uint4 a0 = pa[0], a1 = pa[1];
      uint4 b0 = pa[2], b1 = pa[3];
      float ml0 = dot8(a1, wcp + 4, dot8(a0, wcp, bias));
      float ml1 = dot8(b1, wcp + 4, dot8(b0, wcp, bias));
      float m0 = fmaxf(h0 + ml0, 0.f) + EPS_MSG;
      float m1 = fmaxf(h1 + ml1, 0.f) + EPS_MSG;
      float ex0 = __expf(m0);
      float ex1 = __expf(m1);
      den += ex0 + ex1;
      num += ex0 * m0 + ex1 * m1;
    }
    for (; j < nf; j++) {
      int s = __shfl(vcsr, lbase + (int)j);
      const uint4* pa = (const uint4*)(eaperm + (size_t)(b + j) * 8);
      uint4 a0 = pa[0], a1 = pa[1];
      float hv = bf1(hbf[(size_t)s * 32 + c]);
      float ml = dot8(a1, wcp + 4, dot8(a0, wcp, bias));
      float m  = fmaxf(hv + ml, 0.f) + EPS_MSG;
      float ex = __expf(m);
      den += ex; num += ex * m;
    }
    for (u32 i = b + nf; i < t; i++) {        // deg > 32 tail
      int s = csr_src[i];
      const uint4* pa = (const uint4*)(eaperm + (size_t)i * 8);
      uint4 a0 = pa[0], a1 = pa[1];
      float hv = bf1(hbf[(size_t)s * 32 + c]);
      float ml = dot8(a1, wcp + 4, dot8(a0, wcp, bias));
      float m  = fmaxf(hv + ml, 0.f) + EPS_MSG;
      float ex = __expf(m);
      den += ex; num += ex * m;
    }
  } else {
    float wc[16];
#pragma unroll
    for (int k = 0; k < 16; k++) wc[k] = we[k * 32 + c];
    for (u32 i = b; i < t; i++) {
      int s = csr_src[i];
      const float4* p = (const float4*)(ea + (size_t)csr_eid[i] * 16);
      float4 a0 = p[0], a1 = p[1], a2 = p[2], a3 = p[3];
      float hv = h[(size_t)s * 32 + c];
      float ml = EDGE_DOT(a0, a1, a2, a3);
      float m  = fmaxf(hv + ml, 0.f) + EPS_MSG;
      float ex = __expf(m);
      den += ex; num += ex * m;
    }
  }
  out[(size_t)node * 32 + c] = hself + num / (den + 1e-16f);
}

// ---- zt = X@W1 + B1 (bf16 split panels) + per-block BN-stat partials --------
template<int D>
__global__ void k_ztstats(const float* __restrict__ X, const float* __restrict__ W,
                          const float* __restrict__ B, u16* __restrict__ Z1,
                          u16* __restrict__ Z2, float* __restrict__ partial, int n) {
  __shared__ float Wl[D * 2 * D];
  __shared__ float Bl[2 * D];
  __shared__ float red[4][4 * D];
  for (int t = threadIdx.x; t < D * 2 * D; t += blockDim.x) Wl[t] = W[t];
  for (int t = threadIdx.x; t < 2 * D; t += blockDim.x) Bl[t] = B[t];
  __syncthreads();
  int i = blockIdx.x * blockDim.x + threadIdx.x;
  bool act = (i < n);
  float acc[2 * D];
#pragma unroll
  for (int c = 0; c < 2 * D; c++) acc[c] = 0.f;
  if (act) {
#pragma unroll
    for (int c = 0; c < 2 * D; c++) acc[c] = Bl[c];
    const float4* xp = (const float4*)(X + (size_t)i * D);
    for (int q = 0; q < D / 4; q++) {
      float4 v = xp[q];
#pragma unroll
      for (int c = 0; c < 2 * D; c++) acc[c] += v.x * Wl[(4 * q + 0) * 2 * D + c];
#pragma unroll
      for (int c = 0; c < 2 * D; c++) acc[c] += v.y * Wl[(4 * q + 1) * 2 * D + c];
#pragma unroll
      for (int c = 0; c < 2 * D; c++) acc[c] += v.z * Wl[(4 * q + 2) * 2 * D + c];
#pragma unroll
      for (int c = 0; c < 2 * D; c++) acc[c] += v.w * Wl[(4 * q + 3) * 2 * D + c];
    }
    u16* z1 = Z1 + (size_t)i * D;
    u16* z2 = Z2 + (size_t)i * D;
#pragma unroll
    for (int c = 0; c < D; c++) { z1[c] = f2bf(acc[c]); z2[c] = f2bf(acc[D + c]); }
  } else {
#pragma unroll
    for (int c = 0; c < 2 * D; c++) acc[c] = 0.f;
  }
  int lane = threadIdx.x & 63;
  int wv   = threadIdx.x >> 6;
#pragma unroll
  for (int c = 0; c < 2 * D; c++) {
    float v = acc[c], v2 = v * v;
#pragma unroll
    for (int o = 32; o; o >>= 1) { v += __shfl_xor(v, o); v2 += __shfl_xor(v2, o); }
    if (lane == 0) { red[wv][c] = v; red[wv][2 * D + c] = v2; }
  }
  __syncthreads();
  if (threadIdx.x < 4 * D) {
    float s = red[0][threadIdx.x] + red[1][threadIdx.x] +
              red[2][threadIdx.x] + red[3][threadIdx.x];
    partial[(size_t)blockIdx.x * 4 * D + threadIdx.x] = s;
  }
}

__global__ void k_bnfin(const float* __restrict__ partial, float* __restrict__ stats,
                        int nb, int m) {
  int c = blockIdx.x * blockDim.x + threadIdx.x;
  if (c >= m) return;
  float s = 0.f;
  for (int b = 0; b < nb; b++) s += partial[(size_t)b * m + c];
  stats[c] = s;
}

// ---- BN -> relu -> @W2+b2 -> relu -> @Ws(+Bs); bf16 zt in; f32/bf16 out -----
template<int D, int DD, int O, bool ADDBS, bool WBF, bool SCALE, bool WOUT>
__global__ void k_mlp_lin(const u16* __restrict__ ztA, const u16* __restrict__ ztB,
                          const float* __restrict__ stats,
                          const float* __restrict__ G, const float* __restrict__ BE,
                          const float* __restrict__ W2, const float* __restrict__ B2,
                          const float* __restrict__ Wsa, const float* __restrict__ Wsb,
                          const float* __restrict__ Bs, const float* __restrict__ dinv,
                          float* __restrict__ out, u16* __restrict__ outbf,
                          float invN, int n) {
  __shared__ float Wl[DD * D];
  __shared__ float Ws[D * O];
  __shared__ float Bl[D];
  __shared__ float Bsl[O];
  __shared__ float sc[DD], sh[DD];
  for (int t = threadIdx.x; t < DD * D; t += blockDim.x) Wl[t] = W2[t];
  if (Wsb == nullptr) {
    for (int t = threadIdx.x; t < D * O; t += blockDim.x) Ws[t] = Wsa[t];
  } else {
    for (int t = threadIdx.x; t < D * O; t += blockDim.x) {
      int k = t / O, o = t % O;
      Ws[t] = (o < O / 2) ? Wsa[k * (O / 2) + o] : Wsb[k * (O / 2) + (o - O / 2)];
    }
  }
  if (threadIdx.x < D) Bl[threadIdx.x] = B2[threadIdx.x];
  if (threadIdx.x < O) Bsl[threadIdx.x] = ADDBS ? Bs[threadIdx.x] : 0.f;
  if (threadIdx.x < DD) {
    int c   = threadIdx.x;
    float m = stats[c] * invN;
    float v = stats[DD + c] * invN - m * m;
    float s = G[c] * rsqrtf(v + BN_EPS);
    sc[c] = s; sh[c] = BE[c] - m * s;
  }
  __syncthreads();
  int i = blockIdx.x * blockDim.x + threadIdx.x;
  if (i >= n) return;
  float y[D];
#pragma unroll
  for (int c = 0; c < D; c++) y[c] = Bl[c];
  const uint2* ap = (const uint2*)(ztA + (size_t)i * D);   // 4 bf16 per uint2
  for (int q = 0; q < D / 4; q++) {
    uint2 v = ap[q];
    int k = q * 4;
    float z0 = fmaxf(bflo(v.x) * sc[k + 0] + sh[k + 0], 0.f);
    float z1 = fmaxf(bfhi(v.x) * sc[k + 1] + sh[k + 1], 0.f);
    float z2 = fmaxf(bflo(v.y) * sc[k + 2] + sh[k + 2], 0.f);
    float z3 = fmaxf(bfhi(v.y) * sc[k + 3] + sh[k + 3], 0.f);
#pragma unroll
    for (int c = 0; c < D; c++)
      y[c] += z0 * Wl[(k + 0) * D + c] + z1 * Wl[(k + 1) * D + c] +
              z2 * Wl[(k + 2) * D + c] + z3 * Wl[(k + 3) * D + c];
  }
  const uint2* bp = (const uint2*)(ztB + (size_t)i * D);
  for (int q = 0; q < D / 4; q++) {
    uint2 v = bp[q];
    int k = D + q * 4;
    float z0 = fmaxf(bflo(v.x) * sc[k + 0] + sh[k + 0], 0.f);
    float z1 = fmaxf(bfhi(v.x) * sc[k + 1] + sh[k + 1], 0.f);
    float z2 = fmaxf(bflo(v.y) * sc[k + 2] + sh[k + 2], 0.f);
    float z3 = fmaxf(bfhi(v.y) * sc[k + 3] + sh[k + 3], 0.f);
#pragma unroll
    for (int c = 0; c < D; c++)
      y[c] += z0 * Wl[(k + 0) * D + c] + z1 * Wl[(k + 1) * D + c] +
              z2 * Wl[(k + 2) * D + c] + z3 * Wl[(k + 3) * D + c];
  }
  float acc[O];
#pragma unroll
  for (int o = 0; o < O; o++) acc[o] = Bsl[o];
#pragma unroll
  for (int k = 0; k < D; k++) {
    float z = fmaxf(y[k], 0.f);
#pragma unroll
    for (int o = 0; o < O; o++) acc[o] += z * Ws[k * O + o];
  }
  float dv = SCALE ? dinv[i] : 1.f;
  if (WOUT) {
    float* yo = out + (size_t)i * O;
#pragma unroll
    for (int o = 0; o < O; o++) yo[o] = SCALE ? acc[o] * dv : acc[o];
  }
  if (WBF) {
    u16* yb = outbf + (size_t)i * O;
#pragma unroll
    for (int o = 0; o < O; o++) yb[o] = f2bf(SCALE ? acc[o] * dv : acc[o]);
  }
}

// ---- GCN heads: bf16 CSR gather, csr preload + __shfl, fused store ----------
__global__ void k_gcn(const u32* __restrict__ rowptr, const int* __restrict__ csr_src,
                      const u16* __restrict__ yzbf, const float* __restrict__ dinv,
                      const float* __restrict__ bmu, const float* __restrict__ bls,
                      float* __restrict__ out, int n) {
  int lane = threadIdx.x & 63;
  int c    = lane & 31;
  int half = (lane >> 5) & 1;
  int node = (blockIdx.x * blockDim.x + threadIdx.x) >> 5;
  if (node >= n) return;
  u32 b = rowptr[node], t = rowptr[node + 1];
  u32 dn = t - b;
  u32 nf = dn < 32u ? dn : 32u;
  int vcsr = ((u32)c < nf) ? csr_src[b + c] : 0;
  int lbase = half << 5;
  float acc = 0.f;
  u32 j = 0;
  for (; j + 2 <= nf; j += 2) {
    int s0 = __shfl(vcsr, lbase + (int)j);
    int s1 = __shfl(vcsr, lbase + (int)j + 1);
    float y0 = bf1(yzbf[(size_t)s0 * 32 + c]);
    float y1 = bf1(yzbf[(size_t)s1 * 32 + c]);
    acc += y0 + y1;
  }
  for (; j < nf; j++) {
    int s = __shfl(vcsr, lbase + (int)j);
    acc += bf1(yzbf[(size_t)s * 32 + c]);
  }
  for (u32 i = b + nf; i < t; i++) acc += bf1(yzbf[(size_t)csr_src[i] * 32 + c]);
  float dv  = dinv[node];
  float val = (acc + bf1(yzbf[(size_t)node * 32 + c])) * dv +
              ((c < 16) ? bmu[c] : bls[c - 16]);
  if (c < 16) out[(size_t)node * 16 + c] = val;
  else        out[(size_t)n * 16 + (size_t)node * 16 + (c - 16)] = val;
}

extern "C" void kernel_launch(void* const* d_in, const int* in_sizes, int n_in,
                              void* d_out, int out_size, void* d_ws, size_t ws_size,
                              hipStream_t stream) {
  const float* x      = (const float*)d_in[0];
  const int*  ei      = (const int*)d_in[1];          // int32 (2,E) rows
  const float* ea     = (const float*)d_in[2];
  const float* w_src1 = (const float*)d_in[3];  const float* b_src1 = (const float*)d_in[4];
  const float* w_edge1= (const float*)d_in[5];  const float* b_edge1= (const float*)d_in[6];
  const float* w_m1a  = (const float*)d_in[7];  const float* b_m1a  = (const float*)d_in[8];
  const float* g1     = (const float*)d_in[9];  const float* be1    = (const float*)d_in[10];
  const float* w_m1b  = (const float*)d_in[11]; const float* b_m1b  = (const float*)d_in[12];
  const float* w_src2 = (const float*)d_in[13]; const float* b_src2 = (const float*)d_in[14];
  const float* w_edge2= (const float*)d_in[15]; const float* b_edge2= (const float*)d_in[16];
  const float* w_m2a  = (const float*)d_in[17]; const float* b_m2a  = (const float*)d_in[18];
  const float* g2     = (const float*)d_in[19]; const float* be2    = (const float*)d_in[20];
  const float* w_m2b  = (const float*)d_in[21]; const float* b_m2b  = (const float*)d_in[22];
  const float* w_mu   = (const float*)d_in[23]; const float* b_mu   = (const float*)d_in[24];
  const float* w_ls   = (const float*)d_in[25]; const float* b_ls   = (const float*)d_in[26];

  const int N = in_sizes[0] / 64;
  const int E = in_sizes[1] / 2;

  const int NB  = (N + 255) / 256;
  const int EB  = (E + 255) / 256;
  const int SB1 = (N + 1023) / 1024;

  float* ws     = (float*)d_ws;
  size_t N48    = (size_t)N * 48;
  float* P0     = ws;
  u16*  Z1      = (u16*)(ws + N48);          // bf16 zt panel A (N*48 u16 fits)
  u16*  Z2      = (u16*)(ws + 2 * N48);      // bf16 zt panel B
  float* P3     = ws + 3 * N48;
  size_t o      = 4 * N48;
  u32*  rowptr  = (u32*)(ws + o);            // N+1
  u32*  cnt     = rowptr + (N + 1);          // N
  u32*  deg     = cnt + N;                   // N
  u32*  part    = deg + N;                   // 256
  float* dinv   = (float*)(part + 256);      // N
  float* stats  = dinv + N;                  // 512
  size_t po     = o + 4 * (size_t)N + 769;
  float* partial= ws + po;                   // NB*192
  size_t co     = (po + (size_t)NB * 192 + 3) & ~(size_t)3;
  int*  csr_src = (int*)(ws + co);           // E ints
  int*  csr_eid = csr_src + E;               // E ints
  size_t eo     = co + 2 * (size_t)E;        // 16B-aligned
  u32*  eaperm  = (u32*)(ws + eo);           // 8E u32 (f16-packed attrs)
  size_t ho     = eo + 8 * (size_t)E;
  u16*  hbf1    = (u16*)(ws + ho);           // N*48 u16
  size_t h2o    = ho + 24 * (size_t)N;
  u16*  hbf2    = (u16*)(ws + h2o);          // N*32 u16 (agg32 in; then yzd bf16)
  size_t needB  = (h2o + 16 * (size_t)N + 16) * sizeof(float);
  const bool PERM = (ws_size >= needB);

  dim3 b256(256);

  hipMemsetAsync(cnt, 0, 2 * (size_t)N * sizeof(u32), stream);

  // CSR build
  k_deg<<<EB, b256, 0, stream>>>(ei, deg, E);
  k_scan1<<<SB1, b256, 0, stream>>>(deg, rowptr, part, N);
  k_scan2<<<1, 64, 0, stream>>>(part, SB1);
  k_scan3<<<NB, b256, 0, stream>>>(rowptr, part, deg, dinv, N, E);
  k_slots<<<EB, b256, 0, stream>>>(ei, rowptr, cnt, csr_src, csr_eid, E);
  if (PERM) k_gather<<<EB, b256, 0, stream>>>(csr_eid, ea, eaperm, E);

  // ---- GENConv 1 (64 -> 48) ----
  if (PERM) k_lin<64, 48, true><<<NB, b256, 0, stream>>>(x, w_src1, b_src1, P0, hbf1, 48, N);
  else      k_lin<64, 48, false><<<NB, b256, 0, stream>>>(x, w_src1, b_src1, P0, nullptr, 48, N);
  if (PERM) k_agg48<true><<<(N * 64 + 255) / 256, b256, 0, stream>>>(rowptr, csr_src,
                       csr_eid, eaperm, ea, w_edge1, b_edge1, P0, hbf1, P3, N);
  else      k_agg48<false><<<(N * 64 + 255) / 256, b256, 0, stream>>>(rowptr, csr_src,
                       csr_eid, eaperm, ea, w_edge1, b_edge1, P0, hbf1, P3, N);
  k_ztstats<48><<<NB, b256, 0, stream>>>(P3, w_m1a, b_m1a, Z1, Z2, partial, N);
  k_bnfin<<<1, 256, 0, stream>>>(partial, stats, NB, 192);
  if (PERM)
    k_mlp_lin<48, 96, 32, true, true, false, true><<<NB, b256, 0, stream>>>(Z1, Z2, stats,
                       g1, be1, w_m1b, b_m1b, w_src2, nullptr, b_src2, nullptr, P0, hbf2,
                       1.0f / (float)N, N);
  else
    k_mlp_lin<48, 96, 32, true, false, false, true><<<NB, b256, 0, stream>>>(Z1, Z2, stats,
                       g1, be1, w_m1b, b_m1b, w_src2, nullptr, b_src2, nullptr, P0, nullptr,
                       1.0f / (float)N, N);

  // ---- GENConv 2 (48 -> 32) ----
  if (PERM) k_agg32<true><<<(N * 32 + 255) / 256, b256, 0, stream>>>(rowptr, csr_src,
                       csr_eid, eaperm, ea, w_edge2, b_edge2, P0, hbf2, P3, N);
  else      k_agg32<false><<<(N * 32 + 255) / 256, b256, 0, stream>>>(rowptr, csr_src,
                       csr_eid, eaperm, ea, w_edge2, b_edge2, P0, hbf2, P3, N);
  k_ztstats<32><<<NB, b256, 0, stream>>>(P3, w_m2a, b_m2a, Z1, Z2, partial, N);
  k_bnfin<<<1, 256, 0, stream>>>(partial, stats + 256, NB, 128);
  // heads output written ONLY as dinv-scaled bf16 (hbf2 free after agg32)
  k_mlp_lin<32, 64, 32, false, true, true, false><<<NB, b256, 0, stream>>>(Z1, Z2,
                       stats + 256, g2, be2, w_m2b, b_m2b, w_mu, w_ls, nullptr, dinv,
                       nullptr, hbf2, 1.0f / (float)N, N);

  // ---- GCN heads ----
  k_gcn<<<(N * 32 + 255) / 256, b256, 0, stream>>>(rowptr, csr_src, hbf2, dinv,
                                                   b_mu, b_ls, (float*)d_out, N);
}